// Round 12
// baseline (411.600 us; speedup 1.0000x reference)
//
#include <hip/hip_runtime.h>

#define NN 50000
#define MP 50176   // row-padded
#define EE 800000
#define BB 64
#define NBUK 256   // buckets per graph
#define NPB 196    // nodes per bucket
#define EPB 4096   // edges per block in bucket passes
#define BBLK ((EE + EPB - 1)/EPB)   // 196 blocks

typedef _Float16 half_t;
typedef __attribute__((ext_vector_type(8))) _Float16 h16x8;
typedef __attribute__((ext_vector_type(4))) float f32x4;

__device__ __forceinline__ int ntld(const int* p){ return __builtin_nontemporal_load(p); }
__device__ __forceinline__ float ntldf(const float* p){ return __builtin_nontemporal_load(p); }

__device__ __forceinline__ unsigned pack_rec(int s, float w){
  union{ _Float16 h; unsigned short u; } c; c.h = (_Float16)w;
  return (unsigned)s | ((unsigned)c.u << 16);
}
__device__ __forceinline__ float rec_w(unsigned r){
  union{ unsigned short u; _Float16 h; } c; c.u = (unsigned short)(r >> 16);
  return (float)c.h;
}

// ---------------- fp32 rows -> fp16 rows (optional -1 masking) ----------------
template<bool MASK>
__global__ __launch_bounds__(256)
void tohalf_kernel(const float* __restrict__ x, half_t* __restrict__ o, int n8){
  int i = blockIdx.x*blockDim.x + threadIdx.x;
  if (i >= n8) return;
  float4 a = ((const float4*)x)[2*i];
  float4 b = ((const float4*)x)[2*i+1];
  float v[8] = {a.x,a.y,a.z,a.w,b.x,b.y,b.z,b.w};
  h16x8 h;
  #pragma unroll
  for (int j=0;j<8;j++){
    float f = v[j];
    if (MASK && f == -1.0f) f = 0.f;
    h[j] = (half_t)f;
  }
  __builtin_nontemporal_store(h, (h16x8*)o + i);
}

// ---------------- fused transpose + fp16 convert for all 8 weights ----------------
struct TS { const float* W; const float* add; half_t* oh; int K; int N; int base; };
struct TS8 { TS t[8]; int total; };

__global__ __launch_bounds__(256)
void tsplit8_kernel(TS8 a){
  int i = blockIdx.x*256 + threadIdx.x;
  if (i >= a.total) return;
  int w = 0;
  #pragma unroll
  for (int j=1;j<8;j++) if (i >= a.t[j].base) w = j;
  TS ts = a.t[w];
  int e = i - ts.base;
  int k = e / ts.N, n = e - k*ts.N;
  float v = ts.W[e] + (ts.add ? ts.add[e] : 0.f);
  ts.oh[(size_t)n*ts.K + k] = (half_t)v;
}

// ---------------- multi-split CSR build ----------------
__global__ __launch_bounds__(256)
void bcount_kernel(const int* __restrict__ dst1, const int* __restrict__ dst2,
                   int* __restrict__ bcnt){
  __shared__ int hist[2*NBUK];
  int t = threadIdx.x;
  for (int s=t; s<2*NBUK; s+=256) hist[s]=0;
  __syncthreads();
  int base = blockIdx.x*EPB;
  #pragma unroll 4
  for (int j=0;j<16;j++){
    int i = base + j*256 + t;
    if (i < EE){
      atomicAdd(&hist[ntld(&dst1[i])/NPB], 1);
      atomicAdd(&hist[NBUK + ntld(&dst2[i])/NPB], 1);
    }
  }
  __syncthreads();
  for (int s=t; s<2*NBUK; s+=256){
    int v = hist[s];
    if (v) atomicAdd(&bcnt[s], v);
  }
}

__global__ __launch_bounds__(512)
void bscan_kernel(const int* __restrict__ bcnt, int* __restrict__ boff, int* __restrict__ bcur){
  __shared__ int s[512];
  int t = threadIdx.x;
  int v = bcnt[t];
  s[t]=v; __syncthreads();
  #pragma unroll
  for (int o=1;o<512;o<<=1){ int u=(t>=o)?s[t-o]:0; __syncthreads(); s[t]+=u; __syncthreads(); }
  int ex = s[t]-v;
  boff[t]=ex; bcur[t]=ex;
  if (t==511) boff[512]=s[511];
}

__global__ __launch_bounds__(256)
void bscatter_kernel(const int* __restrict__ src1, const int* __restrict__ dst1, const float* __restrict__ ea,
                     const int* __restrict__ src2, const int* __restrict__ dst2, const float* __restrict__ dea,
                     int* __restrict__ bcur, uint2* __restrict__ buf){
  __shared__ int hist[2*NBUK];
  __shared__ int bas[2*NBUK];
  int t = threadIdx.x;
  for (int s=t; s<2*NBUK; s+=256) hist[s]=0;
  __syncthreads();
  int base = blockIdx.x*EPB;
  #pragma unroll 4
  for (int j=0;j<16;j++){
    int i = base + j*256 + t;
    if (i < EE){
      atomicAdd(&hist[ntld(&dst1[i])/NPB], 1);
      atomicAdd(&hist[NBUK + ntld(&dst2[i])/NPB], 1);
    }
  }
  __syncthreads();
  for (int s=t; s<2*NBUK; s+=256){
    int v = hist[s];
    bas[s] = v ? atomicAdd(&bcur[s], v) : 0;
  }
  __syncthreads();
  for (int s=t; s<2*NBUK; s+=256) hist[s]=0;
  __syncthreads();
  #pragma unroll 4
  for (int j=0;j<16;j++){
    int i = base + j*256 + t;
    if (i < EE){
      {
        int d = ntld(&dst1[i]); int b = d/NPB;
        int p = atomicAdd(&hist[b],1);
        buf[bas[b]+p] = make_uint2(pack_rec(ntld(&src1[i]), ntldf(&ea[i])), (unsigned)d);
      }
      {
        int d = ntld(&dst2[i]); int b = NBUK + d/NPB;
        int p = atomicAdd(&hist[b],1);
        buf[bas[b]+p] = make_uint2(pack_rec(ntld(&src2[i]), ntldf(&dea[i])), (unsigned)d);
      }
    }
  }
}

__global__ __launch_bounds__(256)
void bfinal_kernel(const uint2* __restrict__ buf, const int* __restrict__ boff,
                   unsigned* __restrict__ rec, int* __restrict__ ptr1, int* __restrict__ ptr2){
  __shared__ int cnt[NPB], off[256], cur[NPB];
  int b = blockIdx.x;
  int g = b >> 8, lb = b & 255;
  int n0 = lb*NPB;
  int t = threadIdx.x;
  int seg0 = boff[b], seg1 = boff[b+1];
  int m = seg1 - seg0;
  if (t < NPB){ cnt[t]=0; cur[t]=0; }
  __syncthreads();
  for (int j=t; j<m; j+=256) atomicAdd(&cnt[(int)buf[seg0+j].y - n0], 1);
  __syncthreads();
  int v = (t < NPB) ? cnt[t] : 0;
  off[t] = v; __syncthreads();
  #pragma unroll
  for (int o=1;o<256;o<<=1){ int u=(t>=o)?off[t-o]:0; __syncthreads(); off[t]+=u; __syncthreads(); }
  int ex = off[t]-v;
  __syncthreads();
  off[t] = ex;
  __syncthreads();
  int node = n0 + t;
  if (t < NPB && node <= NN){
    int val = seg0 + off[t];
    if (g==0) ptr1[node]=val; else ptr2[node]=val;
  }
  for (int j=t; j<m; j+=256){
    uint2 r = buf[seg0+j];
    int l = (int)r.y - n0;
    int p = atomicAdd(&cur[l],1);
    rec[seg0 + off[l] + p] = r.x;
  }
}

// ---------------- compact-CSR gather, coalesced recs + shfl, unroll 8, nt store ----------------
template<int F>
__global__ __launch_bounds__(256)
void gather_kernel(const half_t* __restrict__ H, int ldh,
                   const int* __restrict__ ptr, const unsigned* __restrict__ rec,
                   half_t* __restrict__ Oh, int ldo){
  const int L = F/8;
  int gt = blockIdx.x*blockDim.x + threadIdx.x;
  int node = gt / L, lane = gt - node*L;
  if (node >= NN) return;
  int lo = ptr[node], hi = ptr[node+1];
  int k = hi - lo;
  const unsigned* base = rec + lo;
  float acc[8] = {0,0,0,0,0,0,0,0};
  #pragma unroll 1
  for (int j0=0; j0<k; j0+=L){
    unsigned myrec = (j0 + lane < k) ? base[j0 + lane] : 0u;
    int m = k - j0; if (m > L) m = L;
    int i = 0;
    #pragma unroll 1
    for (; i+8 <= m; i += 8){
      unsigned rr[8];
      #pragma unroll
      for (int u=0;u<8;u++) rr[u] = __shfl(myrec, i+u, L);
      h16x8 vv[8];
      #pragma unroll
      for (int u=0;u<8;u++) vv[u] = *(const h16x8*)(H + (size_t)(rr[u] & 0xFFFFu)*ldh + lane*8);
      #pragma unroll
      for (int u=0;u<8;u++){
        float w = rec_w(rr[u]);
        #pragma unroll
        for (int q=0;q<8;q++) acc[q] += w*(float)vv[u][q];
      }
    }
    #pragma unroll 1
    for (; i+4 <= m; i += 4){
      unsigned r0 = __shfl(myrec, i+0, L);
      unsigned r1 = __shfl(myrec, i+1, L);
      unsigned r2 = __shfl(myrec, i+2, L);
      unsigned r3 = __shfl(myrec, i+3, L);
      h16x8 v0 = *(const h16x8*)(H + (size_t)(r0 & 0xFFFFu)*ldh + lane*8);
      h16x8 v1 = *(const h16x8*)(H + (size_t)(r1 & 0xFFFFu)*ldh + lane*8);
      h16x8 v2 = *(const h16x8*)(H + (size_t)(r2 & 0xFFFFu)*ldh + lane*8);
      h16x8 v3 = *(const h16x8*)(H + (size_t)(r3 & 0xFFFFu)*ldh + lane*8);
      float w0 = rec_w(r0), w1 = rec_w(r1), w2 = rec_w(r2), w3 = rec_w(r3);
      #pragma unroll
      for (int q=0;q<8;q++)
        acc[q] += w0*(float)v0[q] + w1*(float)v1[q] + w2*(float)v2[q] + w3*(float)v3[q];
    }
    for (; i < m; ++i){
      unsigned r = __shfl(myrec, i, L);
      h16x8 v = *(const h16x8*)(H + (size_t)(r & 0xFFFFu)*ldh + lane*8);
      float w = rec_w(r);
      #pragma unroll
      for (int q=0;q<8;q++) acc[q] += w*(float)v[q];
    }
  }
  h16x8 oh;
  #pragma unroll
  for (int q=0;q<8;q++) oh[q] = (half_t)acc[q];
  __builtin_nontemporal_store(oh, (h16x8*)(Oh + (size_t)node*ldo + lane*8));
}

// ---------------- fp16 MFMA dual GEMM, 64x128 tile ----------------
__device__ __forceinline__ int lds_off(int r, int slot){ return r*64 + ((slot ^ (r&7))<<3); }

template<bool OUT16>
__global__ __launch_bounds__(256,3)
void mfma_gemm_kernel(const half_t* __restrict__ A, int K1, const half_t* __restrict__ W1,
                      const half_t* __restrict__ R, int K2, const half_t* __restrict__ W2,
                      const float* __restrict__ b1, const float* __restrict__ b2,
                      float* __restrict__ outf, half_t* __restrict__ out16, int ldo, int coloff){
  __shared__ half_t sA[64*64], sB[128*64];
  const int tid  = threadIdx.x;
  const int lane = tid & 63;
  const int wave = tid >> 6;
  const int wr = (wave>>1)*32, wc = (wave&1)*64;
  const int row0 = blockIdx.x*64;
  const int col0 = blockIdx.y*128;

  f32x4 acc[2][4];
  #pragma unroll
  for (int a=0;a<2;a++)
    #pragma unroll
    for (int b=0;b<4;b++){ acc[a][b][0]=0.f; acc[a][b][1]=0.f; acc[a][b][2]=0.f; acc[a][b][3]=0.f; }

  #pragma unroll 1
  for (int pass=0; pass<2; ++pass){
    const half_t* Ap = pass ? R  : A;
    const half_t* Wp = pass ? W2 : W1;
    const int K = pass ? K2 : K1;
    #pragma unroll 1
    for (int k0=0; k0<K; k0+=64){
      __syncthreads();
      // stage A: 64x8 slots = 512 -> 2 per thread
      #pragma unroll
      for (int i=0;i<2;i++){
        int c = tid + i*256;
        int r = c >> 3, s = c & 7;
        *(h16x8*)&sA[lds_off(r,s)] = *(const h16x8*)(Ap + (size_t)(row0+r)*K + k0 + s*8);
      }
      // stage B: 128x8 = 1024 -> 4 per thread
      #pragma unroll
      for (int i=0;i<4;i++){
        int c = tid + i*256;
        int r = c >> 3, s = c & 7;
        *(h16x8*)&sB[lds_off(r,s)] = *(const h16x8*)(Wp + (size_t)(col0+r)*K + k0 + s*8);
      }
      __syncthreads();
      #pragma unroll
      for (int ks=0; ks<2; ++ks){
        const int rsel = lane >> 4;
        h16x8 af[2];
        #pragma unroll
        for (int mf=0; mf<2; mf++){
          int r = wr + mf*16 + (lane&15);
          af[mf] = *(const h16x8*)&sA[lds_off(r, ks*4 + rsel)];
        }
        #pragma unroll
        for (int nf=0; nf<4; nf++){
          int cix = wc + nf*16 + (lane&15);
          h16x8 b = *(const h16x8*)&sB[lds_off(cix, ks*4 + rsel)];
          #pragma unroll
          for (int mf=0; mf<2; mf++)
            acc[mf][nf] = __builtin_amdgcn_mfma_f32_16x16x32_f16(af[mf], b, acc[mf][nf], 0,0,0);
        }
      }
    }
  }

  #pragma unroll
  for (int nf=0; nf<4; nf++){
    int colg = col0 + wc + nf*16 + (lane&15);
    float bias = b1[colg] + (b2 ? b2[colg] : 0.f);
    #pragma unroll
    for (int mf=0; mf<2; mf++){
      #pragma unroll
      for (int r=0; r<4; r++){
        int rowg = row0 + wr + mf*16 + (lane>>4)*4 + r;
        if (rowg < NN){
          float o = fmaxf(acc[mf][nf][r] + bias, 0.f);
          if (OUT16) __builtin_nontemporal_store((half_t)o, out16 + (size_t)rowg*ldo + coloff + colg);
          else       __builtin_nontemporal_store(o, outf + (size_t)rowg*ldo + coloff + colg);
        }
      }
    }
  }
}

// ---------------- two-phase mean pool (batch sorted, fp16 input) ----------------
__global__ __launch_bounds__(256)
void pool_partial_kernel(const half_t* __restrict__ xcp, const int* __restrict__ batch,
                         float* __restrict__ sums){
  int r0 = blockIdx.x*128;
  int r1 = r0 + 128; if (r1 > NN) r1 = NN;
  int t = threadIdx.x;
  float run = 0.f;
  int cb = batch[r0];
  for (int r=r0; r<r1; ++r){
    int b = batch[r];
    if (b != cb){ atomicAdd(&sums[cb*256 + t], run); run = 0.f; cb = b; }
    run += (float)xcp[(size_t)r*256 + t];
  }
  atomicAdd(&sums[cb*256 + t], run);
}

__device__ __forceinline__ int lower_bound_i(const int* __restrict__ arr, int n, int v){
  int lo=0, hi=n;
  while (lo < hi){ int mid=(lo+hi)>>1; if (arr[mid] < v) lo=mid+1; else hi=mid; }
  return lo;
}

// ---------------- fused tail: pool_final + seq MLP + head ----------------
__global__ __launch_bounds__(256)
void tail_kernel(const float* __restrict__ sums, const int* __restrict__ batch,
                 const float* __restrict__ seq,
                 const float* __restrict__ fc1W, const float* __restrict__ fc1b,
                 const float* __restrict__ fc2W, const float* __restrict__ fc2b,
                 const float* __restrict__ fccW, const float* __restrict__ fccb,
                 const float* __restrict__ clsW, const float* __restrict__ clsb,
                 float* __restrict__ out){
  __shared__ float h[384], s1[256], sin_[256], lg[16];
  __shared__ float mred, lred;
  int b = blockIdx.x, t = threadIdx.x;
  int lo = lower_bound_i(batch, NN, b);
  int hi = lower_bound_i(batch, NN, b+1);
  h[t] = sums[b*256 + t] / fmaxf((float)(hi-lo), 1.0f);
  sin_[t] = seq[b*256 + t];
  __syncthreads();
  float a = fc1b[t];
  for (int k=0;k<256;k++) a += sin_[k]*fc1W[k*256 + t];
  s1[t] = fmaxf(a, 0.f);
  __syncthreads();
  if (t < 128){
    float a2 = fc2b[t];
    for (int k=0;k<256;k++) a2 += s1[k]*fc2W[k*128 + t];
    h[256 + t] = fmaxf(a2, 0.f);
  }
  __syncthreads();
  float a3 = fccb[t];
  for (int k=0;k<384;k++) a3 += h[k]*fccW[k*256 + t];
  float h2v = fmaxf(a3, 0.f);
  __syncthreads();
  s1[t] = h2v;
  __syncthreads();
  if (t < 16){
    float a4 = clsb[t];
    for (int k=0;k<256;k++) a4 += s1[k]*clsW[k*16 + t];
    lg[t] = a4;
  }
  __syncthreads();
  if (t == 0){
    float m = lg[0];
    for (int i=1;i<16;i++) m = fmaxf(m, lg[i]);
    float s = 0.f;
    for (int i=0;i<16;i++) s += expf(lg[i]-m);
    mred = m; lred = logf(s);
  }
  __syncthreads();
  if (t < 16) out[b*16 + t] = lg[t] - mred - lred;
}

extern "C" void kernel_launch(void* const* d_in, const int* in_sizes, int n_in,
                              void* d_out, int out_size, void* d_ws, size_t ws_size,
                              hipStream_t stream){
  const float* x      = (const float*)d_in[0];
  const int*   ei     = (const int*)  d_in[1];
  const float* ea     = (const float*)d_in[2];
  const int*   batch  = (const int*)  d_in[3];
  const float* dx     = (const float*)d_in[4];
  const int*   dei    = (const int*)  d_in[5];
  const float* dea    = (const float*)d_in[6];
  const float* seq    = (const float*)d_in[7];
  const float* g1_Wr  = (const float*)d_in[8];
  const float* g1_br  = (const float*)d_in[9];
  const float* g1_Wrt = (const float*)d_in[10];
  const float* g2_Wr  = (const float*)d_in[11];
  const float* g2_br  = (const float*)d_in[12];
  const float* g2_Wrt = (const float*)d_in[13];
  const float* d1_Wr  = (const float*)d_in[14];
  const float* d1_br  = (const float*)d_in[15];
  const float* d1_Wrt = (const float*)d_in[16];
  const float* c1_Wr  = (const float*)d_in[17];
  const float* c1_br  = (const float*)d_in[18];
  const float* c1_Wrt = (const float*)d_in[19];
  const float* skip_W = (const float*)d_in[20];
  const float* skip_b = (const float*)d_in[21];
  const float* fc1_W  = (const float*)d_in[22];
  const float* fc1_b  = (const float*)d_in[23];
  const float* fc2_W  = (const float*)d_in[24];
  const float* fc2_b  = (const float*)d_in[25];
  const float* fcc_W  = (const float*)d_in[26];
  const float* fcc_b  = (const float*)d_in[27];
  const float* cls_W  = (const float*)d_in[28];
  const float* cls_b  = (const float*)d_in[29];
  float* out = (float*)d_out;

  char* wp = (char*)d_ws;
  auto alloc = [&](size_t bytes)->char*{
    char* p = wp; wp += (bytes + 255) & ~(size_t)255; return p;
  };
  half_t* XM16 = (half_t*)alloc((size_t)MP*128*2);
  half_t* F116 = (half_t*)alloc((size_t)MP*128*2);
  half_t* DX16 = (half_t*)alloc((size_t)MP*64*2);
  half_t* XC16 = (half_t*)alloc((size_t)MP*256*2);
  half_t* AG16 = (half_t*)alloc((size_t)MP*256*2);
  half_t* XCP  = (half_t*)alloc((size_t)MP*256*2);
  half_t* T1 = (half_t*)alloc(128*128*2);
  half_t* T2 = (half_t*)alloc(128*128*2);
  half_t* T3 = (half_t*)alloc(128*128*2);
  half_t* T4 = (half_t*)alloc(128*128*2);
  half_t* T5 = (half_t*)alloc(64*128*2);
  half_t* T6 = (half_t*)alloc(64*128*2);
  half_t* T7 = (half_t*)alloc(256*256*2);
  half_t* T8 = (half_t*)alloc(256*256*2);
  uint2*    BUF  = (uint2*)alloc((size_t)2*EE*8);
  unsigned* REC  = (unsigned*)alloc((size_t)2*EE*4);
  int* BCNT = (int*)alloc((size_t)2*NBUK*4);
  int* BOFF = (int*)alloc((size_t)(2*NBUK+1)*4);
  int* BCUR = (int*)alloc((size_t)2*NBUK*4);
  int* PTR1 = (int*)alloc((size_t)(NN+1)*4);
  int* PTR2 = (int*)alloc((size_t)(NN+1)*4);
  float* EMBS = (float*)alloc((size_t)BB*256*4);

  const int* src1 = ei;  const int* dst1 = ei + EE;
  const int* src2 = dei; const int* dst2 = dei + EE;

  // ---- multi-split CSR build (both graphs) ----
  hipMemsetAsync(BCNT, 0, (size_t)2*NBUK*4, stream);
  bcount_kernel<<<BBLK,256,0,stream>>>(dst1, dst2, BCNT);
  bscan_kernel<<<1,512,0,stream>>>(BCNT, BOFF, BCUR);
  bscatter_kernel<<<BBLK,256,0,stream>>>(src1,dst1,ea, src2,dst2,dea, BCUR, BUF);
  bfinal_kernel<<<2*NBUK,256,0,stream>>>(BUF, BOFF, REC, PTR1, PTR2);

  // fp16 activations
  tohalf_kernel<true ><<<(NN*16+255)/256,256,0,stream>>>(x,  XM16, NN*16);
  tohalf_kernel<false><<<(NN*8 +255)/256,256,0,stream>>>(dx, DX16, NN*8);

  // weight prep (T8 = c1_Wroot + skip_W)
  {
    TS8 a;
    int base = 0;
    auto put = [&](int idx, const float* W, const float* add, half_t* oh, int K, int N){
      a.t[idx] = TS{W, add, oh, K, N, base}; base += K*N;
    };
    put(0, g1_Wr,  nullptr, T1, 128,128);
    put(1, g1_Wrt, nullptr, T2, 128,128);
    put(2, g2_Wr,  nullptr, T3, 128,128);
    put(3, g2_Wrt, nullptr, T4, 128,128);
    put(4, d1_Wr,  nullptr, T5, 64,128);
    put(5, d1_Wrt, nullptr, T6, 64,128);
    put(6, c1_Wr,  nullptr, T7, 256,256);
    put(7, c1_Wrt, skip_W,  T8, 256,256);
    a.total = base;
    tsplit8_kernel<<<(a.total+255)/256,256,0,stream>>>(a);
  }

  const int GB = (NN+63)/64;   // 782

  // ---- g1 ----
  gather_kernel<128><<<(NN*16+255)/256,256,0,stream>>>(XM16,128, PTR1,REC, AG16,128);
  mfma_gemm_kernel<true><<<dim3(GB,1),256,0,stream>>>(AG16,128, T1, XM16,128, T2,
                                                      g1_br, nullptr, nullptr, F116, 128, 0);
  // ---- g2 ----
  gather_kernel<128><<<(NN*16+255)/256,256,0,stream>>>(F116,128, PTR1,REC, AG16,128);
  mfma_gemm_kernel<true><<<dim3(GB,1),256,0,stream>>>(AG16,128, T3, F116,128, T4,
                                                      g2_br, nullptr, nullptr, XC16, 256, 0);
  // ---- duration branch -> XC cols 128..255 ----
  gather_kernel<64><<<(NN*8+255)/256,256,0,stream>>>(DX16,64, PTR2,REC, AG16,64);
  mfma_gemm_kernel<true><<<dim3(GB,1),256,0,stream>>>(AG16,64, T5, DX16,64, T6,
                                                      d1_br, nullptr, nullptr, XC16, 256, 128);
  // ---- c1 + folded skip ----
  gather_kernel<256><<<(NN*32+255)/256,256,0,stream>>>(XC16,256, PTR1,REC, AG16,256);
  mfma_gemm_kernel<true><<<dim3(GB,2),256,0,stream>>>(AG16,256, T7, XC16,256, T8,
                                                      c1_br, skip_b, nullptr, XCP, 256, 0);
  // ---- pool + tail ----
  hipMemsetAsync(EMBS, 0, (size_t)BB*256*4, stream);
  pool_partial_kernel<<<(NN+127)/128,256,0,stream>>>(XCP, batch, EMBS);
  tail_kernel<<<BB,256,0,stream>>>(EMBS, batch, seq, fc1_W, fc1_b, fc2_W, fc2_b,
                                   fcc_W, fcc_b, cls_W, cls_b, out);
}

// Round 13
// 348.020 us; speedup vs baseline: 1.1827x; 1.1827x over previous
//
#include <hip/hip_runtime.h>

#define NN 50000
#define MP 50176   // row-padded
#define EE 800000
#define BB 64
#define NBUK 256   // buckets per graph
#define NPB 196    // nodes per bucket
#define EPB 4096   // edges per block in bucket passes
#define BBLK ((EE + EPB - 1)/EPB)   // 196 blocks

typedef _Float16 half_t;
typedef __attribute__((ext_vector_type(8))) _Float16 h16x8;
typedef __attribute__((ext_vector_type(4))) float f32x4;

__device__ __forceinline__ int ntld(const int* p){ return __builtin_nontemporal_load(p); }
__device__ __forceinline__ float ntldf(const float* p){ return __builtin_nontemporal_load(p); }

__device__ __forceinline__ unsigned pack_rec(int s, float w){
  union{ _Float16 h; unsigned short u; } c; c.h = (_Float16)w;
  return (unsigned)s | ((unsigned)c.u << 16);
}
__device__ __forceinline__ float rec_w(unsigned r){
  union{ unsigned short u; _Float16 h; } c; c.u = (unsigned short)(r >> 16);
  return (float)c.h;
}

// ---------------- fp32 rows -> fp16 rows (optional -1 masking) ----------------
template<bool MASK>
__global__ __launch_bounds__(256)
void tohalf_kernel(const float* __restrict__ x, half_t* __restrict__ o, int n8){
  int i = blockIdx.x*blockDim.x + threadIdx.x;
  if (i >= n8) return;
  float4 a = ((const float4*)x)[2*i];
  float4 b = ((const float4*)x)[2*i+1];
  float v[8] = {a.x,a.y,a.z,a.w,b.x,b.y,b.z,b.w};
  h16x8 h;
  #pragma unroll
  for (int j=0;j<8;j++){
    float f = v[j];
    if (MASK && f == -1.0f) f = 0.f;
    h[j] = (half_t)f;
  }
  ((h16x8*)o)[i] = h;
}

// ---------------- fused transpose + fp16 convert for all 8 weights ----------------
struct TS { const float* W; const float* add; half_t* oh; int K; int N; int base; };
struct TS8 { TS t[8]; int total; };

__global__ __launch_bounds__(256)
void tsplit8_kernel(TS8 a){
  int i = blockIdx.x*256 + threadIdx.x;
  if (i >= a.total) return;
  int w = 0;
  #pragma unroll
  for (int j=1;j<8;j++) if (i >= a.t[j].base) w = j;
  TS ts = a.t[w];
  int e = i - ts.base;
  int k = e / ts.N, n = e - k*ts.N;
  float v = ts.W[e] + (ts.add ? ts.add[e] : 0.f);
  ts.oh[(size_t)n*ts.K + k] = (half_t)v;
}

// ---------------- multi-split CSR build ----------------
__global__ __launch_bounds__(256)
void bcount_kernel(const int* __restrict__ dst1, const int* __restrict__ dst2,
                   int* __restrict__ bcnt){
  __shared__ int hist[2*NBUK];
  int t = threadIdx.x;
  for (int s=t; s<2*NBUK; s+=256) hist[s]=0;
  __syncthreads();
  int base = blockIdx.x*EPB;
  #pragma unroll 4
  for (int j=0;j<16;j++){
    int i = base + j*256 + t;
    if (i < EE){
      atomicAdd(&hist[ntld(&dst1[i])/NPB], 1);
      atomicAdd(&hist[NBUK + ntld(&dst2[i])/NPB], 1);
    }
  }
  __syncthreads();
  for (int s=t; s<2*NBUK; s+=256){
    int v = hist[s];
    if (v) atomicAdd(&bcnt[s], v);
  }
}

__global__ __launch_bounds__(512)
void bscan_kernel(const int* __restrict__ bcnt, int* __restrict__ boff, int* __restrict__ bcur){
  __shared__ int s[512];
  int t = threadIdx.x;
  int v = bcnt[t];
  s[t]=v; __syncthreads();
  #pragma unroll
  for (int o=1;o<512;o<<=1){ int u=(t>=o)?s[t-o]:0; __syncthreads(); s[t]+=u; __syncthreads(); }
  int ex = s[t]-v;
  boff[t]=ex; bcur[t]=ex;
  if (t==511) boff[512]=s[511];
}

__global__ __launch_bounds__(256)
void bscatter_kernel(const int* __restrict__ src1, const int* __restrict__ dst1, const float* __restrict__ ea,
                     const int* __restrict__ src2, const int* __restrict__ dst2, const float* __restrict__ dea,
                     int* __restrict__ bcur, uint2* __restrict__ buf){
  __shared__ int hist[2*NBUK];
  __shared__ int bas[2*NBUK];
  int t = threadIdx.x;
  for (int s=t; s<2*NBUK; s+=256) hist[s]=0;
  __syncthreads();
  int base = blockIdx.x*EPB;
  #pragma unroll 4
  for (int j=0;j<16;j++){
    int i = base + j*256 + t;
    if (i < EE){
      atomicAdd(&hist[ntld(&dst1[i])/NPB], 1);
      atomicAdd(&hist[NBUK + ntld(&dst2[i])/NPB], 1);
    }
  }
  __syncthreads();
  for (int s=t; s<2*NBUK; s+=256){
    int v = hist[s];
    bas[s] = v ? atomicAdd(&bcur[s], v) : 0;
  }
  __syncthreads();
  for (int s=t; s<2*NBUK; s+=256) hist[s]=0;
  __syncthreads();
  #pragma unroll 4
  for (int j=0;j<16;j++){
    int i = base + j*256 + t;
    if (i < EE){
      {
        int d = ntld(&dst1[i]); int b = d/NPB;
        int p = atomicAdd(&hist[b],1);
        buf[bas[b]+p] = make_uint2(pack_rec(ntld(&src1[i]), ntldf(&ea[i])), (unsigned)d);
      }
      {
        int d = ntld(&dst2[i]); int b = NBUK + d/NPB;
        int p = atomicAdd(&hist[b],1);
        buf[bas[b]+p] = make_uint2(pack_rec(ntld(&src2[i]), ntldf(&dea[i])), (unsigned)d);
      }
    }
  }
}

__global__ __launch_bounds__(256)
void bfinal_kernel(const uint2* __restrict__ buf, const int* __restrict__ boff,
                   unsigned* __restrict__ rec, int* __restrict__ ptr1, int* __restrict__ ptr2){
  __shared__ int cnt[NPB], off[256], cur[NPB];
  int b = blockIdx.x;
  int g = b >> 8, lb = b & 255;
  int n0 = lb*NPB;
  int t = threadIdx.x;
  int seg0 = boff[b], seg1 = boff[b+1];
  int m = seg1 - seg0;
  if (t < NPB){ cnt[t]=0; cur[t]=0; }
  __syncthreads();
  for (int j=t; j<m; j+=256) atomicAdd(&cnt[(int)buf[seg0+j].y - n0], 1);
  __syncthreads();
  int v = (t < NPB) ? cnt[t] : 0;
  off[t] = v; __syncthreads();
  #pragma unroll
  for (int o=1;o<256;o<<=1){ int u=(t>=o)?off[t-o]:0; __syncthreads(); off[t]+=u; __syncthreads(); }
  int ex = off[t]-v;
  __syncthreads();
  off[t] = ex;
  __syncthreads();
  int node = n0 + t;
  if (t < NPB && node <= NN){
    int val = seg0 + off[t];
    if (g==0) ptr1[node]=val; else ptr2[node]=val;
  }
  for (int j=t; j<m; j+=256){
    uint2 r = buf[seg0+j];
    int l = (int)r.y - n0;
    int p = atomicAdd(&cur[l],1);
    rec[seg0 + off[l] + p] = r.x;
  }
}

// ---------------- compact-CSR gather, coalesced recs + shfl, unroll 8 ----------------
template<int F>
__global__ __launch_bounds__(256)
void gather_kernel(const half_t* __restrict__ H, int ldh,
                   const int* __restrict__ ptr, const unsigned* __restrict__ rec,
                   half_t* __restrict__ Oh, int ldo){
  const int L = F/8;
  int gt = blockIdx.x*blockDim.x + threadIdx.x;
  int node = gt / L, lane = gt - node*L;
  if (node >= NN) return;
  int lo = ptr[node], hi = ptr[node+1];
  int k = hi - lo;
  const unsigned* base = rec + lo;
  float acc[8] = {0,0,0,0,0,0,0,0};
  #pragma unroll 1
  for (int j0=0; j0<k; j0+=L){
    unsigned myrec = (j0 + lane < k) ? base[j0 + lane] : 0u;
    int m = k - j0; if (m > L) m = L;
    int i = 0;
    #pragma unroll 1
    for (; i+8 <= m; i += 8){
      unsigned rr[8];
      #pragma unroll
      for (int u=0;u<8;u++) rr[u] = __shfl(myrec, i+u, L);
      h16x8 vv[8];
      #pragma unroll
      for (int u=0;u<8;u++) vv[u] = *(const h16x8*)(H + (size_t)(rr[u] & 0xFFFFu)*ldh + lane*8);
      #pragma unroll
      for (int u=0;u<8;u++){
        float w = rec_w(rr[u]);
        #pragma unroll
        for (int q=0;q<8;q++) acc[q] += w*(float)vv[u][q];
      }
    }
    #pragma unroll 1
    for (; i+4 <= m; i += 4){
      unsigned r0 = __shfl(myrec, i+0, L);
      unsigned r1 = __shfl(myrec, i+1, L);
      unsigned r2 = __shfl(myrec, i+2, L);
      unsigned r3 = __shfl(myrec, i+3, L);
      h16x8 v0 = *(const h16x8*)(H + (size_t)(r0 & 0xFFFFu)*ldh + lane*8);
      h16x8 v1 = *(const h16x8*)(H + (size_t)(r1 & 0xFFFFu)*ldh + lane*8);
      h16x8 v2 = *(const h16x8*)(H + (size_t)(r2 & 0xFFFFu)*ldh + lane*8);
      h16x8 v3 = *(const h16x8*)(H + (size_t)(r3 & 0xFFFFu)*ldh + lane*8);
      float w0 = rec_w(r0), w1 = rec_w(r1), w2 = rec_w(r2), w3 = rec_w(r3);
      #pragma unroll
      for (int q=0;q<8;q++)
        acc[q] += w0*(float)v0[q] + w1*(float)v1[q] + w2*(float)v2[q] + w3*(float)v3[q];
    }
    for (; i < m; ++i){
      unsigned r = __shfl(myrec, i, L);
      h16x8 v = *(const h16x8*)(H + (size_t)(r & 0xFFFFu)*ldh + lane*8);
      float w = rec_w(r);
      #pragma unroll
      for (int q=0;q<8;q++) acc[q] += w*(float)v[q];
    }
  }
  h16x8 oh;
  #pragma unroll
  for (int q=0;q<8;q++) oh[q] = (half_t)acc[q];
  *(h16x8*)(Oh + (size_t)node*ldo + lane*8) = oh;
}

// ---------------- fp16 MFMA dual GEMM, 64x128 tile ----------------
__device__ __forceinline__ int lds_off(int r, int slot){ return r*64 + ((slot ^ (r&7))<<3); }

template<bool OUT16>
__global__ __launch_bounds__(256,3)
void mfma_gemm_kernel(const half_t* __restrict__ A, int K1, const half_t* __restrict__ W1,
                      const half_t* __restrict__ R, int K2, const half_t* __restrict__ W2,
                      const float* __restrict__ b1, const float* __restrict__ b2,
                      float* __restrict__ outf, half_t* __restrict__ out16, int ldo, int coloff){
  __shared__ half_t sA[64*64], sB[128*64];
  const int tid  = threadIdx.x;
  const int lane = tid & 63;
  const int wave = tid >> 6;
  const int wr = (wave>>1)*32, wc = (wave&1)*64;
  const int row0 = blockIdx.x*64;
  const int col0 = blockIdx.y*128;

  f32x4 acc[2][4];
  #pragma unroll
  for (int a=0;a<2;a++)
    #pragma unroll
    for (int b=0;b<4;b++){ acc[a][b][0]=0.f; acc[a][b][1]=0.f; acc[a][b][2]=0.f; acc[a][b][3]=0.f; }

  #pragma unroll 1
  for (int pass=0; pass<2; ++pass){
    const half_t* Ap = pass ? R  : A;
    const half_t* Wp = pass ? W2 : W1;
    const int K = pass ? K2 : K1;
    #pragma unroll 1
    for (int k0=0; k0<K; k0+=64){
      __syncthreads();
      #pragma unroll
      for (int i=0;i<2;i++){
        int c = tid + i*256;
        int r = c >> 3, s = c & 7;
        *(h16x8*)&sA[lds_off(r,s)] = *(const h16x8*)(Ap + (size_t)(row0+r)*K + k0 + s*8);
      }
      #pragma unroll
      for (int i=0;i<4;i++){
        int c = tid + i*256;
        int r = c >> 3, s = c & 7;
        *(h16x8*)&sB[lds_off(r,s)] = *(const h16x8*)(Wp + (size_t)(col0+r)*K + k0 + s*8);
      }
      __syncthreads();
      #pragma unroll
      for (int ks=0; ks<2; ++ks){
        const int rsel = lane >> 4;
        h16x8 af[2];
        #pragma unroll
        for (int mf=0; mf<2; mf++){
          int r = wr + mf*16 + (lane&15);
          af[mf] = *(const h16x8*)&sA[lds_off(r, ks*4 + rsel)];
        }
        #pragma unroll
        for (int nf=0; nf<4; nf++){
          int cix = wc + nf*16 + (lane&15);
          h16x8 b = *(const h16x8*)&sB[lds_off(cix, ks*4 + rsel)];
          #pragma unroll
          for (int mf=0; mf<2; mf++)
            acc[mf][nf] = __builtin_amdgcn_mfma_f32_16x16x32_f16(af[mf], b, acc[mf][nf], 0,0,0);
        }
      }
    }
  }

  #pragma unroll
  for (int nf=0; nf<4; nf++){
    int colg = col0 + wc + nf*16 + (lane&15);
    float bias = b1[colg] + (b2 ? b2[colg] : 0.f);
    #pragma unroll
    for (int mf=0; mf<2; mf++){
      #pragma unroll
      for (int r=0; r<4; r++){
        int rowg = row0 + wr + mf*16 + (lane>>4)*4 + r;
        if (rowg < NN){
          float o = fmaxf(acc[mf][nf][r] + bias, 0.f);
          if (OUT16) out16[(size_t)rowg*ldo + coloff + colg] = (half_t)o;
          else       outf [(size_t)rowg*ldo + coloff + colg] = o;
        }
      }
    }
  }
}

// ---------------- two-phase mean pool (batch sorted, fp16 input, 64-row chunks) ----------------
__global__ __launch_bounds__(256)
void pool_partial_kernel(const half_t* __restrict__ xcp, const int* __restrict__ batch,
                         float* __restrict__ sums){
  int r0 = blockIdx.x*64;
  int r1 = r0 + 64; if (r1 > NN) r1 = NN;
  int t = threadIdx.x;
  float run = 0.f;
  int cb = batch[r0];
  for (int r=r0; r<r1; ++r){
    int b = batch[r];
    if (b != cb){ atomicAdd(&sums[cb*256 + t], run); run = 0.f; cb = b; }
    run += (float)xcp[(size_t)r*256 + t];
  }
  atomicAdd(&sums[cb*256 + t], run);
}

__device__ __forceinline__ int lower_bound_i(const int* __restrict__ arr, int n, int v){
  int lo=0, hi=n;
  while (lo < hi){ int mid=(lo+hi)>>1; if (arr[mid] < v) lo=mid+1; else hi=mid; }
  return lo;
}

// ---------------- fused tail: pool_final + seq MLP + head ----------------
__global__ __launch_bounds__(256)
void tail_kernel(const float* __restrict__ sums, const int* __restrict__ batch,
                 const float* __restrict__ seq,
                 const float* __restrict__ fc1W, const float* __restrict__ fc1b,
                 const float* __restrict__ fc2W, const float* __restrict__ fc2b,
                 const float* __restrict__ fccW, const float* __restrict__ fccb,
                 const float* __restrict__ clsW, const float* __restrict__ clsb,
                 float* __restrict__ out){
  __shared__ float h[384], s1[256], sin_[256], lg[16];
  __shared__ float mred, lred;
  int b = blockIdx.x, t = threadIdx.x;
  int lo = lower_bound_i(batch, NN, b);
  int hi = lower_bound_i(batch, NN, b+1);
  h[t] = sums[b*256 + t] / fmaxf((float)(hi-lo), 1.0f);
  sin_[t] = seq[b*256 + t];
  __syncthreads();
  float a = fc1b[t];
  for (int k=0;k<256;k++) a += sin_[k]*fc1W[k*256 + t];
  s1[t] = fmaxf(a, 0.f);
  __syncthreads();
  if (t < 128){
    float a2 = fc2b[t];
    for (int k=0;k<256;k++) a2 += s1[k]*fc2W[k*128 + t];
    h[256 + t] = fmaxf(a2, 0.f);
  }
  __syncthreads();
  float a3 = fccb[t];
  for (int k=0;k<384;k++) a3 += h[k]*fccW[k*256 + t];
  float h2v = fmaxf(a3, 0.f);
  __syncthreads();
  s1[t] = h2v;
  __syncthreads();
  if (t < 16){
    float a4 = clsb[t];
    for (int k=0;k<256;k++) a4 += s1[k]*clsW[k*16 + t];
    lg[t] = a4;
  }
  __syncthreads();
  if (t == 0){
    float m = lg[0];
    for (int i=1;i<16;i++) m = fmaxf(m, lg[i]);
    float s = 0.f;
    for (int i=0;i<16;i++) s += expf(lg[i]-m);
    mred = m; lred = logf(s);
  }
  __syncthreads();
  if (t < 16) out[b*16 + t] = lg[t] - mred - lred;
}

extern "C" void kernel_launch(void* const* d_in, const int* in_sizes, int n_in,
                              void* d_out, int out_size, void* d_ws, size_t ws_size,
                              hipStream_t stream){
  const float* x      = (const float*)d_in[0];
  const int*   ei     = (const int*)  d_in[1];
  const float* ea     = (const float*)d_in[2];
  const int*   batch  = (const int*)  d_in[3];
  const float* dx     = (const float*)d_in[4];
  const int*   dei    = (const int*)  d_in[5];
  const float* dea    = (const float*)d_in[6];
  const float* seq    = (const float*)d_in[7];
  const float* g1_Wr  = (const float*)d_in[8];
  const float* g1_br  = (const float*)d_in[9];
  const float* g1_Wrt = (const float*)d_in[10];
  const float* g2_Wr  = (const float*)d_in[11];
  const float* g2_br  = (const float*)d_in[12];
  const float* g2_Wrt = (const float*)d_in[13];
  const float* d1_Wr  = (const float*)d_in[14];
  const float* d1_br  = (const float*)d_in[15];
  const float* d1_Wrt = (const float*)d_in[16];
  const float* c1_Wr  = (const float*)d_in[17];
  const float* c1_br  = (const float*)d_in[18];
  const float* c1_Wrt = (const float*)d_in[19];
  const float* skip_W = (const float*)d_in[20];
  const float* skip_b = (const float*)d_in[21];
  const float* fc1_W  = (const float*)d_in[22];
  const float* fc1_b  = (const float*)d_in[23];
  const float* fc2_W  = (const float*)d_in[24];
  const float* fc2_b  = (const float*)d_in[25];
  const float* fcc_W  = (const float*)d_in[26];
  const float* fcc_b  = (const float*)d_in[27];
  const float* cls_W  = (const float*)d_in[28];
  const float* cls_b  = (const float*)d_in[29];
  float* out = (float*)d_out;

  char* wp = (char*)d_ws;
  auto alloc = [&](size_t bytes)->char*{
    char* p = wp; wp += (bytes + 255) & ~(size_t)255; return p;
  };
  half_t* XM16 = (half_t*)alloc((size_t)MP*128*2);
  half_t* F116 = (half_t*)alloc((size_t)MP*128*2);
  half_t* DX16 = (half_t*)alloc((size_t)MP*64*2);
  half_t* XC16 = (half_t*)alloc((size_t)MP*256*2);
  half_t* AG16 = (half_t*)alloc((size_t)MP*256*2);
  half_t* XCP  = (half_t*)alloc((size_t)MP*256*2);
  half_t* T1 = (half_t*)alloc(128*128*2);
  half_t* T2 = (half_t*)alloc(128*128*2);
  half_t* T3 = (half_t*)alloc(128*128*2);
  half_t* T4 = (half_t*)alloc(128*128*2);
  half_t* T5 = (half_t*)alloc(64*128*2);
  half_t* T6 = (half_t*)alloc(64*128*2);
  half_t* T7 = (half_t*)alloc(256*256*2);
  half_t* T8 = (half_t*)alloc(256*256*2);
  uint2*    BUF  = (uint2*)alloc((size_t)2*EE*8);
  unsigned* REC  = (unsigned*)alloc((size_t)2*EE*4);
  int* BCNT = (int*)alloc((size_t)2*NBUK*4);
  int* BOFF = (int*)alloc((size_t)(2*NBUK+1)*4);
  int* BCUR = (int*)alloc((size_t)2*NBUK*4);
  int* PTR1 = (int*)alloc((size_t)(NN+1)*4);
  int* PTR2 = (int*)alloc((size_t)(NN+1)*4);
  float* EMBS = (float*)alloc((size_t)BB*256*4);

  const int* src1 = ei;  const int* dst1 = ei + EE;
  const int* src2 = dei; const int* dst2 = dei + EE;

  // ---- multi-split CSR build (both graphs) ----
  hipMemsetAsync(BCNT, 0, (size_t)2*NBUK*4, stream);
  bcount_kernel<<<BBLK,256,0,stream>>>(dst1, dst2, BCNT);
  bscan_kernel<<<1,512,0,stream>>>(BCNT, BOFF, BCUR);
  bscatter_kernel<<<BBLK,256,0,stream>>>(src1,dst1,ea, src2,dst2,dea, BCUR, BUF);
  bfinal_kernel<<<2*NBUK,256,0,stream>>>(BUF, BOFF, REC, PTR1, PTR2);

  // fp16 activations
  tohalf_kernel<true ><<<(NN*16+255)/256,256,0,stream>>>(x,  XM16, NN*16);
  tohalf_kernel<false><<<(NN*8 +255)/256,256,0,stream>>>(dx, DX16, NN*8);

  // weight prep (T8 = c1_Wroot + skip_W)
  {
    TS8 a;
    int base = 0;
    auto put = [&](int idx, const float* W, const float* add, half_t* oh, int K, int N){
      a.t[idx] = TS{W, add, oh, K, N, base}; base += K*N;
    };
    put(0, g1_Wr,  nullptr, T1, 128,128);
    put(1, g1_Wrt, nullptr, T2, 128,128);
    put(2, g2_Wr,  nullptr, T3, 128,128);
    put(3, g2_Wrt, nullptr, T4, 128,128);
    put(4, d1_Wr,  nullptr, T5, 64,128);
    put(5, d1_Wrt, nullptr, T6, 64,128);
    put(6, c1_Wr,  nullptr, T7, 256,256);
    put(7, c1_Wrt, skip_W,  T8, 256,256);
    a.total = base;
    tsplit8_kernel<<<(a.total+255)/256,256,0,stream>>>(a);
  }

  const int GB = (NN+63)/64;   // 782

  // ---- g1 ----
  gather_kernel<128><<<(NN*16+255)/256,256,0,stream>>>(XM16,128, PTR1,REC, AG16,128);
  mfma_gemm_kernel<true><<<dim3(GB,1),256,0,stream>>>(AG16,128, T1, XM16,128, T2,
                                                      g1_br, nullptr, nullptr, F116, 128, 0);
  // ---- g2 ----
  gather_kernel<128><<<(NN*16+255)/256,256,0,stream>>>(F116,128, PTR1,REC, AG16,128);
  mfma_gemm_kernel<true><<<dim3(GB,1),256,0,stream>>>(AG16,128, T3, F116,128, T4,
                                                      g2_br, nullptr, nullptr, XC16, 256, 0);
  // ---- duration branch -> XC cols 128..255 ----
  gather_kernel<64><<<(NN*8+255)/256,256,0,stream>>>(DX16,64, PTR2,REC, AG16,64);
  mfma_gemm_kernel<true><<<dim3(GB,1),256,0,stream>>>(AG16,64, T5, DX16,64, T6,
                                                      d1_br, nullptr, nullptr, XC16, 256, 128);
  // ---- c1 + folded skip ----
  gather_kernel<256><<<(NN*32+255)/256,256,0,stream>>>(XC16,256, PTR1,REC, AG16,256);
  mfma_gemm_kernel<true><<<dim3(GB,2),256,0,stream>>>(AG16,256, T7, XC16,256, T8,
                                                      c1_br, skip_b, nullptr, XCP, 256, 0);
  // ---- pool + tail ----
  hipMemsetAsync(EMBS, 0, (size_t)BB*256*4, stream);
  pool_partial_kernel<<<(NN+63)/64,256,0,stream>>>(XCP, batch, EMBS);
  tail_kernel<<<BB,256,0,stream>>>(EMBS, batch, seq, fc1_W, fc1_b, fc2_W, fc2_b,
                                   fcc_W, fcc_b, cls_W, cls_b, out);
}

// Round 14
// 304.502 us; speedup vs baseline: 1.3517x; 1.1429x over previous
//
#include <hip/hip_runtime.h>

#define NN 50000
#define MP 50176   // row-padded
#define EE 800000
#define BB 64
#define NBUK 256   // buckets per graph
#define NPB 196    // nodes per bucket
#define EPB 4096   // edges per block in bucket passes
#define BBLK ((EE + EPB - 1)/EPB)   // 196 blocks

typedef _Float16 half_t;
typedef __attribute__((ext_vector_type(8))) _Float16 h16x8;
typedef __attribute__((ext_vector_type(4))) float f32x4;
typedef __attribute__((ext_vector_type(2))) float f32x2;

__device__ __forceinline__ int ntld(const int* p){ return __builtin_nontemporal_load(p); }
__device__ __forceinline__ float ntldf(const float* p){ return __builtin_nontemporal_load(p); }

__device__ __forceinline__ unsigned pack_rec(int s, float w){
  union{ _Float16 h; unsigned short u; } c; c.h = (_Float16)w;
  return (unsigned)s | ((unsigned)c.u << 16);
}
__device__ __forceinline__ float rec_w(unsigned r){
  union{ unsigned short u; _Float16 h; } c; c.u = (unsigned short)(r >> 16);
  return (float)c.h;
}

// ---- fp8 e4m3 helpers (HW cvt) ----
__device__ __forceinline__ unsigned pack4_fp8(float f0, float f1, float f2, float f3){
  int r = __builtin_amdgcn_cvt_pk_fp8_f32(f0, f1, 0, false);
  r = __builtin_amdgcn_cvt_pk_fp8_f32(f2, f3, r, true);
  return (unsigned)r;
}
__device__ __forceinline__ unsigned char to_fp8(float f){
  return (unsigned char)(__builtin_amdgcn_cvt_pk_fp8_f32(f, 0.f, 0, false) & 0xff);
}
__device__ __forceinline__ void fp8x8_to_f32(uint2 u, float* f){
  f32x2 a = __builtin_amdgcn_cvt_pk_f32_fp8(u.x, false);
  f32x2 b = __builtin_amdgcn_cvt_pk_f32_fp8(u.x, true);
  f32x2 c = __builtin_amdgcn_cvt_pk_f32_fp8(u.y, false);
  f32x2 d = __builtin_amdgcn_cvt_pk_f32_fp8(u.y, true);
  f[0]=a[0]; f[1]=a[1]; f[2]=b[0]; f[3]=b[1];
  f[4]=c[0]; f[5]=c[1]; f[6]=d[0]; f[7]=d[1];
}

// ---------------- fp32 rows -> fp16 + fp8 rows (optional -1 masking) ----------------
template<bool MASK>
__global__ __launch_bounds__(256)
void tohalf_kernel(const float* __restrict__ x, half_t* __restrict__ o16,
                   unsigned char* __restrict__ o8, int n8){
  int i = blockIdx.x*blockDim.x + threadIdx.x;
  if (i >= n8) return;
  float4 a = ((const float4*)x)[2*i];
  float4 b = ((const float4*)x)[2*i+1];
  float v[8] = {a.x,a.y,a.z,a.w,b.x,b.y,b.z,b.w};
  h16x8 h;
  #pragma unroll
  for (int j=0;j<8;j++){
    float f = v[j];
    if (MASK && f == -1.0f) f = 0.f;
    v[j] = f;
    h[j] = (half_t)f;
  }
  ((h16x8*)o16)[i] = h;
  ((uint2*)o8)[i] = make_uint2(pack4_fp8(v[0],v[1],v[2],v[3]), pack4_fp8(v[4],v[5],v[6],v[7]));
}

// ---------------- fused transpose + fp16 convert for all 8 weights ----------------
struct TS { const float* W; const float* add; half_t* oh; int K; int N; int base; };
struct TS8 { TS t[8]; int total; };

__global__ __launch_bounds__(256)
void tsplit8_kernel(TS8 a){
  int i = blockIdx.x*256 + threadIdx.x;
  if (i >= a.total) return;
  int w = 0;
  #pragma unroll
  for (int j=1;j<8;j++) if (i >= a.t[j].base) w = j;
  TS ts = a.t[w];
  int e = i - ts.base;
  int k = e / ts.N, n = e - k*ts.N;
  float v = ts.W[e] + (ts.add ? ts.add[e] : 0.f);
  ts.oh[(size_t)n*ts.K + k] = (half_t)v;
}

// ---------------- multi-split CSR build ----------------
__global__ __launch_bounds__(256)
void bcount_kernel(const int* __restrict__ dst1, const int* __restrict__ dst2,
                   int* __restrict__ bcnt){
  __shared__ int hist[2*NBUK];
  int t = threadIdx.x;
  for (int s=t; s<2*NBUK; s+=256) hist[s]=0;
  __syncthreads();
  int base = blockIdx.x*EPB;
  #pragma unroll 4
  for (int j=0;j<16;j++){
    int i = base + j*256 + t;
    if (i < EE){
      atomicAdd(&hist[ntld(&dst1[i])/NPB], 1);
      atomicAdd(&hist[NBUK + ntld(&dst2[i])/NPB], 1);
    }
  }
  __syncthreads();
  for (int s=t; s<2*NBUK; s+=256){
    int v = hist[s];
    if (v) atomicAdd(&bcnt[s], v);
  }
}

__global__ __launch_bounds__(512)
void bscan_kernel(const int* __restrict__ bcnt, int* __restrict__ boff, int* __restrict__ bcur){
  __shared__ int s[512];
  int t = threadIdx.x;
  int v = bcnt[t];
  s[t]=v; __syncthreads();
  #pragma unroll
  for (int o=1;o<512;o<<=1){ int u=(t>=o)?s[t-o]:0; __syncthreads(); s[t]+=u; __syncthreads(); }
  int ex = s[t]-v;
  boff[t]=ex; bcur[t]=ex;
  if (t==511) boff[512]=s[511];
}

__global__ __launch_bounds__(256)
void bscatter_kernel(const int* __restrict__ src1, const int* __restrict__ dst1, const float* __restrict__ ea,
                     const int* __restrict__ src2, const int* __restrict__ dst2, const float* __restrict__ dea,
                     int* __restrict__ bcur, uint2* __restrict__ buf){
  __shared__ int hist[2*NBUK];
  __shared__ int bas[2*NBUK];
  int t = threadIdx.x;
  for (int s=t; s<2*NBUK; s+=256) hist[s]=0;
  __syncthreads();
  int base = blockIdx.x*EPB;
  #pragma unroll 4
  for (int j=0;j<16;j++){
    int i = base + j*256 + t;
    if (i < EE){
      atomicAdd(&hist[ntld(&dst1[i])/NPB], 1);
      atomicAdd(&hist[NBUK + ntld(&dst2[i])/NPB], 1);
    }
  }
  __syncthreads();
  for (int s=t; s<2*NBUK; s+=256){
    int v = hist[s];
    bas[s] = v ? atomicAdd(&bcur[s], v) : 0;
  }
  __syncthreads();
  for (int s=t; s<2*NBUK; s+=256) hist[s]=0;
  __syncthreads();
  #pragma unroll 4
  for (int j=0;j<16;j++){
    int i = base + j*256 + t;
    if (i < EE){
      {
        int d = ntld(&dst1[i]); int b = d/NPB;
        int p = atomicAdd(&hist[b],1);
        buf[bas[b]+p] = make_uint2(pack_rec(ntld(&src1[i]), ntldf(&ea[i])), (unsigned)d);
      }
      {
        int d = ntld(&dst2[i]); int b = NBUK + d/NPB;
        int p = atomicAdd(&hist[b],1);
        buf[bas[b]+p] = make_uint2(pack_rec(ntld(&src2[i]), ntldf(&dea[i])), (unsigned)d);
      }
    }
  }
}

__global__ __launch_bounds__(256)
void bfinal_kernel(const uint2* __restrict__ buf, const int* __restrict__ boff,
                   unsigned* __restrict__ rec, int* __restrict__ ptr1, int* __restrict__ ptr2){
  __shared__ int cnt[NPB], off[256], cur[NPB];
  int b = blockIdx.x;
  int g = b >> 8, lb = b & 255;
  int n0 = lb*NPB;
  int t = threadIdx.x;
  int seg0 = boff[b], seg1 = boff[b+1];
  int m = seg1 - seg0;
  if (t < NPB){ cnt[t]=0; cur[t]=0; }
  __syncthreads();
  for (int j=t; j<m; j+=256) atomicAdd(&cnt[(int)buf[seg0+j].y - n0], 1);
  __syncthreads();
  int v = (t < NPB) ? cnt[t] : 0;
  off[t] = v; __syncthreads();
  #pragma unroll
  for (int o=1;o<256;o<<=1){ int u=(t>=o)?off[t-o]:0; __syncthreads(); off[t]+=u; __syncthreads(); }
  int ex = off[t]-v;
  __syncthreads();
  off[t] = ex;
  __syncthreads();
  int node = n0 + t;
  if (t < NPB && node <= NN){
    int val = seg0 + off[t];
    if (g==0) ptr1[node]=val; else ptr2[node]=val;
  }
  for (int j=t; j<m; j+=256){
    uint2 r = buf[seg0+j];
    int l = (int)r.y - n0;
    int p = atomicAdd(&cur[l],1);
    rec[seg0 + off[l] + p] = r.x;
  }
}

// ---------------- compact-CSR gather over fp8 rows, fp16 out ----------------
template<int F>
__global__ __launch_bounds__(256)
void gather_kernel(const unsigned char* __restrict__ H, int ldh,
                   const int* __restrict__ ptr, const unsigned* __restrict__ rec,
                   half_t* __restrict__ Oh, int ldo){
  const int L = F/8;
  int gt = blockIdx.x*blockDim.x + threadIdx.x;
  int node = gt / L, lane = gt - node*L;
  if (node >= NN) return;
  int lo = ptr[node], hi = ptr[node+1];
  int k = hi - lo;
  const unsigned* base = rec + lo;
  float acc[8] = {0,0,0,0,0,0,0,0};
  #pragma unroll 1
  for (int j0=0; j0<k; j0+=L){
    unsigned myrec = (j0 + lane < k) ? base[j0 + lane] : 0u;
    int m = k - j0; if (m > L) m = L;
    int i = 0;
    #pragma unroll 1
    for (; i+8 <= m; i += 8){
      unsigned rr[8];
      #pragma unroll
      for (int u=0;u<8;u++) rr[u] = __shfl(myrec, i+u, L);
      uint2 vv[8];
      #pragma unroll
      for (int u=0;u<8;u++) vv[u] = *(const uint2*)(H + (size_t)(rr[u] & 0xFFFFu)*ldh + lane*8);
      #pragma unroll
      for (int u=0;u<8;u++){
        float f[8]; fp8x8_to_f32(vv[u], f);
        float w = rec_w(rr[u]);
        #pragma unroll
        for (int q=0;q<8;q++) acc[q] += w*f[q];
      }
    }
    #pragma unroll 1
    for (; i+4 <= m; i += 4){
      unsigned r0 = __shfl(myrec, i+0, L);
      unsigned r1 = __shfl(myrec, i+1, L);
      unsigned r2 = __shfl(myrec, i+2, L);
      unsigned r3 = __shfl(myrec, i+3, L);
      uint2 v0 = *(const uint2*)(H + (size_t)(r0 & 0xFFFFu)*ldh + lane*8);
      uint2 v1 = *(const uint2*)(H + (size_t)(r1 & 0xFFFFu)*ldh + lane*8);
      uint2 v2 = *(const uint2*)(H + (size_t)(r2 & 0xFFFFu)*ldh + lane*8);
      uint2 v3 = *(const uint2*)(H + (size_t)(r3 & 0xFFFFu)*ldh + lane*8);
      float f0[8], f1[8], f2[8], f3[8];
      fp8x8_to_f32(v0, f0); fp8x8_to_f32(v1, f1);
      fp8x8_to_f32(v2, f2); fp8x8_to_f32(v3, f3);
      float w0 = rec_w(r0), w1 = rec_w(r1), w2 = rec_w(r2), w3 = rec_w(r3);
      #pragma unroll
      for (int q=0;q<8;q++)
        acc[q] += w0*f0[q] + w1*f1[q] + w2*f2[q] + w3*f3[q];
    }
    for (; i < m; ++i){
      unsigned r = __shfl(myrec, i, L);
      uint2 v = *(const uint2*)(H + (size_t)(r & 0xFFFFu)*ldh + lane*8);
      float f[8]; fp8x8_to_f32(v, f);
      float w = rec_w(r);
      #pragma unroll
      for (int q=0;q<8;q++) acc[q] += w*f[q];
    }
  }
  h16x8 oh;
  #pragma unroll
  for (int q=0;q<8;q++) oh[q] = (half_t)acc[q];
  *(h16x8*)(Oh + (size_t)node*ldo + lane*8) = oh;
}

// ---------------- fp16 MFMA dual GEMM, 64x128 tile, fp16 + optional fp8 out ----------------
__device__ __forceinline__ int lds_off(int r, int slot){ return r*64 + ((slot ^ (r&7))<<3); }

template<bool OUT8>
__global__ __launch_bounds__(256,3)
void mfma_gemm_kernel(const half_t* __restrict__ A, int K1, const half_t* __restrict__ W1,
                      const half_t* __restrict__ R, int K2, const half_t* __restrict__ W2,
                      const float* __restrict__ b1, const float* __restrict__ b2,
                      half_t* __restrict__ out16, unsigned char* __restrict__ out8,
                      int ldo, int coloff){
  __shared__ half_t sA[64*64], sB[128*64];
  const int tid  = threadIdx.x;
  const int lane = tid & 63;
  const int wave = tid >> 6;
  const int wr = (wave>>1)*32, wc = (wave&1)*64;
  const int row0 = blockIdx.x*64;
  const int col0 = blockIdx.y*128;

  f32x4 acc[2][4];
  #pragma unroll
  for (int a=0;a<2;a++)
    #pragma unroll
    for (int b=0;b<4;b++){ acc[a][b][0]=0.f; acc[a][b][1]=0.f; acc[a][b][2]=0.f; acc[a][b][3]=0.f; }

  #pragma unroll 1
  for (int pass=0; pass<2; ++pass){
    const half_t* Ap = pass ? R  : A;
    const half_t* Wp = pass ? W2 : W1;
    const int K = pass ? K2 : K1;
    #pragma unroll 1
    for (int k0=0; k0<K; k0+=64){
      __syncthreads();
      #pragma unroll
      for (int i=0;i<2;i++){
        int c = tid + i*256;
        int r = c >> 3, s = c & 7;
        *(h16x8*)&sA[lds_off(r,s)] = *(const h16x8*)(Ap + (size_t)(row0+r)*K + k0 + s*8);
      }
      #pragma unroll
      for (int i=0;i<4;i++){
        int c = tid + i*256;
        int r = c >> 3, s = c & 7;
        *(h16x8*)&sB[lds_off(r,s)] = *(const h16x8*)(Wp + (size_t)(col0+r)*K + k0 + s*8);
      }
      __syncthreads();
      #pragma unroll
      for (int ks=0; ks<2; ++ks){
        const int rsel = lane >> 4;
        h16x8 af[2];
        #pragma unroll
        for (int mf=0; mf<2; mf++){
          int r = wr + mf*16 + (lane&15);
          af[mf] = *(const h16x8*)&sA[lds_off(r, ks*4 + rsel)];
        }
        #pragma unroll
        for (int nf=0; nf<4; nf++){
          int cix = wc + nf*16 + (lane&15);
          h16x8 b = *(const h16x8*)&sB[lds_off(cix, ks*4 + rsel)];
          #pragma unroll
          for (int mf=0; mf<2; mf++)
            acc[mf][nf] = __builtin_amdgcn_mfma_f32_16x16x32_f16(af[mf], b, acc[mf][nf], 0,0,0);
        }
      }
    }
  }

  #pragma unroll
  for (int nf=0; nf<4; nf++){
    int colg = col0 + wc + nf*16 + (lane&15);
    float bias = b1[colg] + (b2 ? b2[colg] : 0.f);
    #pragma unroll
    for (int mf=0; mf<2; mf++){
      #pragma unroll
      for (int r=0; r<4; r++){
        int rowg = row0 + wr + mf*16 + (lane>>4)*4 + r;
        if (rowg < NN){
          float o = fmaxf(acc[mf][nf][r] + bias, 0.f);
          size_t idx = (size_t)rowg*ldo + coloff + colg;
          out16[idx] = (half_t)o;
          if (OUT8) out8[idx] = to_fp8(o);
        }
      }
    }
  }
}

// ---------------- two-phase mean pool (batch sorted, fp16 input, 64-row chunks) ----------------
__global__ __launch_bounds__(256)
void pool_partial_kernel(const half_t* __restrict__ xcp, const int* __restrict__ batch,
                         float* __restrict__ sums){
  int r0 = blockIdx.x*64;
  int r1 = r0 + 64; if (r1 > NN) r1 = NN;
  int t = threadIdx.x;
  float run = 0.f;
  int cb = batch[r0];
  for (int r=r0; r<r1; ++r){
    int b = batch[r];
    if (b != cb){ atomicAdd(&sums[cb*256 + t], run); run = 0.f; cb = b; }
    run += (float)xcp[(size_t)r*256 + t];
  }
  atomicAdd(&sums[cb*256 + t], run);
}

__device__ __forceinline__ int lower_bound_i(const int* __restrict__ arr, int n, int v){
  int lo=0, hi=n;
  while (lo < hi){ int mid=(lo+hi)>>1; if (arr[mid] < v) lo=mid+1; else hi=mid; }
  return lo;
}

// ---------------- fused tail: pool_final + seq MLP + head ----------------
__global__ __launch_bounds__(256)
void tail_kernel(const float* __restrict__ sums, const int* __restrict__ batch,
                 const float* __restrict__ seq,
                 const float* __restrict__ fc1W, const float* __restrict__ fc1b,
                 const float* __restrict__ fc2W, const float* __restrict__ fc2b,
                 const float* __restrict__ fccW, const float* __restrict__ fccb,
                 const float* __restrict__ clsW, const float* __restrict__ clsb,
                 float* __restrict__ out){
  __shared__ float h[384], s1[256], sin_[256], lg[16];
  __shared__ float mred, lred;
  int b = blockIdx.x, t = threadIdx.x;
  int lo = lower_bound_i(batch, NN, b);
  int hi = lower_bound_i(batch, NN, b+1);
  h[t] = sums[b*256 + t] / fmaxf((float)(hi-lo), 1.0f);
  sin_[t] = seq[b*256 + t];
  __syncthreads();
  float a = fc1b[t];
  for (int k=0;k<256;k++) a += sin_[k]*fc1W[k*256 + t];
  s1[t] = fmaxf(a, 0.f);
  __syncthreads();
  if (t < 128){
    float a2 = fc2b[t];
    for (int k=0;k<256;k++) a2 += s1[k]*fc2W[k*128 + t];
    h[256 + t] = fmaxf(a2, 0.f);
  }
  __syncthreads();
  float a3 = fccb[t];
  for (int k=0;k<384;k++) a3 += h[k]*fccW[k*256 + t];
  float h2v = fmaxf(a3, 0.f);
  __syncthreads();
  s1[t] = h2v;
  __syncthreads();
  if (t < 16){
    float a4 = clsb[t];
    for (int k=0;k<256;k++) a4 += s1[k]*clsW[k*16 + t];
    lg[t] = a4;
  }
  __syncthreads();
  if (t == 0){
    float m = lg[0];
    for (int i=1;i<16;i++) m = fmaxf(m, lg[i]);
    float s = 0.f;
    for (int i=0;i<16;i++) s += expf(lg[i]-m);
    mred = m; lred = logf(s);
  }
  __syncthreads();
  if (t < 16) out[b*16 + t] = lg[t] - mred - lred;
}

extern "C" void kernel_launch(void* const* d_in, const int* in_sizes, int n_in,
                              void* d_out, int out_size, void* d_ws, size_t ws_size,
                              hipStream_t stream){
  const float* x      = (const float*)d_in[0];
  const int*   ei     = (const int*)  d_in[1];
  const float* ea     = (const float*)d_in[2];
  const int*   batch  = (const int*)  d_in[3];
  const float* dx     = (const float*)d_in[4];
  const int*   dei    = (const int*)  d_in[5];
  const float* dea    = (const float*)d_in[6];
  const float* seq    = (const float*)d_in[7];
  const float* g1_Wr  = (const float*)d_in[8];
  const float* g1_br  = (const float*)d_in[9];
  const float* g1_Wrt = (const float*)d_in[10];
  const float* g2_Wr  = (const float*)d_in[11];
  const float* g2_br  = (const float*)d_in[12];
  const float* g2_Wrt = (const float*)d_in[13];
  const float* d1_Wr  = (const float*)d_in[14];
  const float* d1_br  = (const float*)d_in[15];
  const float* d1_Wrt = (const float*)d_in[16];
  const float* c1_Wr  = (const float*)d_in[17];
  const float* c1_br  = (const float*)d_in[18];
  const float* c1_Wrt = (const float*)d_in[19];
  const float* skip_W = (const float*)d_in[20];
  const float* skip_b = (const float*)d_in[21];
  const float* fc1_W  = (const float*)d_in[22];
  const float* fc1_b  = (const float*)d_in[23];
  const float* fc2_W  = (const float*)d_in[24];
  const float* fc2_b  = (const float*)d_in[25];
  const float* fcc_W  = (const float*)d_in[26];
  const float* fcc_b  = (const float*)d_in[27];
  const float* cls_W  = (const float*)d_in[28];
  const float* cls_b  = (const float*)d_in[29];
  float* out = (float*)d_out;

  char* wp = (char*)d_ws;
  auto alloc = [&](size_t bytes)->char*{
    char* p = wp; wp += (bytes + 255) & ~(size_t)255; return p;
  };
  half_t* XM16 = (half_t*)alloc((size_t)MP*128*2);
  half_t* F116 = (half_t*)alloc((size_t)MP*128*2);
  half_t* DX16 = (half_t*)alloc((size_t)MP*64*2);
  half_t* XC16 = (half_t*)alloc((size_t)MP*256*2);
  half_t* AG16 = (half_t*)alloc((size_t)MP*256*2);
  half_t* XCP  = (half_t*)alloc((size_t)MP*256*2);
  unsigned char* XM8 = (unsigned char*)alloc((size_t)MP*128);
  unsigned char* F18 = (unsigned char*)alloc((size_t)MP*128);
  unsigned char* DX8 = (unsigned char*)alloc((size_t)MP*64);
  unsigned char* XC8 = (unsigned char*)alloc((size_t)MP*256);
  half_t* T1 = (half_t*)alloc(128*128*2);
  half_t* T2 = (half_t*)alloc(128*128*2);
  half_t* T3 = (half_t*)alloc(128*128*2);
  half_t* T4 = (half_t*)alloc(128*128*2);
  half_t* T5 = (half_t*)alloc(64*128*2);
  half_t* T6 = (half_t*)alloc(64*128*2);
  half_t* T7 = (half_t*)alloc(256*256*2);
  half_t* T8 = (half_t*)alloc(256*256*2);
  uint2*    BUF  = (uint2*)alloc((size_t)2*EE*8);
  unsigned* REC  = (unsigned*)alloc((size_t)2*EE*4);
  int* BCNT = (int*)alloc((size_t)2*NBUK*4);
  int* BOFF = (int*)alloc((size_t)(2*NBUK+1)*4);
  int* BCUR = (int*)alloc((size_t)2*NBUK*4);
  int* PTR1 = (int*)alloc((size_t)(NN+1)*4);
  int* PTR2 = (int*)alloc((size_t)(NN+1)*4);
  float* EMBS = (float*)alloc((size_t)BB*256*4);

  const int* src1 = ei;  const int* dst1 = ei + EE;
  const int* src2 = dei; const int* dst2 = dei + EE;

  // ---- multi-split CSR build (both graphs) ----
  hipMemsetAsync(BCNT, 0, (size_t)2*NBUK*4, stream);
  bcount_kernel<<<BBLK,256,0,stream>>>(dst1, dst2, BCNT);
  bscan_kernel<<<1,512,0,stream>>>(BCNT, BOFF, BCUR);
  bscatter_kernel<<<BBLK,256,0,stream>>>(src1,dst1,ea, src2,dst2,dea, BCUR, BUF);
  bfinal_kernel<<<2*NBUK,256,0,stream>>>(BUF, BOFF, REC, PTR1, PTR2);

  // fp16+fp8 activations
  tohalf_kernel<true ><<<(NN*16+255)/256,256,0,stream>>>(x,  XM16, XM8, NN*16);
  tohalf_kernel<false><<<(NN*8 +255)/256,256,0,stream>>>(dx, DX16, DX8, NN*8);

  // weight prep (T8 = c1_Wroot + skip_W)
  {
    TS8 a;
    int base = 0;
    auto put = [&](int idx, const float* W, const float* add, half_t* oh, int K, int N){
      a.t[idx] = TS{W, add, oh, K, N, base}; base += K*N;
    };
    put(0, g1_Wr,  nullptr, T1, 128,128);
    put(1, g1_Wrt, nullptr, T2, 128,128);
    put(2, g2_Wr,  nullptr, T3, 128,128);
    put(3, g2_Wrt, nullptr, T4, 128,128);
    put(4, d1_Wr,  nullptr, T5, 64,128);
    put(5, d1_Wrt, nullptr, T6, 64,128);
    put(6, c1_Wr,  nullptr, T7, 256,256);
    put(7, c1_Wrt, skip_W,  T8, 256,256);
    a.total = base;
    tsplit8_kernel<<<(a.total+255)/256,256,0,stream>>>(a);
  }

  const int GB = (NN+63)/64;   // 782

  // ---- g1 ----
  gather_kernel<128><<<(NN*16+255)/256,256,0,stream>>>(XM8,128, PTR1,REC, AG16,128);
  mfma_gemm_kernel<true><<<dim3(GB,1),256,0,stream>>>(AG16,128, T1, XM16,128, T2,
                                                      g1_br, nullptr, F116, F18, 128, 0);
  // ---- g2 ----
  gather_kernel<128><<<(NN*16+255)/256,256,0,stream>>>(F18,128, PTR1,REC, AG16,128);
  mfma_gemm_kernel<true><<<dim3(GB,1),256,0,stream>>>(AG16,128, T3, F116,128, T4,
                                                      g2_br, nullptr, XC16, XC8, 256, 0);
  // ---- duration branch -> XC cols 128..255 ----
  gather_kernel<64><<<(NN*8+255)/256,256,0,stream>>>(DX8,64, PTR2,REC, AG16,64);
  mfma_gemm_kernel<true><<<dim3(GB,1),256,0,stream>>>(AG16,64, T5, DX16,64, T6,
                                                      d1_br, nullptr, XC16, XC8, 256, 128);
  // ---- c1 + folded skip ----
  gather_kernel<256><<<(NN*32+255)/256,256,0,stream>>>(XC8,256, PTR1,REC, AG16,256);
  mfma_gemm_kernel<false><<<dim3(GB,2),256,0,stream>>>(AG16,256, T7, XC16,256, T8,
                                                       c1_br, skip_b, XCP, nullptr, 256, 0);
  // ---- pool + tail ----
  hipMemsetAsync(EMBS, 0, (size_t)BB*256*4, stream);
  pool_partial_kernel<<<(NN+63)/64,256,0,stream>>>(XCP, batch, EMBS);
  tail_kernel<<<BB,256,0,stream>>>(EMBS, batch, seq, fc1_W, fc1_b, fc2_W, fc2_b,
                                   fcc_W, fcc_b, cls_W, cls_b, out);
}

// Round 15
// 288.947 us; speedup vs baseline: 1.4245x; 1.0538x over previous
//
#include <hip/hip_runtime.h>

#define NN 50000
#define MP 50176   // row-padded
#define EE 800000
#define BB 64
#define NBUK 256   // buckets per graph
#define NPB 196    // nodes per bucket (256*196 = 50176 >= NN)
#define EPB 1024   // edges per block in scatter pass
#define SBLK ((EE + EPB - 1)/EPB)   // 782 blocks
#define SEGCAP 4096 // fixed bucket segment capacity (mean 3136, +17 sigma)

typedef _Float16 half_t;
typedef __attribute__((ext_vector_type(8))) _Float16 h16x8;
typedef __attribute__((ext_vector_type(4))) float f32x4;
typedef __attribute__((ext_vector_type(2))) float f32x2;

__device__ __forceinline__ int ntld(const int* p){ return __builtin_nontemporal_load(p); }
__device__ __forceinline__ float ntldf(const float* p){ return __builtin_nontemporal_load(p); }

__device__ __forceinline__ unsigned pack_rec(int s, float w){
  union{ _Float16 h; unsigned short u; } c; c.h = (_Float16)w;
  return (unsigned)s | ((unsigned)c.u << 16);
}
__device__ __forceinline__ float rec_w(unsigned r){
  union{ unsigned short u; _Float16 h; } c; c.u = (unsigned short)(r >> 16);
  return (float)c.h;
}

// ---- fp8 e4m3 helpers (HW cvt) ----
__device__ __forceinline__ unsigned pack4_fp8(float f0, float f1, float f2, float f3){
  int r = __builtin_amdgcn_cvt_pk_fp8_f32(f0, f1, 0, false);
  r = __builtin_amdgcn_cvt_pk_fp8_f32(f2, f3, r, true);
  return (unsigned)r;
}
__device__ __forceinline__ unsigned char to_fp8(float f){
  return (unsigned char)(__builtin_amdgcn_cvt_pk_fp8_f32(f, 0.f, 0, false) & 0xff);
}
__device__ __forceinline__ void fp8x8_to_f32(uint2 u, float* f){
  f32x2 a = __builtin_amdgcn_cvt_pk_f32_fp8(u.x, false);
  f32x2 b = __builtin_amdgcn_cvt_pk_f32_fp8(u.x, true);
  f32x2 c = __builtin_amdgcn_cvt_pk_f32_fp8(u.y, false);
  f32x2 d = __builtin_amdgcn_cvt_pk_f32_fp8(u.y, true);
  f[0]=a[0]; f[1]=a[1]; f[2]=b[0]; f[3]=b[1];
  f[4]=c[0]; f[5]=c[1]; f[6]=d[0]; f[7]=d[1];
}

// ---------------- fp32 rows -> fp16 + fp8 rows (optional -1 masking) ----------------
template<bool MASK>
__global__ __launch_bounds__(256)
void tohalf_kernel(const float* __restrict__ x, half_t* __restrict__ o16,
                   unsigned char* __restrict__ o8, int n8){
  int i = blockIdx.x*blockDim.x + threadIdx.x;
  if (i >= n8) return;
  float4 a = ((const float4*)x)[2*i];
  float4 b = ((const float4*)x)[2*i+1];
  float v[8] = {a.x,a.y,a.z,a.w,b.x,b.y,b.z,b.w};
  h16x8 h;
  #pragma unroll
  for (int j=0;j<8;j++){
    float f = v[j];
    if (MASK && f == -1.0f) f = 0.f;
    v[j] = f;
    h[j] = (half_t)f;
  }
  ((h16x8*)o16)[i] = h;
  ((uint2*)o8)[i] = make_uint2(pack4_fp8(v[0],v[1],v[2],v[3]), pack4_fp8(v[4],v[5],v[6],v[7]));
}

// ---------------- fused transpose + fp16 convert for all 8 weights ----------------
struct TS { const float* W; const float* add; half_t* oh; int K; int N; int base; };
struct TS8 { TS t[8]; int total; };

__global__ __launch_bounds__(256)
void tsplit8_kernel(TS8 a){
  int i = blockIdx.x*256 + threadIdx.x;
  if (i >= a.total) return;
  int w = 0;
  #pragma unroll
  for (int j=1;j<8;j++) if (i >= a.t[j].base) w = j;
  TS ts = a.t[w];
  int e = i - ts.base;
  int k = e / ts.N, n = e - k*ts.N;
  float v = ts.W[e] + (ts.add ? ts.add[e] : 0.f);
  ts.oh[(size_t)n*ts.K + k] = (half_t)v;
}

// ---------------- single-pass clustered scatter into fixed bucket segments ----------------
__global__ __launch_bounds__(256)
void bscatter_kernel(const int* __restrict__ src1, const int* __restrict__ dst1, const float* __restrict__ ea,
                     const int* __restrict__ src2, const int* __restrict__ dst2, const float* __restrict__ dea,
                     int* __restrict__ bcur, uint2* __restrict__ buf){
  __shared__ int hist[2*NBUK];
  __shared__ int bas[2*NBUK];
  int t = threadIdx.x;
  for (int s=t; s<2*NBUK; s+=256) hist[s]=0;
  __syncthreads();
  int base = blockIdx.x*EPB;
  #pragma unroll
  for (int j=0;j<4;j++){
    int i = base + j*256 + t;
    if (i < EE){
      atomicAdd(&hist[ntld(&dst1[i])/NPB], 1);
      atomicAdd(&hist[NBUK + ntld(&dst2[i])/NPB], 1);
    }
  }
  __syncthreads();
  for (int s=t; s<2*NBUK; s+=256){
    int v = hist[s];
    bas[s] = v ? atomicAdd(&bcur[s], v) : 0;
  }
  __syncthreads();
  for (int s=t; s<2*NBUK; s+=256) hist[s]=0;
  __syncthreads();
  #pragma unroll
  for (int j=0;j<4;j++){
    int i = base + j*256 + t;
    if (i < EE){
      {
        int d = ntld(&dst1[i]); int b = d/NPB;
        int p = bas[b] + atomicAdd(&hist[b],1);
        if (p < SEGCAP) buf[(size_t)b*SEGCAP + p] = make_uint2(pack_rec(ntld(&src1[i]), ntldf(&ea[i])), (unsigned)d);
      }
      {
        int d = ntld(&dst2[i]); int b = NBUK + d/NPB;
        int p = bas[b] + atomicAdd(&hist[b],1);
        if (p < SEGCAP) buf[(size_t)b*SEGCAP + p] = make_uint2(pack_rec(ntld(&src2[i]), ntldf(&dea[i])), (unsigned)d);
      }
    }
  }
}

// ---------------- per-bucket node sort -> segmented CSR (int2 ptr = {start,count}) ----------------
__global__ __launch_bounds__(256)
void bfinal_kernel(const uint2* __restrict__ buf, const int* __restrict__ bcur,
                   unsigned* __restrict__ rec, int2* __restrict__ ptr1, int2* __restrict__ ptr2){
  __shared__ int cnt[NPB], off[256], cur[NPB];
  int b = blockIdx.x;          // 0..511
  int g = b >> 8, lb = b & 255;
  int n0 = lb*NPB;
  int t = threadIdx.x;
  int m = bcur[b]; if (m > SEGCAP) m = SEGCAP;
  const uint2* seg = buf + (size_t)b*SEGCAP;
  if (t < NPB){ cnt[t]=0; cur[t]=0; }
  __syncthreads();
  for (int j=t; j<m; j+=256) atomicAdd(&cnt[(int)seg[j].y - n0], 1);
  __syncthreads();
  int v = (t < NPB) ? cnt[t] : 0;
  off[t] = v; __syncthreads();
  #pragma unroll
  for (int o=1;o<256;o<<=1){ int u=(t>=o)?off[t-o]:0; __syncthreads(); off[t]+=u; __syncthreads(); }
  int ex = off[t]-v;
  __syncthreads();
  off[t] = ex;
  __syncthreads();
  int node = n0 + t;
  if (t < NPB && node < NN){
    int2 pv; pv.x = b*SEGCAP + off[t]; pv.y = (t < NPB) ? cnt[t] : 0;
    if (g==0) ptr1[node]=pv; else ptr2[node]=pv;
  }
  for (int j=t; j<m; j+=256){
    uint2 r = seg[j];
    int l = (int)r.y - n0;
    int p = atomicAdd(&cur[l],1);
    rec[(size_t)b*SEGCAP + off[l] + p] = r.x;
  }
}

// ---------------- segmented-CSR gather over fp8 rows, fp16 out ----------------
template<int F>
__global__ __launch_bounds__(256)
void gather_kernel(const unsigned char* __restrict__ H, int ldh,
                   const int2* __restrict__ ptr, const unsigned* __restrict__ rec,
                   half_t* __restrict__ Oh, int ldo){
  const int L = F/8;
  int gt = blockIdx.x*blockDim.x + threadIdx.x;
  int node = gt / L, lane = gt - node*L;
  if (node >= NN) return;
  int2 pv = ptr[node];
  int k = pv.y;
  const unsigned* base = rec + pv.x;
  float acc[8] = {0,0,0,0,0,0,0,0};
  #pragma unroll 1
  for (int j0=0; j0<k; j0+=L){
    unsigned myrec = (j0 + lane < k) ? base[j0 + lane] : 0u;
    int m = k - j0; if (m > L) m = L;
    int i = 0;
    #pragma unroll 1
    for (; i+8 <= m; i += 8){
      unsigned rr[8];
      #pragma unroll
      for (int u=0;u<8;u++) rr[u] = __shfl(myrec, i+u, L);
      uint2 vv[8];
      #pragma unroll
      for (int u=0;u<8;u++) vv[u] = *(const uint2*)(H + (size_t)(rr[u] & 0xFFFFu)*ldh + lane*8);
      #pragma unroll
      for (int u=0;u<8;u++){
        float f[8]; fp8x8_to_f32(vv[u], f);
        float w = rec_w(rr[u]);
        #pragma unroll
        for (int q=0;q<8;q++) acc[q] += w*f[q];
      }
    }
    #pragma unroll 1
    for (; i+4 <= m; i += 4){
      unsigned r0 = __shfl(myrec, i+0, L);
      unsigned r1 = __shfl(myrec, i+1, L);
      unsigned r2 = __shfl(myrec, i+2, L);
      unsigned r3 = __shfl(myrec, i+3, L);
      uint2 v0 = *(const uint2*)(H + (size_t)(r0 & 0xFFFFu)*ldh + lane*8);
      uint2 v1 = *(const uint2*)(H + (size_t)(r1 & 0xFFFFu)*ldh + lane*8);
      uint2 v2 = *(const uint2*)(H + (size_t)(r2 & 0xFFFFu)*ldh + lane*8);
      uint2 v3 = *(const uint2*)(H + (size_t)(r3 & 0xFFFFu)*ldh + lane*8);
      float f0[8], f1[8], f2[8], f3[8];
      fp8x8_to_f32(v0, f0); fp8x8_to_f32(v1, f1);
      fp8x8_to_f32(v2, f2); fp8x8_to_f32(v3, f3);
      float w0 = rec_w(r0), w1 = rec_w(r1), w2 = rec_w(r2), w3 = rec_w(r3);
      #pragma unroll
      for (int q=0;q<8;q++)
        acc[q] += w0*f0[q] + w1*f1[q] + w2*f2[q] + w3*f3[q];
    }
    for (; i < m; ++i){
      unsigned r = __shfl(myrec, i, L);
      uint2 v = *(const uint2*)(H + (size_t)(r & 0xFFFFu)*ldh + lane*8);
      float f[8]; fp8x8_to_f32(v, f);
      float w = rec_w(r);
      #pragma unroll
      for (int q=0;q<8;q++) acc[q] += w*f[q];
    }
  }
  h16x8 oh;
  #pragma unroll
  for (int q=0;q<8;q++) oh[q] = (half_t)acc[q];
  *(h16x8*)(Oh + (size_t)node*ldo + lane*8) = oh;
}

// ---------------- fp16 MFMA dual GEMM, 64x128 tile, fp16 + optional fp8 out ----------------
__device__ __forceinline__ int lds_off(int r, int slot){ return r*64 + ((slot ^ (r&7))<<3); }

template<bool OUT8>
__global__ __launch_bounds__(256,3)
void mfma_gemm_kernel(const half_t* __restrict__ A, int K1, const half_t* __restrict__ W1,
                      const half_t* __restrict__ R, int K2, const half_t* __restrict__ W2,
                      const float* __restrict__ b1, const float* __restrict__ b2,
                      half_t* __restrict__ out16, unsigned char* __restrict__ out8,
                      int ldo, int coloff){
  __shared__ half_t sA[64*64], sB[128*64];
  const int tid  = threadIdx.x;
  const int lane = tid & 63;
  const int wave = tid >> 6;
  const int wr = (wave>>1)*32, wc = (wave&1)*64;
  const int row0 = blockIdx.x*64;
  const int col0 = blockIdx.y*128;

  f32x4 acc[2][4];
  #pragma unroll
  for (int a=0;a<2;a++)
    #pragma unroll
    for (int b=0;b<4;b++){ acc[a][b][0]=0.f; acc[a][b][1]=0.f; acc[a][b][2]=0.f; acc[a][b][3]=0.f; }

  #pragma unroll 1
  for (int pass=0; pass<2; ++pass){
    const half_t* Ap = pass ? R  : A;
    const half_t* Wp = pass ? W2 : W1;
    const int K = pass ? K2 : K1;
    #pragma unroll 1
    for (int k0=0; k0<K; k0+=64){
      __syncthreads();
      #pragma unroll
      for (int i=0;i<2;i++){
        int c = tid + i*256;
        int r = c >> 3, s = c & 7;
        *(h16x8*)&sA[lds_off(r,s)] = *(const h16x8*)(Ap + (size_t)(row0+r)*K + k0 + s*8);
      }
      #pragma unroll
      for (int i=0;i<4;i++){
        int c = tid + i*256;
        int r = c >> 3, s = c & 7;
        *(h16x8*)&sB[lds_off(r,s)] = *(const h16x8*)(Wp + (size_t)(col0+r)*K + k0 + s*8);
      }
      __syncthreads();
      #pragma unroll
      for (int ks=0; ks<2; ++ks){
        const int rsel = lane >> 4;
        h16x8 af[2];
        #pragma unroll
        for (int mf=0; mf<2; mf++){
          int r = wr + mf*16 + (lane&15);
          af[mf] = *(const h16x8*)&sA[lds_off(r, ks*4 + rsel)];
        }
        #pragma unroll
        for (int nf=0; nf<4; nf++){
          int cix = wc + nf*16 + (lane&15);
          h16x8 b = *(const h16x8*)&sB[lds_off(cix, ks*4 + rsel)];
          #pragma unroll
          for (int mf=0; mf<2; mf++)
            acc[mf][nf] = __builtin_amdgcn_mfma_f32_16x16x32_f16(af[mf], b, acc[mf][nf], 0,0,0);
        }
      }
    }
  }

  #pragma unroll
  for (int nf=0; nf<4; nf++){
    int colg = col0 + wc + nf*16 + (lane&15);
    float bias = b1[colg] + (b2 ? b2[colg] : 0.f);
    #pragma unroll
    for (int mf=0; mf<2; mf++){
      #pragma unroll
      for (int r=0; r<4; r++){
        int rowg = row0 + wr + mf*16 + (lane>>4)*4 + r;
        if (rowg < NN){
          float o = fmaxf(acc[mf][nf][r] + bias, 0.f);
          size_t idx = (size_t)rowg*ldo + coloff + colg;
          out16[idx] = (half_t)o;
          if (OUT8) out8[idx] = to_fp8(o);
        }
      }
    }
  }
}

// ---------------- two-phase mean pool (batch sorted, fp16 input, 64-row chunks) ----------------
__global__ __launch_bounds__(256)
void pool_partial_kernel(const half_t* __restrict__ xcp, const int* __restrict__ batch,
                         float* __restrict__ sums){
  int r0 = blockIdx.x*64;
  int r1 = r0 + 64; if (r1 > NN) r1 = NN;
  int t = threadIdx.x;
  float run = 0.f;
  int cb = batch[r0];
  for (int r=r0; r<r1; ++r){
    int b = batch[r];
    if (b != cb){ atomicAdd(&sums[cb*256 + t], run); run = 0.f; cb = b; }
    run += (float)xcp[(size_t)r*256 + t];
  }
  atomicAdd(&sums[cb*256 + t], run);
}

__device__ __forceinline__ int lower_bound_i(const int* __restrict__ arr, int n, int v){
  int lo=0, hi=n;
  while (lo < hi){ int mid=(lo+hi)>>1; if (arr[mid] < v) lo=mid+1; else hi=mid; }
  return lo;
}

// ---------------- fused tail: pool_final + seq MLP + head ----------------
__global__ __launch_bounds__(256)
void tail_kernel(const float* __restrict__ sums, const int* __restrict__ batch,
                 const float* __restrict__ seq,
                 const float* __restrict__ fc1W, const float* __restrict__ fc1b,
                 const float* __restrict__ fc2W, const float* __restrict__ fc2b,
                 const float* __restrict__ fccW, const float* __restrict__ fccb,
                 const float* __restrict__ clsW, const float* __restrict__ clsb,
                 float* __restrict__ out){
  __shared__ float h[384], s1[256], sin_[256], lg[16];
  __shared__ float mred, lred;
  int b = blockIdx.x, t = threadIdx.x;
  int lo = lower_bound_i(batch, NN, b);
  int hi = lower_bound_i(batch, NN, b+1);
  h[t] = sums[b*256 + t] / fmaxf((float)(hi-lo), 1.0f);
  sin_[t] = seq[b*256 + t];
  __syncthreads();
  float a = fc1b[t];
  for (int k=0;k<256;k++) a += sin_[k]*fc1W[k*256 + t];
  s1[t] = fmaxf(a, 0.f);
  __syncthreads();
  if (t < 128){
    float a2 = fc2b[t];
    for (int k=0;k<256;k++) a2 += s1[k]*fc2W[k*128 + t];
    h[256 + t] = fmaxf(a2, 0.f);
  }
  __syncthreads();
  float a3 = fccb[t];
  for (int k=0;k<384;k++) a3 += h[k]*fccW[k*256 + t];
  float h2v = fmaxf(a3, 0.f);
  __syncthreads();
  s1[t] = h2v;
  __syncthreads();
  if (t < 16){
    float a4 = clsb[t];
    for (int k=0;k<256;k++) a4 += s1[k]*clsW[k*16 + t];
    lg[t] = a4;
  }
  __syncthreads();
  if (t == 0){
    float m = lg[0];
    for (int i=1;i<16;i++) m = fmaxf(m, lg[i]);
    float s = 0.f;
    for (int i=0;i<16;i++) s += expf(lg[i]-m);
    mred = m; lred = logf(s);
  }
  __syncthreads();
  if (t < 16) out[b*16 + t] = lg[t] - mred - lred;
}

extern "C" void kernel_launch(void* const* d_in, const int* in_sizes, int n_in,
                              void* d_out, int out_size, void* d_ws, size_t ws_size,
                              hipStream_t stream){
  const float* x      = (const float*)d_in[0];
  const int*   ei     = (const int*)  d_in[1];
  const float* ea     = (const float*)d_in[2];
  const int*   batch  = (const int*)  d_in[3];
  const float* dx     = (const float*)d_in[4];
  const int*   dei    = (const int*)  d_in[5];
  const float* dea    = (const float*)d_in[6];
  const float* seq    = (const float*)d_in[7];
  const float* g1_Wr  = (const float*)d_in[8];
  const float* g1_br  = (const float*)d_in[9];
  const float* g1_Wrt = (const float*)d_in[10];
  const float* g2_Wr  = (const float*)d_in[11];
  const float* g2_br  = (const float*)d_in[12];
  const float* g2_Wrt = (const float*)d_in[13];
  const float* d1_Wr  = (const float*)d_in[14];
  const float* d1_br  = (const float*)d_in[15];
  const float* d1_Wrt = (const float*)d_in[16];
  const float* c1_Wr  = (const float*)d_in[17];
  const float* c1_br  = (const float*)d_in[18];
  const float* c1_Wrt = (const float*)d_in[19];
  const float* skip_W = (const float*)d_in[20];
  const float* skip_b = (const float*)d_in[21];
  const float* fc1_W  = (const float*)d_in[22];
  const float* fc1_b  = (const float*)d_in[23];
  const float* fc2_W  = (const float*)d_in[24];
  const float* fc2_b  = (const float*)d_in[25];
  const float* fcc_W  = (const float*)d_in[26];
  const float* fcc_b  = (const float*)d_in[27];
  const float* cls_W  = (const float*)d_in[28];
  const float* cls_b  = (const float*)d_in[29];
  float* out = (float*)d_out;

  char* wp = (char*)d_ws;
  auto alloc = [&](size_t bytes)->char*{
    char* p = wp; wp += (bytes + 255) & ~(size_t)255; return p;
  };
  half_t* XM16 = (half_t*)alloc((size_t)MP*128*2);
  half_t* F116 = (half_t*)alloc((size_t)MP*128*2);
  half_t* DX16 = (half_t*)alloc((size_t)MP*64*2);
  half_t* XC16 = (half_t*)alloc((size_t)MP*256*2);
  half_t* AG16 = (half_t*)alloc((size_t)MP*256*2);
  half_t* XCP  = (half_t*)alloc((size_t)MP*256*2);
  unsigned char* XM8 = (unsigned char*)alloc((size_t)MP*128);
  unsigned char* F18 = (unsigned char*)alloc((size_t)MP*128);
  unsigned char* DX8 = (unsigned char*)alloc((size_t)MP*64);
  unsigned char* XC8 = (unsigned char*)alloc((size_t)MP*256);
  half_t* T1 = (half_t*)alloc(128*128*2);
  half_t* T2 = (half_t*)alloc(128*128*2);
  half_t* T3 = (half_t*)alloc(128*128*2);
  half_t* T4 = (half_t*)alloc(128*128*2);
  half_t* T5 = (half_t*)alloc(64*128*2);
  half_t* T6 = (half_t*)alloc(64*128*2);
  half_t* T7 = (half_t*)alloc(256*256*2);
  half_t* T8 = (half_t*)alloc(256*256*2);
  uint2*    BUF  = (uint2*)alloc((size_t)2*NBUK*SEGCAP*8);
  unsigned* REC  = (unsigned*)alloc((size_t)2*NBUK*SEGCAP*4);
  int* BCUR = (int*)alloc((size_t)2*NBUK*4);
  int2* PTR1 = (int2*)alloc((size_t)NN*8);
  int2* PTR2 = (int2*)alloc((size_t)NN*8);
  float* EMBS = (float*)alloc((size_t)BB*256*4);

  const int* src1 = ei;  const int* dst1 = ei + EE;
  const int* src2 = dei; const int* dst2 = dei + EE;

  // ---- CSR build: single scatter pass into fixed segments + per-bucket compact ----
  hipMemsetAsync(BCUR, 0, (size_t)2*NBUK*4, stream);
  bscatter_kernel<<<SBLK,256,0,stream>>>(src1,dst1,ea, src2,dst2,dea, BCUR, BUF);
  bfinal_kernel<<<2*NBUK,256,0,stream>>>(BUF, BCUR, REC, PTR1, PTR2);

  // fp16+fp8 activations
  tohalf_kernel<true ><<<(NN*16+255)/256,256,0,stream>>>(x,  XM16, XM8, NN*16);
  tohalf_kernel<false><<<(NN*8 +255)/256,256,0,stream>>>(dx, DX16, DX8, NN*8);

  // weight prep (T8 = c1_Wroot + skip_W)
  {
    TS8 a;
    int base = 0;
    auto put = [&](int idx, const float* W, const float* add, half_t* oh, int K, int N){
      a.t[idx] = TS{W, add, oh, K, N, base}; base += K*N;
    };
    put(0, g1_Wr,  nullptr, T1, 128,128);
    put(1, g1_Wrt, nullptr, T2, 128,128);
    put(2, g2_Wr,  nullptr, T3, 128,128);
    put(3, g2_Wrt, nullptr, T4, 128,128);
    put(4, d1_Wr,  nullptr, T5, 64,128);
    put(5, d1_Wrt, nullptr, T6, 64,128);
    put(6, c1_Wr,  nullptr, T7, 256,256);
    put(7, c1_Wrt, skip_W,  T8, 256,256);
    a.total = base;
    tsplit8_kernel<<<(a.total+255)/256,256,0,stream>>>(a);
  }

  const int GB = (NN+63)/64;   // 782

  // ---- g1 ----
  gather_kernel<128><<<(NN*16+255)/256,256,0,stream>>>(XM8,128, PTR1,REC, AG16,128);
  mfma_gemm_kernel<true><<<dim3(GB,1),256,0,stream>>>(AG16,128, T1, XM16,128, T2,
                                                      g1_br, nullptr, F116, F18, 128, 0);
  // ---- g2 ----
  gather_kernel<128><<<(NN*16+255)/256,256,0,stream>>>(F18,128, PTR1,REC, AG16,128);
  mfma_gemm_kernel<true><<<dim3(GB,1),256,0,stream>>>(AG16,128, T3, F116,128, T4,
                                                      g2_br, nullptr, XC16, XC8, 256, 0);
  // ---- duration branch -> XC cols 128..255 ----
  gather_kernel<64><<<(NN*8+255)/256,256,0,stream>>>(DX8,64, PTR2,REC, AG16,64);
  mfma_gemm_kernel<true><<<dim3(GB,1),256,0,stream>>>(AG16,64, T5, DX16,64, T6,
                                                      d1_br, nullptr, XC16, XC8, 256, 128);
  // ---- c1 + folded skip ----
  gather_kernel<256><<<(NN*32+255)/256,256,0,stream>>>(XC8,256, PTR1,REC, AG16,256);
  mfma_gemm_kernel<false><<<dim3(GB,2),256,0,stream>>>(AG16,256, T7, XC16,256, T8,
                                                       c1_br, skip_b, XCP, nullptr, 256, 0);
  // ---- pool + tail ----
  hipMemsetAsync(EMBS, 0, (size_t)BB*256*4, stream);
  pool_partial_kernel<<<(NN+63)/64,256,0,stream>>>(XCP, batch, EMBS);
  tail_kernel<<<BB,256,0,stream>>>(EMBS, batch, seq, fc1_W, fc1_b, fc2_W, fc2_b,
                                   fcc_W, fcc_b, cls_W, cls_b, out);
}

// Round 16
// 268.165 us; speedup vs baseline: 1.5349x; 1.0775x over previous
//
#include <hip/hip_runtime.h>

#define NN 50000
#define MP 50176   // row-padded
#define EE 800000
#define BB 64
#define NBUK 256   // buckets per graph
#define NPB 196    // nodes per bucket (256*196 = 50176 >= NN)
#define EPB 2048   // edges per block in scatter pass
#define SBLK ((EE + EPB - 1)/EPB)   // 391 blocks
#define SEGCAP 4096 // fixed bucket segment capacity (mean 3136, +17 sigma)

typedef _Float16 half_t;
typedef __attribute__((ext_vector_type(8))) _Float16 h16x8;
typedef __attribute__((ext_vector_type(4))) float f32x4;
typedef __attribute__((ext_vector_type(2))) float f32x2;

__device__ __forceinline__ int ntld(const int* p){ return __builtin_nontemporal_load(p); }
__device__ __forceinline__ float ntldf(const float* p){ return __builtin_nontemporal_load(p); }

__device__ __forceinline__ unsigned pack_rec(int s, float w){
  union{ _Float16 h; unsigned short u; } c; c.h = (_Float16)w;
  return (unsigned)s | ((unsigned)c.u << 16);
}
__device__ __forceinline__ float rec_w(unsigned r){
  union{ unsigned short u; _Float16 h; } c; c.u = (unsigned short)(r >> 16);
  return (float)c.h;
}

// ---- fp8 e4m3 helpers (HW cvt) ----
__device__ __forceinline__ unsigned pack4_fp8(float f0, float f1, float f2, float f3){
  int r = __builtin_amdgcn_cvt_pk_fp8_f32(f0, f1, 0, false);
  r = __builtin_amdgcn_cvt_pk_fp8_f32(f2, f3, r, true);
  return (unsigned)r;
}
__device__ __forceinline__ unsigned char to_fp8(float f){
  return (unsigned char)(__builtin_amdgcn_cvt_pk_fp8_f32(f, 0.f, 0, false) & 0xff);
}
__device__ __forceinline__ void fp8x8_to_f32(uint2 u, float* f){
  f32x2 a = __builtin_amdgcn_cvt_pk_f32_fp8(u.x, false);
  f32x2 b = __builtin_amdgcn_cvt_pk_f32_fp8(u.x, true);
  f32x2 c = __builtin_amdgcn_cvt_pk_f32_fp8(u.y, false);
  f32x2 d = __builtin_amdgcn_cvt_pk_f32_fp8(u.y, true);
  f[0]=a[0]; f[1]=a[1]; f[2]=b[0]; f[3]=b[1];
  f[4]=c[0]; f[5]=c[1]; f[6]=d[0]; f[7]=d[1];
}

// ---------------- fp32 rows -> fp16 + fp8 rows (optional -1 masking) ----------------
template<bool MASK>
__global__ __launch_bounds__(256)
void tohalf_kernel(const float* __restrict__ x, half_t* __restrict__ o16,
                   unsigned char* __restrict__ o8, int n8){
  int i = blockIdx.x*blockDim.x + threadIdx.x;
  if (i >= n8) return;
  float4 a = ((const float4*)x)[2*i];
  float4 b = ((const float4*)x)[2*i+1];
  float v[8] = {a.x,a.y,a.z,a.w,b.x,b.y,b.z,b.w};
  h16x8 h;
  #pragma unroll
  for (int j=0;j<8;j++){
    float f = v[j];
    if (MASK && f == -1.0f) f = 0.f;
    v[j] = f;
    h[j] = (half_t)f;
  }
  ((h16x8*)o16)[i] = h;
  ((uint2*)o8)[i] = make_uint2(pack4_fp8(v[0],v[1],v[2],v[3]), pack4_fp8(v[4],v[5],v[6],v[7]));
}

// ---------------- fused transpose + fp16 convert for all 8 weights ----------------
struct TS { const float* W; const float* add; half_t* oh; int K; int N; int base; };
struct TS8 { TS t[8]; int total; };

__global__ __launch_bounds__(256)
void tsplit8_kernel(TS8 a){
  int i = blockIdx.x*256 + threadIdx.x;
  if (i >= a.total) return;
  int w = 0;
  #pragma unroll
  for (int j=1;j<8;j++) if (i >= a.t[j].base) w = j;
  TS ts = a.t[w];
  int e = i - ts.base;
  int k = e / ts.N, n = e - k*ts.N;
  float v = ts.W[e] + (ts.add ? ts.add[e] : 0.f);
  ts.oh[(size_t)n*ts.K + k] = (half_t)v;
}

// ---------------- single-pass scatter: LDS bucket-sort then coalesced write-out ----------------
__global__ __launch_bounds__(256)
void bscatter_kernel(const int* __restrict__ src1, const int* __restrict__ dst1, const float* __restrict__ ea,
                     const int* __restrict__ src2, const int* __restrict__ dst2, const float* __restrict__ dea,
                     int* __restrict__ bcur, uint2* __restrict__ buf){
  __shared__ int hist[2*NBUK], lofs[2*NBUK], bas[2*NBUK], cur[2*NBUK];
  __shared__ int sscan[256];
  __shared__ uint2 srec[2*EPB];             // 32 KB
  __shared__ unsigned short sbkt[2*EPB];    // 8 KB
  int t = threadIdx.x;
  int base = blockIdx.x*EPB;

  int da[16]; unsigned pa[16];   // 8 iters x 2 graphs
  for (int s=t; s<2*NBUK; s+=256){ hist[s]=0; cur[s]=0; }
  __syncthreads();
  #pragma unroll
  for (int j=0;j<8;j++){
    int i = base + j*256 + t;
    if (i < EE){
      int d1 = ntld(&dst1[i]);
      da[2*j]   = d1;
      pa[2*j]   = pack_rec(ntld(&src1[i]), ntldf(&ea[i]));
      atomicAdd(&hist[d1/NPB], 1);
      int d2 = ntld(&dst2[i]);
      da[2*j+1] = d2;
      pa[2*j+1] = pack_rec(ntld(&src2[i]), ntldf(&dea[i]));
      atomicAdd(&hist[NBUK + d2/NPB], 1);
    } else { da[2*j] = -1; da[2*j+1] = -1; }
  }
  __syncthreads();
  // scan 512 hist (2 elems/thread) + reserve global space
  int h0 = hist[2*t], h1 = hist[2*t+1];
  sscan[t] = h0 + h1;
  __syncthreads();
  #pragma unroll
  for (int o=1;o<256;o<<=1){ int u=(t>=o)?sscan[t-o]:0; __syncthreads(); sscan[t]+=u; __syncthreads(); }
  int ex = sscan[t] - (h0 + h1);
  lofs[2*t]   = ex;
  lofs[2*t+1] = ex + h0;
  bas[2*t]   = h0 ? atomicAdd(&bcur[2*t],   h0) : 0;
  bas[2*t+1] = h1 ? atomicAdd(&bcur[2*t+1], h1) : 0;
  __syncthreads();
  // scatter into LDS, bucket-sorted
  #pragma unroll
  for (int j=0;j<16;j++){
    int d = da[j];
    if (d >= 0){
      int b = ((j&1) ? NBUK : 0) + d/NPB;
      int p = lofs[b] + atomicAdd(&cur[b],1);
      srec[p] = make_uint2(pa[j], (unsigned)d);
      sbkt[p] = (unsigned short)b;
    }
  }
  __syncthreads();
  // coalesced write-out (consecutive threads -> consecutive addrs within a bucket run)
  int total = sscan[255];
  for (int p=t; p<total; p+=256){
    int b = sbkt[p];
    int g = bas[b] + (p - lofs[b]);
    if (g < SEGCAP) buf[(size_t)b*SEGCAP + g] = srec[p];
  }
}

// ---------------- per-bucket node sort -> segmented CSR (int2 ptr = {start,count}) ----------------
__global__ __launch_bounds__(256)
void bfinal_kernel(const uint2* __restrict__ buf, const int* __restrict__ bcur,
                   unsigned* __restrict__ rec, int2* __restrict__ ptr1, int2* __restrict__ ptr2){
  __shared__ int cnt[NPB], off[256], cur[NPB];
  int b = blockIdx.x;          // 0..511
  int g = b >> 8, lb = b & 255;
  int n0 = lb*NPB;
  int t = threadIdx.x;
  int m = bcur[b]; if (m > SEGCAP) m = SEGCAP;
  const uint2* seg = buf + (size_t)b*SEGCAP;
  if (t < NPB){ cnt[t]=0; cur[t]=0; }
  __syncthreads();
  for (int j=t; j<m; j+=256) atomicAdd(&cnt[(int)seg[j].y - n0], 1);
  __syncthreads();
  int v = (t < NPB) ? cnt[t] : 0;
  off[t] = v; __syncthreads();
  #pragma unroll
  for (int o=1;o<256;o<<=1){ int u=(t>=o)?off[t-o]:0; __syncthreads(); off[t]+=u; __syncthreads(); }
  int ex = off[t]-v;
  __syncthreads();
  off[t] = ex;
  __syncthreads();
  int node = n0 + t;
  if (t < NPB && node < NN){
    int2 pv; pv.x = b*SEGCAP + off[t]; pv.y = (t < NPB) ? cnt[t] : 0;
    if (g==0) ptr1[node]=pv; else ptr2[node]=pv;
  }
  for (int j=t; j<m; j+=256){
    uint2 r = seg[j];
    int l = (int)r.y - n0;
    int p = atomicAdd(&cur[l],1);
    rec[(size_t)b*SEGCAP + off[l] + p] = r.x;
  }
}

// ---------------- segmented-CSR gather over fp8 rows, fp16 out ----------------
template<int F>
__global__ __launch_bounds__(256)
void gather_kernel(const unsigned char* __restrict__ H, int ldh,
                   const int2* __restrict__ ptr, const unsigned* __restrict__ rec,
                   half_t* __restrict__ Oh, int ldo){
  const int L = F/8;
  int gt = blockIdx.x*blockDim.x + threadIdx.x;
  int node = gt / L, lane = gt - node*L;
  if (node >= NN) return;
  int2 pv = ptr[node];
  int k = pv.y;
  const unsigned* base = rec + pv.x;
  float acc[8] = {0,0,0,0,0,0,0,0};
  #pragma unroll 1
  for (int j0=0; j0<k; j0+=L){
    unsigned myrec = (j0 + lane < k) ? base[j0 + lane] : 0u;
    int m = k - j0; if (m > L) m = L;
    int i = 0;
    #pragma unroll 1
    for (; i+8 <= m; i += 8){
      unsigned rr[8];
      #pragma unroll
      for (int u=0;u<8;u++) rr[u] = __shfl(myrec, i+u, L);
      uint2 vv[8];
      #pragma unroll
      for (int u=0;u<8;u++) vv[u] = *(const uint2*)(H + (size_t)(rr[u] & 0xFFFFu)*ldh + lane*8);
      #pragma unroll
      for (int u=0;u<8;u++){
        float f[8]; fp8x8_to_f32(vv[u], f);
        float w = rec_w(rr[u]);
        #pragma unroll
        for (int q=0;q<8;q++) acc[q] += w*f[q];
      }
    }
    #pragma unroll 1
    for (; i+4 <= m; i += 4){
      unsigned r0 = __shfl(myrec, i+0, L);
      unsigned r1 = __shfl(myrec, i+1, L);
      unsigned r2 = __shfl(myrec, i+2, L);
      unsigned r3 = __shfl(myrec, i+3, L);
      uint2 v0 = *(const uint2*)(H + (size_t)(r0 & 0xFFFFu)*ldh + lane*8);
      uint2 v1 = *(const uint2*)(H + (size_t)(r1 & 0xFFFFu)*ldh + lane*8);
      uint2 v2 = *(const uint2*)(H + (size_t)(r2 & 0xFFFFu)*ldh + lane*8);
      uint2 v3 = *(const uint2*)(H + (size_t)(r3 & 0xFFFFu)*ldh + lane*8);
      float f0[8], f1[8], f2[8], f3[8];
      fp8x8_to_f32(v0, f0); fp8x8_to_f32(v1, f1);
      fp8x8_to_f32(v2, f2); fp8x8_to_f32(v3, f3);
      float w0 = rec_w(r0), w1 = rec_w(r1), w2 = rec_w(r2), w3 = rec_w(r3);
      #pragma unroll
      for (int q=0;q<8;q++)
        acc[q] += w0*f0[q] + w1*f1[q] + w2*f2[q] + w3*f3[q];
    }
    for (; i < m; ++i){
      unsigned r = __shfl(myrec, i, L);
      uint2 v = *(const uint2*)(H + (size_t)(r & 0xFFFFu)*ldh + lane*8);
      float f[8]; fp8x8_to_f32(v, f);
      float w = rec_w(r);
      #pragma unroll
      for (int q=0;q<8;q++) acc[q] += w*f[q];
    }
  }
  h16x8 oh;
  #pragma unroll
  for (int q=0;q<8;q++) oh[q] = (half_t)acc[q];
  *(h16x8*)(Oh + (size_t)node*ldo + lane*8) = oh;
}

// ---------------- fp16 MFMA dual GEMM, 64x128 tile, fp16 + optional fp8 out ----------------
__device__ __forceinline__ int lds_off(int r, int slot){ return r*64 + ((slot ^ (r&7))<<3); }

template<bool OUT8>
__global__ __launch_bounds__(256,3)
void mfma_gemm_kernel(const half_t* __restrict__ A, int K1, const half_t* __restrict__ W1,
                      const half_t* __restrict__ R, int K2, const half_t* __restrict__ W2,
                      const float* __restrict__ b1, const float* __restrict__ b2,
                      half_t* __restrict__ out16, unsigned char* __restrict__ out8,
                      int ldo, int coloff){
  __shared__ half_t sA[64*64], sB[128*64];
  const int tid  = threadIdx.x;
  const int lane = tid & 63;
  const int wave = tid >> 6;
  const int wr = (wave>>1)*32, wc = (wave&1)*64;
  const int row0 = blockIdx.x*64;
  const int col0 = blockIdx.y*128;

  f32x4 acc[2][4];
  #pragma unroll
  for (int a=0;a<2;a++)
    #pragma unroll
    for (int b=0;b<4;b++){ acc[a][b][0]=0.f; acc[a][b][1]=0.f; acc[a][b][2]=0.f; acc[a][b][3]=0.f; }

  #pragma unroll 1
  for (int pass=0; pass<2; ++pass){
    const half_t* Ap = pass ? R  : A;
    const half_t* Wp = pass ? W2 : W1;
    const int K = pass ? K2 : K1;
    #pragma unroll 1
    for (int k0=0; k0<K; k0+=64){
      __syncthreads();
      #pragma unroll
      for (int i=0;i<2;i++){
        int c = tid + i*256;
        int r = c >> 3, s = c & 7;
        *(h16x8*)&sA[lds_off(r,s)] = *(const h16x8*)(Ap + (size_t)(row0+r)*K + k0 + s*8);
      }
      #pragma unroll
      for (int i=0;i<4;i++){
        int c = tid + i*256;
        int r = c >> 3, s = c & 7;
        *(h16x8*)&sB[lds_off(r,s)] = *(const h16x8*)(Wp + (size_t)(col0+r)*K + k0 + s*8);
      }
      __syncthreads();
      #pragma unroll
      for (int ks=0; ks<2; ++ks){
        const int rsel = lane >> 4;
        h16x8 af[2];
        #pragma unroll
        for (int mf=0; mf<2; mf++){
          int r = wr + mf*16 + (lane&15);
          af[mf] = *(const h16x8*)&sA[lds_off(r, ks*4 + rsel)];
        }
        #pragma unroll
        for (int nf=0; nf<4; nf++){
          int cix = wc + nf*16 + (lane&15);
          h16x8 b = *(const h16x8*)&sB[lds_off(cix, ks*4 + rsel)];
          #pragma unroll
          for (int mf=0; mf<2; mf++)
            acc[mf][nf] = __builtin_amdgcn_mfma_f32_16x16x32_f16(af[mf], b, acc[mf][nf], 0,0,0);
        }
      }
    }
  }

  #pragma unroll
  for (int nf=0; nf<4; nf++){
    int colg = col0 + wc + nf*16 + (lane&15);
    float bias = b1[colg] + (b2 ? b2[colg] : 0.f);
    #pragma unroll
    for (int mf=0; mf<2; mf++){
      #pragma unroll
      for (int r=0; r<4; r++){
        int rowg = row0 + wr + mf*16 + (lane>>4)*4 + r;
        if (rowg < NN){
          float o = fmaxf(acc[mf][nf][r] + bias, 0.f);
          size_t idx = (size_t)rowg*ldo + coloff + colg;
          out16[idx] = (half_t)o;
          if (OUT8) out8[idx] = to_fp8(o);
        }
      }
    }
  }
}

// ---------------- two-phase mean pool (batch sorted, fp16 input, 64-row chunks) ----------------
__global__ __launch_bounds__(256)
void pool_partial_kernel(const half_t* __restrict__ xcp, const int* __restrict__ batch,
                         float* __restrict__ sums){
  int r0 = blockIdx.x*64;
  int r1 = r0 + 64; if (r1 > NN) r1 = NN;
  int t = threadIdx.x;
  float run = 0.f;
  int cb = batch[r0];
  for (int r=r0; r<r1; ++r){
    int b = batch[r];
    if (b != cb){ atomicAdd(&sums[cb*256 + t], run); run = 0.f; cb = b; }
    run += (float)xcp[(size_t)r*256 + t];
  }
  atomicAdd(&sums[cb*256 + t], run);
}

__device__ __forceinline__ int lower_bound_i(const int* __restrict__ arr, int n, int v){
  int lo=0, hi=n;
  while (lo < hi){ int mid=(lo+hi)>>1; if (arr[mid] < v) lo=mid+1; else hi=mid; }
  return lo;
}

// ---------------- fused tail: pool_final + seq MLP + head ----------------
__global__ __launch_bounds__(256)
void tail_kernel(const float* __restrict__ sums, const int* __restrict__ batch,
                 const float* __restrict__ seq,
                 const float* __restrict__ fc1W, const float* __restrict__ fc1b,
                 const float* __restrict__ fc2W, const float* __restrict__ fc2b,
                 const float* __restrict__ fccW, const float* __restrict__ fccb,
                 const float* __restrict__ clsW, const float* __restrict__ clsb,
                 float* __restrict__ out){
  __shared__ float h[384], s1[256], sin_[256], lg[16];
  __shared__ float mred, lred;
  int b = blockIdx.x, t = threadIdx.x;
  int lo = lower_bound_i(batch, NN, b);
  int hi = lower_bound_i(batch, NN, b+1);
  h[t] = sums[b*256 + t] / fmaxf((float)(hi-lo), 1.0f);
  sin_[t] = seq[b*256 + t];
  __syncthreads();
  float a = fc1b[t];
  for (int k=0;k<256;k++) a += sin_[k]*fc1W[k*256 + t];
  s1[t] = fmaxf(a, 0.f);
  __syncthreads();
  if (t < 128){
    float a2 = fc2b[t];
    for (int k=0;k<256;k++) a2 += s1[k]*fc2W[k*128 + t];
    h[256 + t] = fmaxf(a2, 0.f);
  }
  __syncthreads();
  float a3 = fccb[t];
  for (int k=0;k<384;k++) a3 += h[k]*fccW[k*256 + t];
  float h2v = fmaxf(a3, 0.f);
  __syncthreads();
  s1[t] = h2v;
  __syncthreads();
  if (t < 16){
    float a4 = clsb[t];
    for (int k=0;k<256;k++) a4 += s1[k]*clsW[k*16 + t];
    lg[t] = a4;
  }
  __syncthreads();
  if (t == 0){
    float m = lg[0];
    for (int i=1;i<16;i++) m = fmaxf(m, lg[i]);
    float s = 0.f;
    for (int i=0;i<16;i++) s += expf(lg[i]-m);
    mred = m; lred = logf(s);
  }
  __syncthreads();
  if (t < 16) out[b*16 + t] = lg[t] - mred - lred;
}

extern "C" void kernel_launch(void* const* d_in, const int* in_sizes, int n_in,
                              void* d_out, int out_size, void* d_ws, size_t ws_size,
                              hipStream_t stream){
  const float* x      = (const float*)d_in[0];
  const int*   ei     = (const int*)  d_in[1];
  const float* ea     = (const float*)d_in[2];
  const int*   batch  = (const int*)  d_in[3];
  const float* dx     = (const float*)d_in[4];
  const int*   dei    = (const int*)  d_in[5];
  const float* dea    = (const float*)d_in[6];
  const float* seq    = (const float*)d_in[7];
  const float* g1_Wr  = (const float*)d_in[8];
  const float* g1_br  = (const float*)d_in[9];
  const float* g1_Wrt = (const float*)d_in[10];
  const float* g2_Wr  = (const float*)d_in[11];
  const float* g2_br  = (const float*)d_in[12];
  const float* g2_Wrt = (const float*)d_in[13];
  const float* d1_Wr  = (const float*)d_in[14];
  const float* d1_br  = (const float*)d_in[15];
  const float* d1_Wrt = (const float*)d_in[16];
  const float* c1_Wr  = (const float*)d_in[17];
  const float* c1_br  = (const float*)d_in[18];
  const float* c1_Wrt = (const float*)d_in[19];
  const float* skip_W = (const float*)d_in[20];
  const float* skip_b = (const float*)d_in[21];
  const float* fc1_W  = (const float*)d_in[22];
  const float* fc1_b  = (const float*)d_in[23];
  const float* fc2_W  = (const float*)d_in[24];
  const float* fc2_b  = (const float*)d_in[25];
  const float* fcc_W  = (const float*)d_in[26];
  const float* fcc_b  = (const float*)d_in[27];
  const float* cls_W  = (const float*)d_in[28];
  const float* cls_b  = (const float*)d_in[29];
  float* out = (float*)d_out;

  char* wp = (char*)d_ws;
  auto alloc = [&](size_t bytes)->char*{
    char* p = wp; wp += (bytes + 255) & ~(size_t)255; return p;
  };
  half_t* XM16 = (half_t*)alloc((size_t)MP*128*2);
  half_t* F116 = (half_t*)alloc((size_t)MP*128*2);
  half_t* DX16 = (half_t*)alloc((size_t)MP*64*2);
  half_t* XC16 = (half_t*)alloc((size_t)MP*256*2);
  half_t* AG16 = (half_t*)alloc((size_t)MP*256*2);
  half_t* XCP  = (half_t*)alloc((size_t)MP*256*2);
  unsigned char* XM8 = (unsigned char*)alloc((size_t)MP*128);
  unsigned char* F18 = (unsigned char*)alloc((size_t)MP*128);
  unsigned char* DX8 = (unsigned char*)alloc((size_t)MP*64);
  unsigned char* XC8 = (unsigned char*)alloc((size_t)MP*256);
  half_t* T1 = (half_t*)alloc(128*128*2);
  half_t* T2 = (half_t*)alloc(128*128*2);
  half_t* T3 = (half_t*)alloc(128*128*2);
  half_t* T4 = (half_t*)alloc(128*128*2);
  half_t* T5 = (half_t*)alloc(64*128*2);
  half_t* T6 = (half_t*)alloc(64*128*2);
  half_t* T7 = (half_t*)alloc(256*256*2);
  half_t* T8 = (half_t*)alloc(256*256*2);
  uint2*    BUF  = (uint2*)alloc((size_t)2*NBUK*SEGCAP*8);
  unsigned* REC  = (unsigned*)alloc((size_t)2*NBUK*SEGCAP*4);
  int* BCUR = (int*)alloc((size_t)2*NBUK*4);
  int2* PTR1 = (int2*)alloc((size_t)NN*8);
  int2* PTR2 = (int2*)alloc((size_t)NN*8);
  float* EMBS = (float*)alloc((size_t)BB*256*4);

  const int* src1 = ei;  const int* dst1 = ei + EE;
  const int* src2 = dei; const int* dst2 = dei + EE;

  // ---- CSR build: LDS-sorted scatter pass + per-bucket compact ----
  hipMemsetAsync(BCUR, 0, (size_t)2*NBUK*4, stream);
  bscatter_kernel<<<SBLK,256,0,stream>>>(src1,dst1,ea, src2,dst2,dea, BCUR, BUF);
  bfinal_kernel<<<2*NBUK,256,0,stream>>>(BUF, BCUR, REC, PTR1, PTR2);

  // fp16+fp8 activations
  tohalf_kernel<true ><<<(NN*16+255)/256,256,0,stream>>>(x,  XM16, XM8, NN*16);
  tohalf_kernel<false><<<(NN*8 +255)/256,256,0,stream>>>(dx, DX16, DX8, NN*8);

  // weight prep (T8 = c1_Wroot + skip_W)
  {
    TS8 a;
    int base = 0;
    auto put = [&](int idx, const float* W, const float* add, half_t* oh, int K, int N){
      a.t[idx] = TS{W, add, oh, K, N, base}; base += K*N;
    };
    put(0, g1_Wr,  nullptr, T1, 128,128);
    put(1, g1_Wrt, nullptr, T2, 128,128);
    put(2, g2_Wr,  nullptr, T3, 128,128);
    put(3, g2_Wrt, nullptr, T4, 128,128);
    put(4, d1_Wr,  nullptr, T5, 64,128);
    put(5, d1_Wrt, nullptr, T6, 64,128);
    put(6, c1_Wr,  nullptr, T7, 256,256);
    put(7, c1_Wrt, skip_W,  T8, 256,256);
    a.total = base;
    tsplit8_kernel<<<(a.total+255)/256,256,0,stream>>>(a);
  }

  const int GB = (NN+63)/64;   // 782

  // ---- g1 ----
  gather_kernel<128><<<(NN*16+255)/256,256,0,stream>>>(XM8,128, PTR1,REC, AG16,128);
  mfma_gemm_kernel<true><<<dim3(GB,1),256,0,stream>>>(AG16,128, T1, XM16,128, T2,
                                                      g1_br, nullptr, F116, F18, 128, 0);
  // ---- g2 ----
  gather_kernel<128><<<(NN*16+255)/256,256,0,stream>>>(F18,128, PTR1,REC, AG16,128);
  mfma_gemm_kernel<true><<<dim3(GB,1),256,0,stream>>>(AG16,128, T3, F116,128, T4,
                                                      g2_br, nullptr, XC16, XC8, 256, 0);
  // ---- duration branch -> XC cols 128..255 ----
  gather_kernel<64><<<(NN*8+255)/256,256,0,stream>>>(DX8,64, PTR2,REC, AG16,64);
  mfma_gemm_kernel<true><<<dim3(GB,1),256,0,stream>>>(AG16,64, T5, DX16,64, T6,
                                                      d1_br, nullptr, XC16, XC8, 256, 128);
  // ---- c1 + folded skip ----
  gather_kernel<256><<<(NN*32+255)/256,256,0,stream>>>(XC8,256, PTR1,REC, AG16,256);
  mfma_gemm_kernel<false><<<dim3(GB,2),256,0,stream>>>(AG16,256, T7, XC16,256, T8,
                                                       c1_br, skip_b, XCP, nullptr, 256, 0);
  // ---- pool + tail ----
  hipMemsetAsync(EMBS, 0, (size_t)BB*256*4, stream);
  pool_partial_kernel<<<(NN+63)/64,256,0,stream>>>(XCP, batch, EMBS);
  tail_kernel<<<BB,256,0,stream>>>(EMBS, batch, seq, fc1_W, fc1_b, fc2_W, fc2_b,
                                   fcc_W, fcc_b, cls_W, cls_b, out);
}

// Round 17
// 252.535 us; speedup vs baseline: 1.6299x; 1.0619x over previous
//
#include <hip/hip_runtime.h>

#define NN 50000
#define MP 50176   // row-padded
#define EE 800000
#define BB 64
#define NBUK 256   // buckets per graph
#define NPB 196    // nodes per bucket (256*196 = 50176 >= NN)
#define EPB 2048   // edges per block in scatter pass
#define SBLK ((EE + EPB - 1)/EPB)   // 391 blocks
#define SEGCAP 4096 // fixed bucket segment capacity (mean 3136, +17 sigma)

typedef _Float16 half_t;
typedef __attribute__((ext_vector_type(8))) _Float16 h16x8;
typedef __attribute__((ext_vector_type(4))) float f32x4;
typedef __attribute__((ext_vector_type(2))) float f32x2;

__device__ __forceinline__ int ntld(const int* p){ return __builtin_nontemporal_load(p); }
__device__ __forceinline__ float ntldf(const float* p){ return __builtin_nontemporal_load(p); }

__device__ __forceinline__ unsigned pack_rec(int s, float w){
  union{ _Float16 h; unsigned short u; } c; c.h = (_Float16)w;
  return (unsigned)s | ((unsigned)c.u << 16);
}
__device__ __forceinline__ float rec_w(unsigned r){
  union{ unsigned short u; _Float16 h; } c; c.u = (unsigned short)(r >> 16);
  return (float)c.h;
}

// ---- fp8 e4m3 helpers (HW cvt) ----
__device__ __forceinline__ unsigned pack4_fp8(float f0, float f1, float f2, float f3){
  int r = __builtin_amdgcn_cvt_pk_fp8_f32(f0, f1, 0, false);
  r = __builtin_amdgcn_cvt_pk_fp8_f32(f2, f3, r, true);
  return (unsigned)r;
}
__device__ __forceinline__ unsigned char to_fp8(float f){
  return (unsigned char)(__builtin_amdgcn_cvt_pk_fp8_f32(f, 0.f, 0, false) & 0xff);
}
__device__ __forceinline__ void fp8x8_to_f32(uint2 u, float* f){
  f32x2 a = __builtin_amdgcn_cvt_pk_f32_fp8(u.x, false);
  f32x2 b = __builtin_amdgcn_cvt_pk_f32_fp8(u.x, true);
  f32x2 c = __builtin_amdgcn_cvt_pk_f32_fp8(u.y, false);
  f32x2 d = __builtin_amdgcn_cvt_pk_f32_fp8(u.y, true);
  f[0]=a[0]; f[1]=a[1]; f[2]=b[0]; f[3]=b[1];
  f[4]=c[0]; f[5]=c[1]; f[6]=d[0]; f[7]=d[1];
}

// ---------------- fp32 rows -> fp16 + fp8 rows (optional -1 masking) ----------------
template<bool MASK>
__global__ __launch_bounds__(256)
void tohalf_kernel(const float* __restrict__ x, half_t* __restrict__ o16,
                   unsigned char* __restrict__ o8, int n8){
  int i = blockIdx.x*blockDim.x + threadIdx.x;
  if (i >= n8) return;
  float4 a = ((const float4*)x)[2*i];
  float4 b = ((const float4*)x)[2*i+1];
  float v[8] = {a.x,a.y,a.z,a.w,b.x,b.y,b.z,b.w};
  h16x8 h;
  #pragma unroll
  for (int j=0;j<8;j++){
    float f = v[j];
    if (MASK && f == -1.0f) f = 0.f;
    v[j] = f;
    h[j] = (half_t)f;
  }
  ((h16x8*)o16)[i] = h;
  ((uint2*)o8)[i] = make_uint2(pack4_fp8(v[0],v[1],v[2],v[3]), pack4_fp8(v[4],v[5],v[6],v[7]));
}

// ---------------- fused transpose + fp16 convert for all 8 weights ----------------
struct TS { const float* W; const float* add; half_t* oh; int K; int N; int base; };
struct TS8 { TS t[8]; int total; };

__global__ __launch_bounds__(256)
void tsplit8_kernel(TS8 a){
  int i = blockIdx.x*256 + threadIdx.x;
  if (i >= a.total) return;
  int w = 0;
  #pragma unroll
  for (int j=1;j<8;j++) if (i >= a.t[j].base) w = j;
  TS ts = a.t[w];
  int e = i - ts.base;
  int k = e / ts.N, n = e - k*ts.N;
  float v = ts.W[e] + (ts.add ? ts.add[e] : 0.f);
  ts.oh[(size_t)n*ts.K + k] = (half_t)v;
}

// ---------------- single-pass scatter: LDS bucket-sort then coalesced write-out ----------------
__global__ __launch_bounds__(256)
void bscatter_kernel(const int* __restrict__ src1, const int* __restrict__ dst1, const float* __restrict__ ea,
                     const int* __restrict__ src2, const int* __restrict__ dst2, const float* __restrict__ dea,
                     int* __restrict__ bcur, uint2* __restrict__ buf){
  __shared__ int hist[2*NBUK], lofs[2*NBUK], bas[2*NBUK], cur[2*NBUK];
  __shared__ int sscan[256];
  __shared__ uint2 srec[2*EPB];             // 32 KB
  __shared__ unsigned short sbkt[2*EPB];    // 8 KB
  int t = threadIdx.x;
  int base = blockIdx.x*EPB;

  int da[16]; unsigned pa[16];   // 8 iters x 2 graphs
  for (int s=t; s<2*NBUK; s+=256){ hist[s]=0; cur[s]=0; }
  __syncthreads();
  #pragma unroll
  for (int j=0;j<8;j++){
    int i = base + j*256 + t;
    if (i < EE){
      int d1 = ntld(&dst1[i]);
      da[2*j]   = d1;
      pa[2*j]   = pack_rec(ntld(&src1[i]), ntldf(&ea[i]));
      atomicAdd(&hist[d1/NPB], 1);
      int d2 = ntld(&dst2[i]);
      da[2*j+1] = d2;
      pa[2*j+1] = pack_rec(ntld(&src2[i]), ntldf(&dea[i]));
      atomicAdd(&hist[NBUK + d2/NPB], 1);
    } else { da[2*j] = -1; da[2*j+1] = -1; }
  }
  __syncthreads();
  int h0 = hist[2*t], h1 = hist[2*t+1];
  sscan[t] = h0 + h1;
  __syncthreads();
  #pragma unroll
  for (int o=1;o<256;o<<=1){ int u=(t>=o)?sscan[t-o]:0; __syncthreads(); sscan[t]+=u; __syncthreads(); }
  int ex = sscan[t] - (h0 + h1);
  lofs[2*t]   = ex;
  lofs[2*t+1] = ex + h0;
  bas[2*t]   = h0 ? atomicAdd(&bcur[2*t],   h0) : 0;
  bas[2*t+1] = h1 ? atomicAdd(&bcur[2*t+1], h1) : 0;
  __syncthreads();
  #pragma unroll
  for (int j=0;j<16;j++){
    int d = da[j];
    if (d >= 0){
      int b = ((j&1) ? NBUK : 0) + d/NPB;
      int p = lofs[b] + atomicAdd(&cur[b],1);
      srec[p] = make_uint2(pa[j], (unsigned)d);
      sbkt[p] = (unsigned short)b;
    }
  }
  __syncthreads();
  int total = sscan[255];
  for (int p=t; p<total; p+=256){
    int b = sbkt[p];
    int g = bas[b] + (p - lofs[b]);
    if (g < SEGCAP) buf[(size_t)b*SEGCAP + g] = srec[p];
  }
}

// ---------------- per-bucket node sort -> segmented CSR (int2 ptr = {start,count}) ----------------
__global__ __launch_bounds__(256)
void bfinal_kernel(const uint2* __restrict__ buf, const int* __restrict__ bcur,
                   unsigned* __restrict__ rec, int2* __restrict__ ptr1, int2* __restrict__ ptr2){
  __shared__ int cnt[NPB], off[256], cur[NPB];
  int b = blockIdx.x;          // 0..511
  int g = b >> 8, lb = b & 255;
  int n0 = lb*NPB;
  int t = threadIdx.x;
  int m = bcur[b]; if (m > SEGCAP) m = SEGCAP;
  const uint2* seg = buf + (size_t)b*SEGCAP;
  if (t < NPB){ cnt[t]=0; cur[t]=0; }
  __syncthreads();
  for (int j=t; j<m; j+=256) atomicAdd(&cnt[(int)seg[j].y - n0], 1);
  __syncthreads();
  int v = (t < NPB) ? cnt[t] : 0;
  off[t] = v; __syncthreads();
  #pragma unroll
  for (int o=1;o<256;o<<=1){ int u=(t>=o)?off[t-o]:0; __syncthreads(); off[t]+=u; __syncthreads(); }
  int ex = off[t]-v;
  __syncthreads();
  off[t] = ex;
  __syncthreads();
  int node = n0 + t;
  if (t < NPB && node < NN){
    int2 pv; pv.x = b*SEGCAP + off[t]; pv.y = (t < NPB) ? cnt[t] : 0;
    if (g==0) ptr1[node]=pv; else ptr2[node]=pv;
  }
  for (int j=t; j<m; j+=256){
    uint2 r = seg[j];
    int l = (int)r.y - n0;
    int p = atomicAdd(&cur[l],1);
    rec[(size_t)b*SEGCAP + off[l] + p] = r.x;
  }
}

// ---------------- segmented-CSR gather over fp8 rows, fp16 out ----------------
template<int F>
__global__ __launch_bounds__(256)
void gather_kernel(const unsigned char* __restrict__ H, int ldh,
                   const int2* __restrict__ ptr, const unsigned* __restrict__ rec,
                   half_t* __restrict__ Oh, int ldo){
  const int L = F/8;
  int gt = blockIdx.x*blockDim.x + threadIdx.x;
  int node = gt / L, lane = gt - node*L;
  if (node >= NN) return;
  int2 pv = ptr[node];
  int k = pv.y;
  const unsigned* base = rec + pv.x;
  float acc[8] = {0,0,0,0,0,0,0,0};
  #pragma unroll 1
  for (int j0=0; j0<k; j0+=L){
    unsigned myrec = (j0 + lane < k) ? base[j0 + lane] : 0u;
    int m = k - j0; if (m > L) m = L;
    int i = 0;
    #pragma unroll 1
    for (; i+8 <= m; i += 8){
      unsigned rr[8];
      #pragma unroll
      for (int u=0;u<8;u++) rr[u] = __shfl(myrec, i+u, L);
      uint2 vv[8];
      #pragma unroll
      for (int u=0;u<8;u++) vv[u] = *(const uint2*)(H + (size_t)(rr[u] & 0xFFFFu)*ldh + lane*8);
      #pragma unroll
      for (int u=0;u<8;u++){
        float f[8]; fp8x8_to_f32(vv[u], f);
        float w = rec_w(rr[u]);
        #pragma unroll
        for (int q=0;q<8;q++) acc[q] += w*f[q];
      }
    }
    #pragma unroll 1
    for (; i+4 <= m; i += 4){
      unsigned r0 = __shfl(myrec, i+0, L);
      unsigned r1 = __shfl(myrec, i+1, L);
      unsigned r2 = __shfl(myrec, i+2, L);
      unsigned r3 = __shfl(myrec, i+3, L);
      uint2 v0 = *(const uint2*)(H + (size_t)(r0 & 0xFFFFu)*ldh + lane*8);
      uint2 v1 = *(const uint2*)(H + (size_t)(r1 & 0xFFFFu)*ldh + lane*8);
      uint2 v2 = *(const uint2*)(H + (size_t)(r2 & 0xFFFFu)*ldh + lane*8);
      uint2 v3 = *(const uint2*)(H + (size_t)(r3 & 0xFFFFu)*ldh + lane*8);
      float f0[8], f1[8], f2[8], f3[8];
      fp8x8_to_f32(v0, f0); fp8x8_to_f32(v1, f1);
      fp8x8_to_f32(v2, f2); fp8x8_to_f32(v3, f3);
      float w0 = rec_w(r0), w1 = rec_w(r1), w2 = rec_w(r2), w3 = rec_w(r3);
      #pragma unroll
      for (int q=0;q<8;q++)
        acc[q] += w0*f0[q] + w1*f1[q] + w2*f2[q] + w3*f3[q];
    }
    for (; i < m; ++i){
      unsigned r = __shfl(myrec, i, L);
      uint2 v = *(const uint2*)(H + (size_t)(r & 0xFFFFu)*ldh + lane*8);
      float f[8]; fp8x8_to_f32(v, f);
      float w = rec_w(r);
      #pragma unroll
      for (int q=0;q<8;q++) acc[q] += w*f[q];
    }
  }
  h16x8 oh;
  #pragma unroll
  for (int q=0;q<8;q++) oh[q] = (half_t)acc[q];
  *(h16x8*)(Oh + (size_t)node*ldo + lane*8) = oh;
}

// ---------------- fp16 MFMA dual GEMM, 64x128 tile, fp16 + optional fp8 out ----------------
__device__ __forceinline__ int lds_off(int r, int slot){ return r*64 + ((slot ^ (r&7))<<3); }

template<bool OUT8>
__global__ __launch_bounds__(256,3)
void mfma_gemm_kernel(const half_t* __restrict__ A, int K1, const half_t* __restrict__ W1,
                      const half_t* __restrict__ R, int K2, const half_t* __restrict__ W2,
                      const float* __restrict__ b1, const float* __restrict__ b2,
                      half_t* __restrict__ out16, unsigned char* __restrict__ out8,
                      int ldo, int coloff){
  __shared__ half_t sA[64*64], sB[128*64];
  const int tid  = threadIdx.x;
  const int lane = tid & 63;
  const int wave = tid >> 6;
  const int wr = (wave>>1)*32, wc = (wave&1)*64;
  const int row0 = blockIdx.x*64;
  const int col0 = blockIdx.y*128;

  f32x4 acc[2][4];
  #pragma unroll
  for (int a=0;a<2;a++)
    #pragma unroll
    for (int b=0;b<4;b++){ acc[a][b][0]=0.f; acc[a][b][1]=0.f; acc[a][b][2]=0.f; acc[a][b][3]=0.f; }

  #pragma unroll 1
  for (int pass=0; pass<2; ++pass){
    const half_t* Ap = pass ? R  : A;
    const half_t* Wp = pass ? W2 : W1;
    const int K = pass ? K2 : K1;
    #pragma unroll 1
    for (int k0=0; k0<K; k0+=64){
      __syncthreads();
      #pragma unroll
      for (int i=0;i<2;i++){
        int c = tid + i*256;
        int r = c >> 3, s = c & 7;
        *(h16x8*)&sA[lds_off(r,s)] = *(const h16x8*)(Ap + (size_t)(row0+r)*K + k0 + s*8);
      }
      #pragma unroll
      for (int i=0;i<4;i++){
        int c = tid + i*256;
        int r = c >> 3, s = c & 7;
        *(h16x8*)&sB[lds_off(r,s)] = *(const h16x8*)(Wp + (size_t)(col0+r)*K + k0 + s*8);
      }
      __syncthreads();
      #pragma unroll
      for (int ks=0; ks<2; ++ks){
        const int rsel = lane >> 4;
        h16x8 af[2];
        #pragma unroll
        for (int mf=0; mf<2; mf++){
          int r = wr + mf*16 + (lane&15);
          af[mf] = *(const h16x8*)&sA[lds_off(r, ks*4 + rsel)];
        }
        #pragma unroll
        for (int nf=0; nf<4; nf++){
          int cix = wc + nf*16 + (lane&15);
          h16x8 b = *(const h16x8*)&sB[lds_off(cix, ks*4 + rsel)];
          #pragma unroll
          for (int mf=0; mf<2; mf++)
            acc[mf][nf] = __builtin_amdgcn_mfma_f32_16x16x32_f16(af[mf], b, acc[mf][nf], 0,0,0);
        }
      }
    }
  }

  #pragma unroll
  for (int nf=0; nf<4; nf++){
    int colg = col0 + wc + nf*16 + (lane&15);
    float bias = b1[colg] + (b2 ? b2[colg] : 0.f);
    #pragma unroll
    for (int mf=0; mf<2; mf++){
      #pragma unroll
      for (int r=0; r<4; r++){
        int rowg = row0 + wr + mf*16 + (lane>>4)*4 + r;
        if (rowg < NN){
          float o = fmaxf(acc[mf][nf][r] + bias, 0.f);
          size_t idx = (size_t)rowg*ldo + coloff + colg;
          out16[idx] = (half_t)o;
          if (OUT8) out8[idx] = to_fp8(o);
        }
      }
    }
  }
}

// ---------------- two-phase mean pool (batch sorted, fp16 input, 64-row chunks) ----------------
__global__ __launch_bounds__(256)
void pool_partial_kernel(const half_t* __restrict__ xcp, const int* __restrict__ batch,
                         float* __restrict__ sums){
  int r0 = blockIdx.x*64;
  int r1 = r0 + 64; if (r1 > NN) r1 = NN;
  int t = threadIdx.x;
  float run = 0.f;
  int cb = batch[r0];
  for (int r=r0; r<r1; ++r){
    int b = batch[r];
    if (b != cb){ atomicAdd(&sums[cb*256 + t], run); run = 0.f; cb = b; }
    run += (float)xcp[(size_t)r*256 + t];
  }
  atomicAdd(&sums[cb*256 + t], run);
}

__device__ __forceinline__ int lower_bound_i(const int* __restrict__ arr, int n, int v){
  int lo=0, hi=n;
  while (lo < hi){ int mid=(lo+hi)>>1; if (arr[mid] < v) lo=mid+1; else hi=mid; }
  return lo;
}

// ---------------- fused tail: pool_final + seq MLP + head, 1024 threads split-k ----------------
__global__ __launch_bounds__(1024)
void tail_kernel(const float* __restrict__ sums, const int* __restrict__ batch,
                 const float* __restrict__ seq,
                 const float* __restrict__ fc1W, const float* __restrict__ fc1b,
                 const float* __restrict__ fc2W, const float* __restrict__ fc2b,
                 const float* __restrict__ fccW, const float* __restrict__ fccb,
                 const float* __restrict__ clsW, const float* __restrict__ clsb,
                 float* __restrict__ out){
  __shared__ float h[384], s1[256], sin_[256], red[1024], lg[16];
  __shared__ float mred, lred;
  int b = blockIdx.x, t = threadIdx.x;
  if (t < 256){
    int lo = lower_bound_i(batch, NN, b);
    int hi = lower_bound_i(batch, NN, b+1);
    h[t] = sums[b*256 + t] / fmaxf((float)(hi-lo), 1.0f);
    sin_[t] = seq[b*256 + t];
  }
  __syncthreads();
  // fc1: 256 outs x 4 k-slices of 64
  {
    int o = t & 255, kq = t >> 8;
    float a = 0.f;
    #pragma unroll 8
    for (int k=kq*64; k<kq*64+64; k++) a += sin_[k]*fc1W[k*256 + o];
    red[t] = a;
    __syncthreads();
    if (t < 256){
      float v = red[o] + red[256+o] + red[512+o] + red[768+o] + fc1b[o];
      s1[o] = fmaxf(v, 0.f);
    }
    __syncthreads();
  }
  // fc2: 128 outs x 8 k-slices of 32 -> h[256+o]
  {
    int o = t & 127, kq = t >> 7;
    float a = 0.f;
    #pragma unroll 8
    for (int k=kq*32; k<kq*32+32; k++) a += s1[k]*fc2W[k*128 + o];
    red[t] = a;
    __syncthreads();
    if (t < 128){
      float v = fc2b[o];
      #pragma unroll
      for (int q=0;q<8;q++) v += red[q*128 + o];
      h[256 + o] = fmaxf(v, 0.f);
    }
    __syncthreads();
  }
  // fcc: 256 outs x 4 k-slices of 96 -> s1 (reused as h2)
  {
    int o = t & 255, kq = t >> 8;
    float a = 0.f;
    #pragma unroll 8
    for (int k=kq*96; k<kq*96+96; k++) a += h[k]*fccW[k*256 + o];
    red[t] = a;
    __syncthreads();
    if (t < 256){
      float v = red[o] + red[256+o] + red[512+o] + red[768+o] + fccb[o];
      s1[o] = fmaxf(v, 0.f);
    }
    __syncthreads();
  }
  // cls: 16 outs x 16 k-slices of 16 (threads 0..255)
  if (t < 256){
    int o = t & 15, kq = t >> 4;
    float a = 0.f;
    #pragma unroll
    for (int k=kq*16; k<kq*16+16; k++) a += s1[k]*clsW[k*16 + o];
    red[t] = a;
  }
  __syncthreads();
  if (t < 16){
    float v = clsb[t];
    #pragma unroll
    for (int q=0;q<16;q++) v += red[q*16 + t];
    lg[t] = v;
  }
  __syncthreads();
  if (t == 0){
    float m = lg[0];
    for (int i=1;i<16;i++) m = fmaxf(m, lg[i]);
    float s = 0.f;
    for (int i=0;i<16;i++) s += expf(lg[i]-m);
    mred = m; lred = logf(s);
  }
  __syncthreads();
  if (t < 16) out[b*16 + t] = lg[t] - mred - lred;
}

extern "C" void kernel_launch(void* const* d_in, const int* in_sizes, int n_in,
                              void* d_out, int out_size, void* d_ws, size_t ws_size,
                              hipStream_t stream){
  const float* x      = (const float*)d_in[0];
  const int*   ei     = (const int*)  d_in[1];
  const float* ea     = (const float*)d_in[2];
  const int*   batch  = (const int*)  d_in[3];
  const float* dx     = (const float*)d_in[4];
  const int*   dei    = (const int*)  d_in[5];
  const float* dea    = (const float*)d_in[6];
  const float* seq    = (const float*)d_in[7];
  const float* g1_Wr  = (const float*)d_in[8];
  const float* g1_br  = (const float*)d_in[9];
  const float* g1_Wrt = (const float*)d_in[10];
  const float* g2_Wr  = (const float*)d_in[11];
  const float* g2_br  = (const float*)d_in[12];
  const float* g2_Wrt = (const float*)d_in[13];
  const float* d1_Wr  = (const float*)d_in[14];
  const float* d1_br  = (const float*)d_in[15];
  const float* d1_Wrt = (const float*)d_in[16];
  const float* c1_Wr  = (const float*)d_in[17];
  const float* c1_br  = (const float*)d_in[18];
  const float* c1_Wrt = (const float*)d_in[19];
  const float* skip_W = (const float*)d_in[20];
  const float* skip_b = (const float*)d_in[21];
  const float* fc1_W  = (const float*)d_in[22];
  const float* fc1_b  = (const float*)d_in[23];
  const float* fc2_W  = (const float*)d_in[24];
  const float* fc2_b  = (const float*)d_in[25];
  const float* fcc_W  = (const float*)d_in[26];
  const float* fcc_b  = (const float*)d_in[27];
  const float* cls_W  = (const float*)d_in[28];
  const float* cls_b  = (const float*)d_in[29];
  float* out = (float*)d_out;

  char* wp = (char*)d_ws;
  auto alloc = [&](size_t bytes)->char*{
    char* p = wp; wp += (bytes + 255) & ~(size_t)255; return p;
  };
  half_t* XM16 = (half_t*)alloc((size_t)MP*128*2);
  half_t* F116 = (half_t*)alloc((size_t)MP*128*2);
  half_t* DX16 = (half_t*)alloc((size_t)MP*64*2);
  half_t* XC16 = (half_t*)alloc((size_t)MP*256*2);
  half_t* AG16 = (half_t*)alloc((size_t)MP*256*2);
  half_t* XCP  = (half_t*)alloc((size_t)MP*256*2);
  unsigned char* XM8 = (unsigned char*)alloc((size_t)MP*128);
  unsigned char* F18 = (unsigned char*)alloc((size_t)MP*128);
  unsigned char* DX8 = (unsigned char*)alloc((size_t)MP*64);
  unsigned char* XC8 = (unsigned char*)alloc((size_t)MP*256);
  half_t* T1 = (half_t*)alloc(128*128*2);
  half_t* T2 = (half_t*)alloc(128*128*2);
  half_t* T3 = (half_t*)alloc(128*128*2);
  half_t* T4 = (half_t*)alloc(128*128*2);
  half_t* T5 = (half_t*)alloc(64*128*2);
  half_t* T6 = (half_t*)alloc(64*128*2);
  half_t* T7 = (half_t*)alloc(256*256*2);
  half_t* T8 = (half_t*)alloc(256*256*2);
  uint2*    BUF  = (uint2*)alloc((size_t)2*NBUK*SEGCAP*8);
  unsigned* REC  = (unsigned*)alloc((size_t)2*NBUK*SEGCAP*4);
  int* BCUR = (int*)alloc((size_t)2*NBUK*4);
  int2* PTR1 = (int2*)alloc((size_t)NN*8);
  int2* PTR2 = (int2*)alloc((size_t)NN*8);
  float* EMBS = (float*)alloc((size_t)BB*256*4);

  const int* src1 = ei;  const int* dst1 = ei + EE;
  const int* src2 = dei; const int* dst2 = dei + EE;

  // ---- CSR build: LDS-sorted scatter pass + per-bucket compact ----
  hipMemsetAsync(BCUR, 0, (size_t)2*NBUK*4, stream);
  bscatter_kernel<<<SBLK,256,0,stream>>>(src1,dst1,ea, src2,dst2,dea, BCUR, BUF);
  bfinal_kernel<<<2*NBUK,256,0,stream>>>(BUF, BCUR, REC, PTR1, PTR2);

  // fp16+fp8 activations
  tohalf_kernel<true ><<<(NN*16+255)/256,256,0,stream>>>(x,  XM16, XM8, NN*16);
  tohalf_kernel<false><<<(NN*8 +255)/256,256,0,stream>>>(dx, DX16, DX8, NN*8);

  // weight prep (T8 = c1_Wroot + skip_W)
  {
    TS8 a;
    int base = 0;
    auto put = [&](int idx, const float* W, const float* add, half_t* oh, int K, int N){
      a.t[idx] = TS{W, add, oh, K, N, base}; base += K*N;
    };
    put(0, g1_Wr,  nullptr, T1, 128,128);
    put(1, g1_Wrt, nullptr, T2, 128,128);
    put(2, g2_Wr,  nullptr, T3, 128,128);
    put(3, g2_Wrt, nullptr, T4, 128,128);
    put(4, d1_Wr,  nullptr, T5, 64,128);
    put(5, d1_Wrt, nullptr, T6, 64,128);
    put(6, c1_Wr,  nullptr, T7, 256,256);
    put(7, c1_Wrt, skip_W,  T8, 256,256);
    a.total = base;
    tsplit8_kernel<<<(a.total+255)/256,256,0,stream>>>(a);
  }

  const int GB = (NN+63)/64;   // 782

  // ---- g1 ----
  gather_kernel<128><<<(NN*16+255)/256,256,0,stream>>>(XM8,128, PTR1,REC, AG16,128);
  mfma_gemm_kernel<true><<<dim3(GB,1),256,0,stream>>>(AG16,128, T1, XM16,128, T2,
                                                      g1_br, nullptr, F116, F18, 128, 0);
  // ---- g2 ----
  gather_kernel<128><<<(NN*16+255)/256,256,0,stream>>>(F18,128, PTR1,REC, AG16,128);
  mfma_gemm_kernel<true><<<dim3(GB,1),256,0,stream>>>(AG16,128, T3, F116,128, T4,
                                                      g2_br, nullptr, XC16, XC8, 256, 0);
  // ---- duration branch -> XC cols 128..255 ----
  gather_kernel<64><<<(NN*8+255)/256,256,0,stream>>>(DX8,64, PTR2,REC, AG16,64);
  mfma_gemm_kernel<true><<<dim3(GB,1),256,0,stream>>>(AG16,64, T5, DX16,64, T6,
                                                      d1_br, nullptr, XC16, XC8, 256, 128);
  // ---- c1 + folded skip ----
  gather_kernel<256><<<(NN*32+255)/256,256,0,stream>>>(XC8,256, PTR1,REC, AG16,256);
  mfma_gemm_kernel<false><<<dim3(GB,2),256,0,stream>>>(AG16,256, T7, XC16,256, T8,
                                                       c1_br, skip_b, XCP, nullptr, 256, 0);
  // ---- pool + tail ----
  hipMemsetAsync(EMBS, 0, (size_t)BB*256*4, stream);
  pool_partial_kernel<<<(NN+63)/64,256,0,stream>>>(XCP, batch, EMBS);
  tail_kernel<<<BB,1024,0,stream>>>(EMBS, batch, seq, fc1_W, fc1_b, fc2_W, fc2_b,
                                    fcc_W, fcc_b, cls_W, cls_b, out);
}

// Round 18
// 250.537 us; speedup vs baseline: 1.6429x; 1.0080x over previous
//
#include <hip/hip_runtime.h>

#define NN 50000
#define MP 50176   // row-padded
#define EE 800000
#define BB 64
#define NBUK 256   // buckets per graph
#define NPB 196    // nodes per bucket (256*196 = 50176 >= NN)
#define EPB 2048   // edges per block in scatter pass
#define SBLK ((EE + EPB - 1)/EPB)   // 391 blocks
#define SEGCAP 4096 // fixed bucket segment capacity (mean 3136, +17 sigma)

typedef _Float16 half_t;
typedef __attribute__((ext_vector_type(8))) _Float16 h16x8;
typedef __attribute__((ext_vector_type(4))) float f32x4;
typedef __attribute__((ext_vector_type(2))) float f32x2;

__device__ __forceinline__ int ntld(const int* p){ return __builtin_nontemporal_load(p); }
__device__ __forceinline__ float ntldf(const float* p){ return __builtin_nontemporal_load(p); }

__device__ __forceinline__ unsigned pack_rec(int s, float w){
  union{ _Float16 h; unsigned short u; } c; c.h = (_Float16)w;
  return (unsigned)s | ((unsigned)c.u << 16);
}
__device__ __forceinline__ float rec_w(unsigned r){
  union{ unsigned short u; _Float16 h; } c; c.u = (unsigned short)(r >> 16);
  return (float)c.h;
}

// ---- fp8 e4m3 helpers (HW cvt) ----
__device__ __forceinline__ unsigned pack4_fp8(float f0, float f1, float f2, float f3){
  int r = __builtin_amdgcn_cvt_pk_fp8_f32(f0, f1, 0, false);
  r = __builtin_amdgcn_cvt_pk_fp8_f32(f2, f3, r, true);
  return (unsigned)r;
}
__device__ __forceinline__ unsigned char to_fp8(float f){
  return (unsigned char)(__builtin_amdgcn_cvt_pk_fp8_f32(f, 0.f, 0, false) & 0xff);
}
__device__ __forceinline__ void fp8x8_to_f32(uint2 u, float* f){
  f32x2 a = __builtin_amdgcn_cvt_pk_f32_fp8(u.x, false);
  f32x2 b = __builtin_amdgcn_cvt_pk_f32_fp8(u.x, true);
  f32x2 c = __builtin_amdgcn_cvt_pk_f32_fp8(u.y, false);
  f32x2 d = __builtin_amdgcn_cvt_pk_f32_fp8(u.y, true);
  f[0]=a[0]; f[1]=a[1]; f[2]=b[0]; f[3]=b[1];
  f[4]=c[0]; f[5]=c[1]; f[6]=d[0]; f[7]=d[1];
}

// ---------------- zero init (replaces graph memset nodes) ----------------
__global__ __launch_bounds__(256)
void zero_kernel(int* __restrict__ bcur, float* __restrict__ embs){
  int t = blockIdx.x*256 + threadIdx.x;
  if (t < 2*NBUK) bcur[t] = 0;
  if (t < BB*256) embs[t] = 0.f;
}

// ---------------- fp32 rows -> fp16 + fp8 rows (optional -1 masking) ----------------
template<bool MASK>
__global__ __launch_bounds__(256)
void tohalf_kernel(const float* __restrict__ x, half_t* __restrict__ o16,
                   unsigned char* __restrict__ o8, int n8){
  int i = blockIdx.x*blockDim.x + threadIdx.x;
  if (i >= n8) return;
  float4 a = ((const float4*)x)[2*i];
  float4 b = ((const float4*)x)[2*i+1];
  float v[8] = {a.x,a.y,a.z,a.w,b.x,b.y,b.z,b.w};
  h16x8 h;
  #pragma unroll
  for (int j=0;j<8;j++){
    float f = v[j];
    if (MASK && f == -1.0f) f = 0.f;
    v[j] = f;
    h[j] = (half_t)f;
  }
  ((h16x8*)o16)[i] = h;
  ((uint2*)o8)[i] = make_uint2(pack4_fp8(v[0],v[1],v[2],v[3]), pack4_fp8(v[4],v[5],v[6],v[7]));
}

// ---------------- fused transpose + fp16 convert for all 8 weights ----------------
struct TS { const float* W; const float* add; half_t* oh; int K; int N; int base; };
struct TS8 { TS t[8]; int total; };

__global__ __launch_bounds__(256)
void tsplit8_kernel(TS8 a){
  int i = blockIdx.x*256 + threadIdx.x;
  if (i >= a.total) return;
  int w = 0;
  #pragma unroll
  for (int j=1;j<8;j++) if (i >= a.t[j].base) w = j;
  TS ts = a.t[w];
  int e = i - ts.base;
  int k = e / ts.N, n = e - k*ts.N;
  float v = ts.W[e] + (ts.add ? ts.add[e] : 0.f);
  ts.oh[(size_t)n*ts.K + k] = (half_t)v;
}

// ---------------- single-pass scatter: LDS bucket-sort then coalesced write-out ----------------
__global__ __launch_bounds__(256)
void bscatter_kernel(const int* __restrict__ src1, const int* __restrict__ dst1, const float* __restrict__ ea,
                     const int* __restrict__ src2, const int* __restrict__ dst2, const float* __restrict__ dea,
                     int* __restrict__ bcur, uint2* __restrict__ buf){
  __shared__ int hist[2*NBUK], lofs[2*NBUK], bas[2*NBUK], cur[2*NBUK];
  __shared__ int sscan[256];
  __shared__ uint2 srec[2*EPB];             // 32 KB
  __shared__ unsigned short sbkt[2*EPB];    // 8 KB
  int t = threadIdx.x;
  int base = blockIdx.x*EPB;

  int da[16]; unsigned pa[16];   // 8 iters x 2 graphs
  for (int s=t; s<2*NBUK; s+=256){ hist[s]=0; cur[s]=0; }
  __syncthreads();
  #pragma unroll
  for (int j=0;j<8;j++){
    int i = base + j*256 + t;
    if (i < EE){
      int d1 = ntld(&dst1[i]);
      da[2*j]   = d1;
      pa[2*j]   = pack_rec(ntld(&src1[i]), ntldf(&ea[i]));
      atomicAdd(&hist[d1/NPB], 1);
      int d2 = ntld(&dst2[i]);
      da[2*j+1] = d2;
      pa[2*j+1] = pack_rec(ntld(&src2[i]), ntldf(&dea[i]));
      atomicAdd(&hist[NBUK + d2/NPB], 1);
    } else { da[2*j] = -1; da[2*j+1] = -1; }
  }
  __syncthreads();
  int h0 = hist[2*t], h1 = hist[2*t+1];
  sscan[t] = h0 + h1;
  __syncthreads();
  #pragma unroll
  for (int o=1;o<256;o<<=1){ int u=(t>=o)?sscan[t-o]:0; __syncthreads(); sscan[t]+=u; __syncthreads(); }
  int ex = sscan[t] - (h0 + h1);
  lofs[2*t]   = ex;
  lofs[2*t+1] = ex + h0;
  bas[2*t]   = h0 ? atomicAdd(&bcur[2*t],   h0) : 0;
  bas[2*t+1] = h1 ? atomicAdd(&bcur[2*t+1], h1) : 0;
  __syncthreads();
  #pragma unroll
  for (int j=0;j<16;j++){
    int d = da[j];
    if (d >= 0){
      int b = ((j&1) ? NBUK : 0) + d/NPB;
      int p = lofs[b] + atomicAdd(&cur[b],1);
      srec[p] = make_uint2(pa[j], (unsigned)d);
      sbkt[p] = (unsigned short)b;
    }
  }
  __syncthreads();
  int total = sscan[255];
  for (int p=t; p<total; p+=256){
    int b = sbkt[p];
    int g = bas[b] + (p - lofs[b]);
    if (g < SEGCAP) buf[(size_t)b*SEGCAP + g] = srec[p];
  }
}

// ---------------- per-bucket node sort -> segmented CSR (int2 ptr = {start,count}) ----------------
__global__ __launch_bounds__(256)
void bfinal_kernel(const uint2* __restrict__ buf, const int* __restrict__ bcur,
                   unsigned* __restrict__ rec, int2* __restrict__ ptr1, int2* __restrict__ ptr2){
  __shared__ int cnt[NPB], off[256], cur[NPB];
  int b = blockIdx.x;          // 0..511
  int g = b >> 8, lb = b & 255;
  int n0 = lb*NPB;
  int t = threadIdx.x;
  int m = bcur[b]; if (m > SEGCAP) m = SEGCAP;
  const uint2* seg = buf + (size_t)b*SEGCAP;
  if (t < NPB){ cnt[t]=0; cur[t]=0; }
  __syncthreads();
  for (int j=t; j<m; j+=256) atomicAdd(&cnt[(int)seg[j].y - n0], 1);
  __syncthreads();
  int v = (t < NPB) ? cnt[t] : 0;
  off[t] = v; __syncthreads();
  #pragma unroll
  for (int o=1;o<256;o<<=1){ int u=(t>=o)?off[t-o]:0; __syncthreads(); off[t]+=u; __syncthreads(); }
  int ex = off[t]-v;
  __syncthreads();
  off[t] = ex;
  __syncthreads();
  int node = n0 + t;
  if (t < NPB && node < NN){
    int2 pv; pv.x = b*SEGCAP + off[t]; pv.y = (t < NPB) ? cnt[t] : 0;
    if (g==0) ptr1[node]=pv; else ptr2[node]=pv;
  }
  for (int j=t; j<m; j+=256){
    uint2 r = seg[j];
    int l = (int)r.y - n0;
    int p = atomicAdd(&cur[l],1);
    rec[(size_t)b*SEGCAP + off[l] + p] = r.x;
  }
}

// ---------------- segmented-CSR gather over fp8 rows, fp16 out ----------------
template<int F>
__global__ __launch_bounds__(256)
void gather_kernel(const unsigned char* __restrict__ H, int ldh,
                   const int2* __restrict__ ptr, const unsigned* __restrict__ rec,
                   half_t* __restrict__ Oh, int ldo){
  const int L = F/8;
  int gt = blockIdx.x*blockDim.x + threadIdx.x;
  int node = gt / L, lane = gt - node*L;
  if (node >= NN) return;
  int2 pv = ptr[node];
  int k = pv.y;
  const unsigned* base = rec + pv.x;
  float acc[8] = {0,0,0,0,0,0,0,0};
  #pragma unroll 1
  for (int j0=0; j0<k; j0+=L){
    unsigned myrec = (j0 + lane < k) ? base[j0 + lane] : 0u;
    int m = k - j0; if (m > L) m = L;
    int i = 0;
    #pragma unroll 1
    for (; i+8 <= m; i += 8){
      unsigned rr[8];
      #pragma unroll
      for (int u=0;u<8;u++) rr[u] = __shfl(myrec, i+u, L);
      uint2 vv[8];
      #pragma unroll
      for (int u=0;u<8;u++) vv[u] = *(const uint2*)(H + (size_t)(rr[u] & 0xFFFFu)*ldh + lane*8);
      #pragma unroll
      for (int u=0;u<8;u++){
        float f[8]; fp8x8_to_f32(vv[u], f);
        float w = rec_w(rr[u]);
        #pragma unroll
        for (int q=0;q<8;q++) acc[q] += w*f[q];
      }
    }
    #pragma unroll 1
    for (; i+4 <= m; i += 4){
      unsigned r0 = __shfl(myrec, i+0, L);
      unsigned r1 = __shfl(myrec, i+1, L);
      unsigned r2 = __shfl(myrec, i+2, L);
      unsigned r3 = __shfl(myrec, i+3, L);
      uint2 v0 = *(const uint2*)(H + (size_t)(r0 & 0xFFFFu)*ldh + lane*8);
      uint2 v1 = *(const uint2*)(H + (size_t)(r1 & 0xFFFFu)*ldh + lane*8);
      uint2 v2 = *(const uint2*)(H + (size_t)(r2 & 0xFFFFu)*ldh + lane*8);
      uint2 v3 = *(const uint2*)(H + (size_t)(r3 & 0xFFFFu)*ldh + lane*8);
      float f0[8], f1[8], f2[8], f3[8];
      fp8x8_to_f32(v0, f0); fp8x8_to_f32(v1, f1);
      fp8x8_to_f32(v2, f2); fp8x8_to_f32(v3, f3);
      float w0 = rec_w(r0), w1 = rec_w(r1), w2 = rec_w(r2), w3 = rec_w(r3);
      #pragma unroll
      for (int q=0;q<8;q++)
        acc[q] += w0*f0[q] + w1*f1[q] + w2*f2[q] + w3*f3[q];
    }
    for (; i < m; ++i){
      unsigned r = __shfl(myrec, i, L);
      uint2 v = *(const uint2*)(H + (size_t)(r & 0xFFFFu)*ldh + lane*8);
      float f[8]; fp8x8_to_f32(v, f);
      float w = rec_w(r);
      #pragma unroll
      for (int q=0;q<8;q++) acc[q] += w*f[q];
    }
  }
  h16x8 oh;
  #pragma unroll
  for (int q=0;q<8;q++) oh[q] = (half_t)acc[q];
  *(h16x8*)(Oh + (size_t)node*ldo + lane*8) = oh;
}

// ---------------- fp16 MFMA dual GEMM, 64x128 tile, fp16 + optional fp8 out ----------------
__device__ __forceinline__ int lds_off(int r, int slot){ return r*64 + ((slot ^ (r&7))<<3); }

template<bool OUT8>
__global__ __launch_bounds__(256,3)
void mfma_gemm_kernel(const half_t* __restrict__ A, int K1, const half_t* __restrict__ W1,
                      const half_t* __restrict__ R, int K2, const half_t* __restrict__ W2,
                      const float* __restrict__ b1, const float* __restrict__ b2,
                      half_t* __restrict__ out16, unsigned char* __restrict__ out8,
                      int ldo, int coloff){
  __shared__ half_t sA[64*64], sB[128*64];
  const int tid  = threadIdx.x;
  const int lane = tid & 63;
  const int wave = tid >> 6;
  const int wr = (wave>>1)*32, wc = (wave&1)*64;
  const int row0 = blockIdx.x*64;
  const int col0 = blockIdx.y*128;

  f32x4 acc[2][4];
  #pragma unroll
  for (int a=0;a<2;a++)
    #pragma unroll
    for (int b=0;b<4;b++){ acc[a][b][0]=0.f; acc[a][b][1]=0.f; acc[a][b][2]=0.f; acc[a][b][3]=0.f; }

  #pragma unroll 1
  for (int pass=0; pass<2; ++pass){
    const half_t* Ap = pass ? R  : A;
    const half_t* Wp = pass ? W2 : W1;
    const int K = pass ? K2 : K1;
    #pragma unroll 1
    for (int k0=0; k0<K; k0+=64){
      __syncthreads();
      #pragma unroll
      for (int i=0;i<2;i++){
        int c = tid + i*256;
        int r = c >> 3, s = c & 7;
        *(h16x8*)&sA[lds_off(r,s)] = *(const h16x8*)(Ap + (size_t)(row0+r)*K + k0 + s*8);
      }
      #pragma unroll
      for (int i=0;i<4;i++){
        int c = tid + i*256;
        int r = c >> 3, s = c & 7;
        *(h16x8*)&sB[lds_off(r,s)] = *(const h16x8*)(Wp + (size_t)(col0+r)*K + k0 + s*8);
      }
      __syncthreads();
      #pragma unroll
      for (int ks=0; ks<2; ++ks){
        const int rsel = lane >> 4;
        h16x8 af[2];
        #pragma unroll
        for (int mf=0; mf<2; mf++){
          int r = wr + mf*16 + (lane&15);
          af[mf] = *(const h16x8*)&sA[lds_off(r, ks*4 + rsel)];
        }
        #pragma unroll
        for (int nf=0; nf<4; nf++){
          int cix = wc + nf*16 + (lane&15);
          h16x8 b = *(const h16x8*)&sB[lds_off(cix, ks*4 + rsel)];
          #pragma unroll
          for (int mf=0; mf<2; mf++)
            acc[mf][nf] = __builtin_amdgcn_mfma_f32_16x16x32_f16(af[mf], b, acc[mf][nf], 0,0,0);
        }
      }
    }
  }

  #pragma unroll
  for (int nf=0; nf<4; nf++){
    int colg = col0 + wc + nf*16 + (lane&15);
    float bias = b1[colg] + (b2 ? b2[colg] : 0.f);
    #pragma unroll
    for (int mf=0; mf<2; mf++){
      #pragma unroll
      for (int r=0; r<4; r++){
        int rowg = row0 + wr + mf*16 + (lane>>4)*4 + r;
        if (rowg < NN){
          float o = fmaxf(acc[mf][nf][r] + bias, 0.f);
          size_t idx = (size_t)rowg*ldo + coloff + colg;
          out16[idx] = (half_t)o;
          if (OUT8) out8[idx] = to_fp8(o);
        }
      }
    }
  }
}

// ---------------- two-phase mean pool (batch sorted, fp16 input, 64-row chunks) ----------------
__global__ __launch_bounds__(256)
void pool_partial_kernel(const half_t* __restrict__ xcp, const int* __restrict__ batch,
                         float* __restrict__ sums){
  int r0 = blockIdx.x*64;
  int r1 = r0 + 64; if (r1 > NN) r1 = NN;
  int t = threadIdx.x;
  float run = 0.f;
  int cb = batch[r0];
  for (int r=r0; r<r1; ++r){
    int b = batch[r];
    if (b != cb){ atomicAdd(&sums[cb*256 + t], run); run = 0.f; cb = b; }
    run += (float)xcp[(size_t)r*256 + t];
  }
  atomicAdd(&sums[cb*256 + t], run);
}

__device__ __forceinline__ int lower_bound_i(const int* __restrict__ arr, int n, int v){
  int lo=0, hi=n;
  while (lo < hi){ int mid=(lo+hi)>>1; if (arr[mid] < v) lo=mid+1; else hi=mid; }
  return lo;
}

// ---------------- fused tail: pool_final + seq MLP + head, 1024 threads split-k ----------------
__global__ __launch_bounds__(1024)
void tail_kernel(const float* __restrict__ sums, const int* __restrict__ batch,
                 const float* __restrict__ seq,
                 const float* __restrict__ fc1W, const float* __restrict__ fc1b,
                 const float* __restrict__ fc2W, const float* __restrict__ fc2b,
                 const float* __restrict__ fccW, const float* __restrict__ fccb,
                 const float* __restrict__ clsW, const float* __restrict__ clsb,
                 float* __restrict__ out){
  __shared__ float h[384], s1[256], sin_[256], red[1024], lg[16];
  __shared__ float mred, lred;
  int b = blockIdx.x, t = threadIdx.x;
  if (t < 256){
    int lo = lower_bound_i(batch, NN, b);
    int hi = lower_bound_i(batch, NN, b+1);
    h[t] = sums[b*256 + t] / fmaxf((float)(hi-lo), 1.0f);
    sin_[t] = seq[b*256 + t];
  }
  __syncthreads();
  {
    int o = t & 255, kq = t >> 8;
    float a = 0.f;
    #pragma unroll 8
    for (int k=kq*64; k<kq*64+64; k++) a += sin_[k]*fc1W[k*256 + o];
    red[t] = a;
    __syncthreads();
    if (t < 256){
      float v = red[o] + red[256+o] + red[512+o] + red[768+o] + fc1b[o];
      s1[o] = fmaxf(v, 0.f);
    }
    __syncthreads();
  }
  {
    int o = t & 127, kq = t >> 7;
    float a = 0.f;
    #pragma unroll 8
    for (int k=kq*32; k<kq*32+32; k++) a += s1[k]*fc2W[k*128 + o];
    red[t] = a;
    __syncthreads();
    if (t < 128){
      float v = fc2b[o];
      #pragma unroll
      for (int q=0;q<8;q++) v += red[q*128 + o];
      h[256 + o] = fmaxf(v, 0.f);
    }
    __syncthreads();
  }
  {
    int o = t & 255, kq = t >> 8;
    float a = 0.f;
    #pragma unroll 8
    for (int k=kq*96; k<kq*96+96; k++) a += h[k]*fccW[k*256 + o];
    red[t] = a;
    __syncthreads();
    if (t < 256){
      float v = red[o] + red[256+o] + red[512+o] + red[768+o] + fccb[o];
      s1[o] = fmaxf(v, 0.f);
    }
    __syncthreads();
  }
  if (t < 256){
    int o = t & 15, kq = t >> 4;
    float a = 0.f;
    #pragma unroll
    for (int k=kq*16; k<kq*16+16; k++) a += s1[k]*clsW[k*16 + o];
    red[t] = a;
  }
  __syncthreads();
  if (t < 16){
    float v = clsb[t];
    #pragma unroll
    for (int q=0;q<16;q++) v += red[q*16 + t];
    lg[t] = v;
  }
  __syncthreads();
  if (t == 0){
    float m = lg[0];
    for (int i=1;i<16;i++) m = fmaxf(m, lg[i]);
    float s = 0.f;
    for (int i=0;i<16;i++) s += expf(lg[i]-m);
    mred = m; lred = logf(s);
  }
  __syncthreads();
  if (t < 16) out[b*16 + t] = lg[t] - mred - lred;
}

extern "C" void kernel_launch(void* const* d_in, const int* in_sizes, int n_in,
                              void* d_out, int out_size, void* d_ws, size_t ws_size,
                              hipStream_t stream){
  const float* x      = (const float*)d_in[0];
  const int*   ei     = (const int*)  d_in[1];
  const float* ea     = (const float*)d_in[2];
  const int*   batch  = (const int*)  d_in[3];
  const float* dx     = (const float*)d_in[4];
  const int*   dei    = (const int*)  d_in[5];
  const float* dea    = (const float*)d_in[6];
  const float* seq    = (const float*)d_in[7];
  const float* g1_Wr  = (const float*)d_in[8];
  const float* g1_br  = (const float*)d_in[9];
  const float* g1_Wrt = (const float*)d_in[10];
  const float* g2_Wr  = (const float*)d_in[11];
  const float* g2_br  = (const float*)d_in[12];
  const float* g2_Wrt = (const float*)d_in[13];
  const float* d1_Wr  = (const float*)d_in[14];
  const float* d1_br  = (const float*)d_in[15];
  const float* d1_Wrt = (const float*)d_in[16];
  const float* c1_Wr  = (const float*)d_in[17];
  const float* c1_br  = (const float*)d_in[18];
  const float* c1_Wrt = (const float*)d_in[19];
  const float* skip_W = (const float*)d_in[20];
  const float* skip_b = (const float*)d_in[21];
  const float* fc1_W  = (const float*)d_in[22];
  const float* fc1_b  = (const float*)d_in[23];
  const float* fc2_W  = (const float*)d_in[24];
  const float* fc2_b  = (const float*)d_in[25];
  const float* fcc_W  = (const float*)d_in[26];
  const float* fcc_b  = (const float*)d_in[27];
  const float* cls_W  = (const float*)d_in[28];
  const float* cls_b  = (const float*)d_in[29];
  float* out = (float*)d_out;

  char* wp = (char*)d_ws;
  auto alloc = [&](size_t bytes)->char*{
    char* p = wp; wp += (bytes + 255) & ~(size_t)255; return p;
  };
  half_t* XM16 = (half_t*)alloc((size_t)MP*128*2);
  half_t* F116 = (half_t*)alloc((size_t)MP*128*2);
  half_t* DX16 = (half_t*)alloc((size_t)MP*64*2);
  half_t* XC16 = (half_t*)alloc((size_t)MP*256*2);
  half_t* AG16 = (half_t*)alloc((size_t)MP*256*2);
  half_t* XCP  = (half_t*)alloc((size_t)MP*256*2);
  unsigned char* XM8 = (unsigned char*)alloc((size_t)MP*128);
  unsigned char* F18 = (unsigned char*)alloc((size_t)MP*128);
  unsigned char* DX8 = (unsigned char*)alloc((size_t)MP*64);
  unsigned char* XC8 = (unsigned char*)alloc((size_t)MP*256);
  half_t* T1 = (half_t*)alloc(128*128*2);
  half_t* T2 = (half_t*)alloc(128*128*2);
  half_t* T3 = (half_t*)alloc(128*128*2);
  half_t* T4 = (half_t*)alloc(128*128*2);
  half_t* T5 = (half_t*)alloc(64*128*2);
  half_t* T6 = (half_t*)alloc(64*128*2);
  half_t* T7 = (half_t*)alloc(256*256*2);
  half_t* T8 = (half_t*)alloc(256*256*2);
  uint2*    BUF  = (uint2*)alloc((size_t)2*NBUK*SEGCAP*8);
  unsigned* REC  = (unsigned*)alloc((size_t)2*NBUK*SEGCAP*4);
  int* BCUR = (int*)alloc((size_t)2*NBUK*4);
  int2* PTR1 = (int2*)alloc((size_t)NN*8);
  int2* PTR2 = (int2*)alloc((size_t)NN*8);
  float* EMBS = (float*)alloc((size_t)BB*256*4);

  const int* src1 = ei;  const int* dst1 = ei + EE;
  const int* src2 = dei; const int* dst2 = dei + EE;

  // ---- zero init (kernel node, not graph memset) ----
  zero_kernel<<<64,256,0,stream>>>(BCUR, EMBS);

  // ---- CSR build: LDS-sorted scatter pass + per-bucket compact ----
  bscatter_kernel<<<SBLK,256,0,stream>>>(src1,dst1,ea, src2,dst2,dea, BCUR, BUF);
  bfinal_kernel<<<2*NBUK,256,0,stream>>>(BUF, BCUR, REC, PTR1, PTR2);

  // fp16+fp8 activations
  tohalf_kernel<true ><<<(NN*16+255)/256,256,0,stream>>>(x,  XM16, XM8, NN*16);
  tohalf_kernel<false><<<(NN*8 +255)/256,256,0,stream>>>(dx, DX16, DX8, NN*8);

  // weight prep (T8 = c1_Wroot + skip_W)
  {
    TS8 a;
    int base = 0;
    auto put = [&](int idx, const float* W, const float* add, half_t* oh, int K, int N){
      a.t[idx] = TS{W, add, oh, K, N, base}; base += K*N;
    };
    put(0, g1_Wr,  nullptr, T1, 128,128);
    put(1, g1_Wrt, nullptr, T2, 128,128);
    put(2, g2_Wr,  nullptr, T3, 128,128);
    put(3, g2_Wrt, nullptr, T4, 128,128);
    put(4, d1_Wr,  nullptr, T5, 64,128);
    put(5, d1_Wrt, nullptr, T6, 64,128);
    put(6, c1_Wr,  nullptr, T7, 256,256);
    put(7, c1_Wrt, skip_W,  T8, 256,256);
    a.total = base;
    tsplit8_kernel<<<(a.total+255)/256,256,0,stream>>>(a);
  }

  const int GB = (NN+63)/64;   // 782

  // ---- g1 ----
  gather_kernel<128><<<(NN*16+255)/256,256,0,stream>>>(XM8,128, PTR1,REC, AG16,128);
  mfma_gemm_kernel<true><<<dim3(GB,1),256,0,stream>>>(AG16,128, T1, XM16,128, T2,
                                                      g1_br, nullptr, F116, F18, 128, 0);
  // ---- g2 ----
  gather_kernel<128><<<(NN*16+255)/256,256,0,stream>>>(F18,128, PTR1,REC, AG16,128);
  mfma_gemm_kernel<true><<<dim3(GB,1),256,0,stream>>>(AG16,128, T3, F116,128, T4,
                                                      g2_br, nullptr, XC16, XC8, 256, 0);
  // ---- duration branch -> XC cols 128..255 ----
  gather_kernel<64><<<(NN*8+255)/256,256,0,stream>>>(DX8,64, PTR2,REC, AG16,64);
  mfma_gemm_kernel<true><<<dim3(GB,1),256,0,stream>>>(AG16,64, T5, DX16,64, T6,
                                                      d1_br, nullptr, XC16, XC8, 256, 128);
  // ---- c1 + folded skip ----
  gather_kernel<256><<<(NN*32+255)/256,256,0,stream>>>(XC8,256, PTR1,REC, AG16,256);
  mfma_gemm_kernel<false><<<dim3(GB,2),256,0,stream>>>(AG16,256, T7, XC16,256, T8,
                                                       c1_br, skip_b, XCP, nullptr, 256, 0);
  // ---- pool + tail ----
  pool_partial_kernel<<<(NN+63)/64,256,0,stream>>>(XCP, batch, EMBS);
  tail_kernel<<<BB,1024,0,stream>>>(EMBS, batch, seq, fc1_W, fc1_b, fc2_W, fc2_b,
                                    fcc_W, fcc_b, cls_W, cls_b, out);
}

// Round 19
// 243.442 us; speedup vs baseline: 1.6908x; 1.0291x over previous
//
#include <hip/hip_runtime.h>

#define NN 50000
#define MP 50176   // row-padded
#define EE 800000
#define BB 64
#define NBUK 256   // buckets per graph
#define NPB 196    // nodes per bucket (256*196 = 50176 >= NN)
#define EPB 2048   // edges per block in scatter pass
#define SBLK ((EE + EPB - 1)/EPB)   // 391 blocks
#define SEGCAP 4096 // fixed bucket segment capacity

typedef _Float16 half_t;
typedef __attribute__((ext_vector_type(8))) _Float16 h16x8;
typedef __attribute__((ext_vector_type(4))) float f32x4;
typedef __attribute__((ext_vector_type(2))) float f32x2;

__device__ __forceinline__ int ntld(const int* p){ return __builtin_nontemporal_load(p); }
__device__ __forceinline__ float ntldf(const float* p){ return __builtin_nontemporal_load(p); }

__device__ __forceinline__ unsigned pack_rec(int s, float w){
  union{ _Float16 h; unsigned short u; } c; c.h = (_Float16)w;
  return (unsigned)s | ((unsigned)c.u << 16);
}
__device__ __forceinline__ float rec_w(unsigned r){
  union{ unsigned short u; _Float16 h; } c; c.u = (unsigned short)(r >> 16);
  return (float)c.h;
}

// ---- fp8 e4m3 helpers (HW cvt) ----
__device__ __forceinline__ unsigned pack4_fp8(float f0, float f1, float f2, float f3){
  int r = __builtin_amdgcn_cvt_pk_fp8_f32(f0, f1, 0, false);
  r = __builtin_amdgcn_cvt_pk_fp8_f32(f2, f3, r, true);
  return (unsigned)r;
}
__device__ __forceinline__ unsigned char to_fp8(float f){
  return (unsigned char)(__builtin_amdgcn_cvt_pk_fp8_f32(f, 0.f, 0, false) & 0xff);
}
__device__ __forceinline__ void fp8x8_to_f32(uint2 u, float* f){
  f32x2 a = __builtin_amdgcn_cvt_pk_f32_fp8(u.x, false);
  f32x2 b = __builtin_amdgcn_cvt_pk_f32_fp8(u.x, true);
  f32x2 c = __builtin_amdgcn_cvt_pk_f32_fp8(u.y, false);
  f32x2 d = __builtin_amdgcn_cvt_pk_f32_fp8(u.y, true);
  f[0]=a[0]; f[1]=a[1]; f[2]=b[0]; f[3]=b[1];
  f[4]=c[0]; f[5]=c[1]; f[6]=d[0]; f[7]=d[1];
}

// ---------------- fused prep: zero + tohalf(x) + tohalf(dx) + tsplit8 ----------------
struct TS { const float* W; const float* add; half_t* oh; int K; int N; int base; };
struct Prep {
  const float* x;  half_t* xm16; unsigned char* xm8;   // n8 = NN*16
  const float* dx; half_t* dx16; unsigned char* dx8;   // n8 = NN*8
  int* bcur; float* embs;
  TS t[8]; int ttotal;
  int nbx, nbd, nbt;   // block counts per part
};

__device__ __forceinline__ void tohalf_body(const float* __restrict__ x, half_t* __restrict__ o16,
                                            unsigned char* __restrict__ o8, int n8, int i, bool mask){
  if (i >= n8) return;
  float4 a = ((const float4*)x)[2*i];
  float4 b = ((const float4*)x)[2*i+1];
  float v[8] = {a.x,a.y,a.z,a.w,b.x,b.y,b.z,b.w};
  h16x8 h;
  #pragma unroll
  for (int j=0;j<8;j++){
    float f = v[j];
    if (mask && f == -1.0f) f = 0.f;
    v[j] = f;
    h[j] = (half_t)f;
  }
  ((h16x8*)o16)[i] = h;
  ((uint2*)o8)[i] = make_uint2(pack4_fp8(v[0],v[1],v[2],v[3]), pack4_fp8(v[4],v[5],v[6],v[7]));
}

__global__ __launch_bounds__(256)
void prep_kernel(Prep P){
  int bid = blockIdx.x, t = threadIdx.x;
  if (bid < P.nbx){
    tohalf_body(P.x, P.xm16, P.xm8, NN*16, bid*256 + t, true);
    return;
  }
  bid -= P.nbx;
  if (bid < P.nbd){
    tohalf_body(P.dx, P.dx16, P.dx8, NN*8, bid*256 + t, false);
    return;
  }
  bid -= P.nbd;
  if (bid < P.nbt){
    int i = bid*256 + t;
    if (i < P.ttotal){
      int w = 0;
      #pragma unroll
      for (int j=1;j<8;j++) if (i >= P.t[j].base) w = j;
      TS ts = P.t[w];
      int e = i - ts.base;
      int k = e / ts.N, n = e - k*ts.N;
      float v = ts.W[e] + (ts.add ? ts.add[e] : 0.f);
      ts.oh[(size_t)n*ts.K + k] = (half_t)v;
    }
    return;
  }
  bid -= P.nbt;
  {
    int i = bid*256 + t;
    if (i < 2*NBUK) P.bcur[i] = 0;
    if (i < BB*256) P.embs[i] = 0.f;
  }
}

// ---------------- single-pass scatter: LDS bucket-sort then coalesced write-out ----------------
__global__ __launch_bounds__(256)
void bscatter_kernel(const int* __restrict__ src1, const int* __restrict__ dst1, const float* __restrict__ ea,
                     const int* __restrict__ src2, const int* __restrict__ dst2, const float* __restrict__ dea,
                     int* __restrict__ bcur, uint2* __restrict__ buf){
  __shared__ int hist[2*NBUK], lofs[2*NBUK], bas[2*NBUK], cur[2*NBUK];
  __shared__ int sscan[256];
  __shared__ uint2 srec[2*EPB];             // 32 KB
  __shared__ unsigned short sbkt[2*EPB];    // 8 KB
  int t = threadIdx.x;
  int base = blockIdx.x*EPB;

  int da[16]; unsigned pa[16];
  for (int s=t; s<2*NBUK; s+=256){ hist[s]=0; cur[s]=0; }
  __syncthreads();
  #pragma unroll
  for (int j=0;j<8;j++){
    int i = base + j*256 + t;
    if (i < EE){
      int d1 = ntld(&dst1[i]);
      da[2*j]   = d1;
      pa[2*j]   = pack_rec(ntld(&src1[i]), ntldf(&ea[i]));
      atomicAdd(&hist[d1/NPB], 1);
      int d2 = ntld(&dst2[i]);
      da[2*j+1] = d2;
      pa[2*j+1] = pack_rec(ntld(&src2[i]), ntldf(&dea[i]));
      atomicAdd(&hist[NBUK + d2/NPB], 1);
    } else { da[2*j] = -1; da[2*j+1] = -1; }
  }
  __syncthreads();
  int h0 = hist[2*t], h1 = hist[2*t+1];
  sscan[t] = h0 + h1;
  __syncthreads();
  #pragma unroll
  for (int o=1;o<256;o<<=1){ int u=(t>=o)?sscan[t-o]:0; __syncthreads(); sscan[t]+=u; __syncthreads(); }
  int ex = sscan[t] - (h0 + h1);
  lofs[2*t]   = ex;
  lofs[2*t+1] = ex + h0;
  bas[2*t]   = h0 ? atomicAdd(&bcur[2*t],   h0) : 0;
  bas[2*t+1] = h1 ? atomicAdd(&bcur[2*t+1], h1) : 0;
  __syncthreads();
  #pragma unroll
  for (int j=0;j<16;j++){
    int d = da[j];
    if (d >= 0){
      int b = ((j&1) ? NBUK : 0) + d/NPB;
      int p = lofs[b] + atomicAdd(&cur[b],1);
      srec[p] = make_uint2(pa[j], (unsigned)d);
      sbkt[p] = (unsigned short)b;
    }
  }
  __syncthreads();
  int total = sscan[255];
  for (int p=t; p<total; p+=256){
    int b = sbkt[p];
    int g = bas[b] + (p - lofs[b]);
    if (g < SEGCAP) buf[(size_t)b*SEGCAP + g] = srec[p];
  }
}

// ---------------- per-bucket node sort -> segmented CSR (int2 ptr = {start,count}) ----------------
__global__ __launch_bounds__(256)
void bfinal_kernel(const uint2* __restrict__ buf, const int* __restrict__ bcur,
                   unsigned* __restrict__ rec, int2* __restrict__ ptr1, int2* __restrict__ ptr2){
  __shared__ int cnt[NPB], off[256], cur[NPB];
  int b = blockIdx.x;
  int g = b >> 8, lb = b & 255;
  int n0 = lb*NPB;
  int t = threadIdx.x;
  int m = bcur[b]; if (m > SEGCAP) m = SEGCAP;
  const uint2* seg = buf + (size_t)b*SEGCAP;
  if (t < NPB){ cnt[t]=0; cur[t]=0; }
  __syncthreads();
  for (int j=t; j<m; j+=256) atomicAdd(&cnt[(int)seg[j].y - n0], 1);
  __syncthreads();
  int v = (t < NPB) ? cnt[t] : 0;
  off[t] = v; __syncthreads();
  #pragma unroll
  for (int o=1;o<256;o<<=1){ int u=(t>=o)?off[t-o]:0; __syncthreads(); off[t]+=u; __syncthreads(); }
  int ex = off[t]-v;
  __syncthreads();
  off[t] = ex;
  __syncthreads();
  int node = n0 + t;
  if (t < NPB && node < NN){
    int2 pv; pv.x = b*SEGCAP + off[t]; pv.y = (t < NPB) ? cnt[t] : 0;
    if (g==0) ptr1[node]=pv; else ptr2[node]=pv;
  }
  for (int j=t; j<m; j+=256){
    uint2 r = seg[j];
    int l = (int)r.y - n0;
    int p = atomicAdd(&cur[l],1);
    rec[(size_t)b*SEGCAP + off[l] + p] = r.x;
  }
}

// ---------------- gather body (segmented CSR, fp8 rows, fp16 out) ----------------
template<int F>
__device__ __forceinline__ void gather_body(const unsigned char* __restrict__ H, int ldh,
                                            const int2* __restrict__ ptr, const unsigned* __restrict__ rec,
                                            half_t* __restrict__ Oh, int ldo, int bid){
  const int L = F/8;
  int gt = bid*256 + threadIdx.x;
  int node = gt / L, lane = gt - node*L;
  if (node >= NN) return;
  int2 pv = ptr[node];
  int k = pv.y;
  const unsigned* base = rec + pv.x;
  float acc[8] = {0,0,0,0,0,0,0,0};
  #pragma unroll 1
  for (int j0=0; j0<k; j0+=L){
    unsigned myrec = (j0 + lane < k) ? base[j0 + lane] : 0u;
    int m = k - j0; if (m > L) m = L;
    int i = 0;
    #pragma unroll 1
    for (; i+8 <= m; i += 8){
      unsigned rr[8];
      #pragma unroll
      for (int u=0;u<8;u++) rr[u] = __shfl(myrec, i+u, L);
      uint2 vv[8];
      #pragma unroll
      for (int u=0;u<8;u++) vv[u] = *(const uint2*)(H + (size_t)(rr[u] & 0xFFFFu)*ldh + lane*8);
      #pragma unroll
      for (int u=0;u<8;u++){
        float f[8]; fp8x8_to_f32(vv[u], f);
        float w = rec_w(rr[u]);
        #pragma unroll
        for (int q=0;q<8;q++) acc[q] += w*f[q];
      }
    }
    #pragma unroll 1
    for (; i+4 <= m; i += 4){
      unsigned r0 = __shfl(myrec, i+0, L);
      unsigned r1 = __shfl(myrec, i+1, L);
      unsigned r2 = __shfl(myrec, i+2, L);
      unsigned r3 = __shfl(myrec, i+3, L);
      uint2 v0 = *(const uint2*)(H + (size_t)(r0 & 0xFFFFu)*ldh + lane*8);
      uint2 v1 = *(const uint2*)(H + (size_t)(r1 & 0xFFFFu)*ldh + lane*8);
      uint2 v2 = *(const uint2*)(H + (size_t)(r2 & 0xFFFFu)*ldh + lane*8);
      uint2 v3 = *(const uint2*)(H + (size_t)(r3 & 0xFFFFu)*ldh + lane*8);
      float f0[8], f1[8], f2[8], f3[8];
      fp8x8_to_f32(v0, f0); fp8x8_to_f32(v1, f1);
      fp8x8_to_f32(v2, f2); fp8x8_to_f32(v3, f3);
      float w0 = rec_w(r0), w1 = rec_w(r1), w2 = rec_w(r2), w3 = rec_w(r3);
      #pragma unroll
      for (int q=0;q<8;q++)
        acc[q] += w0*f0[q] + w1*f1[q] + w2*f2[q] + w3*f3[q];
    }
    for (; i < m; ++i){
      unsigned r = __shfl(myrec, i, L);
      uint2 v = *(const uint2*)(H + (size_t)(r & 0xFFFFu)*ldh + lane*8);
      float f[8]; fp8x8_to_f32(v, f);
      float w = rec_w(r);
      #pragma unroll
      for (int q=0;q<8;q++) acc[q] += w*f[q];
    }
  }
  h16x8 oh;
  #pragma unroll
  for (int q=0;q<8;q++) oh[q] = (half_t)acc[q];
  *(h16x8*)(Oh + (size_t)node*ldo + lane*8) = oh;
}

template<int F>
__global__ __launch_bounds__(256)
void gather_kernel(const unsigned char* __restrict__ H, int ldh,
                   const int2* __restrict__ ptr, const unsigned* __restrict__ rec,
                   half_t* __restrict__ Oh, int ldo){
  gather_body<F>(H, ldh, ptr, rec, Oh, ldo, blockIdx.x);
}

// combined g1 (F=128) + duration (F=64) gather
__global__ __launch_bounds__(256)
void gatherA_kernel(const unsigned char* __restrict__ H1, const int2* __restrict__ ptr1,
                    const unsigned char* __restrict__ H2, const int2* __restrict__ ptr2,
                    const unsigned* __restrict__ rec,
                    half_t* __restrict__ O1, half_t* __restrict__ O2, int nb1){
  if ((int)blockIdx.x < nb1) gather_body<128>(H1, 128, ptr1, rec, O1, 128, blockIdx.x);
  else                       gather_body<64> (H2, 64,  ptr2, rec, O2, 64,  blockIdx.x - nb1);
}

// ---------------- fp16 MFMA dual GEMM, 64x128 tile ----------------
__device__ __forceinline__ int lds_off(int r, int slot){ return r*64 + ((slot ^ (r&7))<<3); }

struct GemmJob {
  const half_t* A; int K1; const half_t* W1;
  const half_t* R; int K2; const half_t* W2;
  const float* b1;
  half_t* out16; unsigned char* out8;
  int ldo; int coloff;
};

__device__ __forceinline__ void gemm_body(const GemmJob& j, const float* __restrict__ b2, bool out8en,
                                          half_t* sA, half_t* sB){
  const int tid  = threadIdx.x;
  const int lane = tid & 63;
  const int wave = tid >> 6;
  const int wr = (wave>>1)*32, wc = (wave&1)*64;
  const int row0 = blockIdx.x*64;
  const int col0 = 0*128;  // cols handled by caller grid? (see kernels below)

  // NOTE: this body is specialized by the two kernels below which pass col0.
  (void)sA; (void)sB; (void)col0; (void)wr; (void)wc; (void)row0; (void)lane; (void)b2; (void)out8en;
}

template<bool OUT8>
__global__ __launch_bounds__(256,3)
void mfma_gemm_kernel(const half_t* __restrict__ A, int K1, const half_t* __restrict__ W1,
                      const half_t* __restrict__ R, int K2, const half_t* __restrict__ W2,
                      const float* __restrict__ b1, const float* __restrict__ b2,
                      half_t* __restrict__ out16, unsigned char* __restrict__ out8,
                      int ldo, int coloff){
  __shared__ half_t sA[64*64], sB[128*64];
  const int tid  = threadIdx.x;
  const int lane = tid & 63;
  const int wave = tid >> 6;
  const int wr = (wave>>1)*32, wc = (wave&1)*64;
  const int row0 = blockIdx.x*64;
  const int col0 = blockIdx.y*128;

  f32x4 acc[2][4];
  #pragma unroll
  for (int a=0;a<2;a++)
    #pragma unroll
    for (int b=0;b<4;b++){ acc[a][b][0]=0.f; acc[a][b][1]=0.f; acc[a][b][2]=0.f; acc[a][b][3]=0.f; }

  #pragma unroll 1
  for (int pass=0; pass<2; ++pass){
    const half_t* Ap = pass ? R  : A;
    const half_t* Wp = pass ? W2 : W1;
    const int K = pass ? K2 : K1;
    #pragma unroll 1
    for (int k0=0; k0<K; k0+=64){
      __syncthreads();
      #pragma unroll
      for (int i=0;i<2;i++){
        int c = tid + i*256;
        int r = c >> 3, s = c & 7;
        *(h16x8*)&sA[lds_off(r,s)] = *(const h16x8*)(Ap + (size_t)(row0+r)*K + k0 + s*8);
      }
      #pragma unroll
      for (int i=0;i<4;i++){
        int c = tid + i*256;
        int r = c >> 3, s = c & 7;
        *(h16x8*)&sB[lds_off(r,s)] = *(const h16x8*)(Wp + (size_t)(col0+r)*K + k0 + s*8);
      }
      __syncthreads();
      #pragma unroll
      for (int ks=0; ks<2; ++ks){
        const int rsel = lane >> 4;
        h16x8 af[2];
        #pragma unroll
        for (int mf=0; mf<2; mf++){
          int r = wr + mf*16 + (lane&15);
          af[mf] = *(const h16x8*)&sA[lds_off(r, ks*4 + rsel)];
        }
        #pragma unroll
        for (int nf=0; nf<4; nf++){
          int cix = wc + nf*16 + (lane&15);
          h16x8 b = *(const h16x8*)&sB[lds_off(cix, ks*4 + rsel)];
          #pragma unroll
          for (int mf=0; mf<2; mf++)
            acc[mf][nf] = __builtin_amdgcn_mfma_f32_16x16x32_f16(af[mf], b, acc[mf][nf], 0,0,0);
        }
      }
    }
  }

  #pragma unroll
  for (int nf=0; nf<4; nf++){
    int colg = col0 + wc + nf*16 + (lane&15);
    float bias = b1[colg] + (b2 ? b2[colg] : 0.f);
    #pragma unroll
    for (int mf=0; mf<2; mf++){
      #pragma unroll
      for (int r=0; r<4; r++){
        int rowg = row0 + wr + mf*16 + (lane>>4)*4 + r;
        if (rowg < NN){
          float o = fmaxf(acc[mf][nf][r] + bias, 0.f);
          size_t idx = (size_t)rowg*ldo + coloff + colg;
          out16[idx] = (half_t)o;
          if (OUT8) out8[idx] = to_fp8(o);
        }
      }
    }
  }
}

// combined g1 + duration GEMM (grid.y selects job; both 128-col, fp16+fp8 out)
__global__ __launch_bounds__(256,3)
void gemm2_kernel(GemmJob j0, GemmJob j1){
  __shared__ half_t sA[64*64], sB[128*64];
  const GemmJob j = (blockIdx.y == 0) ? j0 : j1;
  const int tid  = threadIdx.x;
  const int lane = tid & 63;
  const int wave = tid >> 6;
  const int wr = (wave>>1)*32, wc = (wave&1)*64;
  const int row0 = blockIdx.x*64;

  f32x4 acc[2][4];
  #pragma unroll
  for (int a=0;a<2;a++)
    #pragma unroll
    for (int b=0;b<4;b++){ acc[a][b][0]=0.f; acc[a][b][1]=0.f; acc[a][b][2]=0.f; acc[a][b][3]=0.f; }

  #pragma unroll 1
  for (int pass=0; pass<2; ++pass){
    const half_t* Ap = pass ? j.R  : j.A;
    const half_t* Wp = pass ? j.W2 : j.W1;
    const int K = pass ? j.K2 : j.K1;
    #pragma unroll 1
    for (int k0=0; k0<K; k0+=64){
      __syncthreads();
      #pragma unroll
      for (int i=0;i<2;i++){
        int c = tid + i*256;
        int r = c >> 3, s = c & 7;
        *(h16x8*)&sA[lds_off(r,s)] = *(const h16x8*)(Ap + (size_t)(row0+r)*K + k0 + s*8);
      }
      #pragma unroll
      for (int i=0;i<4;i++){
        int c = tid + i*256;
        int r = c >> 3, s = c & 7;
        *(h16x8*)&sB[lds_off(r,s)] = *(const h16x8*)(Wp + (size_t)r*K + k0 + s*8);
      }
      __syncthreads();
      #pragma unroll
      for (int ks=0; ks<2; ++ks){
        const int rsel = lane >> 4;
        h16x8 af[2];
        #pragma unroll
        for (int mf=0; mf<2; mf++){
          int r = wr + mf*16 + (lane&15);
          af[mf] = *(const h16x8*)&sA[lds_off(r, ks*4 + rsel)];
        }
        #pragma unroll
        for (int nf=0; nf<4; nf++){
          int cix = wc + nf*16 + (lane&15);
          h16x8 b = *(const h16x8*)&sB[lds_off(cix, ks*4 + rsel)];
          #pragma unroll
          for (int mf=0; mf<2; mf++)
            acc[mf][nf] = __builtin_amdgcn_mfma_f32_16x16x32_f16(af[mf], b, acc[mf][nf], 0,0,0);
        }
      }
    }
  }

  #pragma unroll
  for (int nf=0; nf<4; nf++){
    int colg = wc + nf*16 + (lane&15);
    float bias = j.b1[colg];
    #pragma unroll
    for (int mf=0; mf<2; mf++){
      #pragma unroll
      for (int r=0; r<4; r++){
        int rowg = row0 + wr + mf*16 + (lane>>4)*4 + r;
        if (rowg < NN){
          float o = fmaxf(acc[mf][nf][r] + bias, 0.f);
          size_t idx = (size_t)rowg*j.ldo + j.coloff + colg;
          j.out16[idx] = (half_t)o;
          j.out8[idx] = to_fp8(o);
        }
      }
    }
  }
}

// ---------------- two-phase mean pool (batch sorted, fp16 input, 64-row chunks) ----------------
__global__ __launch_bounds__(256)
void pool_partial_kernel(const half_t* __restrict__ xcp, const int* __restrict__ batch,
                         float* __restrict__ sums){
  int r0 = blockIdx.x*64;
  int r1 = r0 + 64; if (r1 > NN) r1 = NN;
  int t = threadIdx.x;
  float run = 0.f;
  int cb = batch[r0];
  for (int r=r0; r<r1; ++r){
    int b = batch[r];
    if (b != cb){ atomicAdd(&sums[cb*256 + t], run); run = 0.f; cb = b; }
    run += (float)xcp[(size_t)r*256 + t];
  }
  atomicAdd(&sums[cb*256 + t], run);
}

__device__ __forceinline__ int lower_bound_i(const int* __restrict__ arr, int n, int v){
  int lo=0, hi=n;
  while (lo < hi){ int mid=(lo+hi)>>1; if (arr[mid] < v) lo=mid+1; else hi=mid; }
  return lo;
}

// ---------------- fused tail: pool_final + seq MLP + head, 1024 threads split-k ----------------
__global__ __launch_bounds__(1024)
void tail_kernel(const float* __restrict__ sums, const int* __restrict__ batch,
                 const float* __restrict__ seq,
                 const float* __restrict__ fc1W, const float* __restrict__ fc1b,
                 const float* __restrict__ fc2W, const float* __restrict__ fc2b,
                 const float* __restrict__ fccW, const float* __restrict__ fccb,
                 const float* __restrict__ clsW, const float* __restrict__ clsb,
                 float* __restrict__ out){
  __shared__ float h[384], s1[256], sin_[256], red[1024], lg[16];
  __shared__ float mred, lred;
  int b = blockIdx.x, t = threadIdx.x;
  if (t < 256){
    int lo = lower_bound_i(batch, NN, b);
    int hi = lower_bound_i(batch, NN, b+1);
    h[t] = sums[b*256 + t] / fmaxf((float)(hi-lo), 1.0f);
    sin_[t] = seq[b*256 + t];
  }
  __syncthreads();
  {
    int o = t & 255, kq = t >> 8;
    float a = 0.f;
    #pragma unroll 8
    for (int k=kq*64; k<kq*64+64; k++) a += sin_[k]*fc1W[k*256 + o];
    red[t] = a;
    __syncthreads();
    if (t < 256){
      float v = red[o] + red[256+o] + red[512+o] + red[768+o] + fc1b[o];
      s1[o] = fmaxf(v, 0.f);
    }
    __syncthreads();
  }
  {
    int o = t & 127, kq = t >> 7;
    float a = 0.f;
    #pragma unroll 8
    for (int k=kq*32; k<kq*32+32; k++) a += s1[k]*fc2W[k*128 + o];
    red[t] = a;
    __syncthreads();
    if (t < 128){
      float v = fc2b[o];
      #pragma unroll
      for (int q=0;q<8;q++) v += red[q*128 + o];
      h[256 + o] = fmaxf(v, 0.f);
    }
    __syncthreads();
  }
  {
    int o = t & 255, kq = t >> 8;
    float a = 0.f;
    #pragma unroll 8
    for (int k=kq*96; k<kq*96+96; k++) a += h[k]*fccW[k*256 + o];
    red[t] = a;
    __syncthreads();
    if (t < 256){
      float v = red[o] + red[256+o] + red[512+o] + red[768+o] + fccb[o];
      s1[o] = fmaxf(v, 0.f);
    }
    __syncthreads();
  }
  if (t < 256){
    int o = t & 15, kq = t >> 4;
    float a = 0.f;
    #pragma unroll
    for (int k=kq*16; k<kq*16+16; k++) a += s1[k]*clsW[k*16 + o];
    red[t] = a;
  }
  __syncthreads();
  if (t < 16){
    float v = clsb[t];
    #pragma unroll
    for (int q=0;q<16;q++) v += red[q*16 + t];
    lg[t] = v;
  }
  __syncthreads();
  if (t == 0){
    float m = lg[0];
    for (int i=1;i<16;i++) m = fmaxf(m, lg[i]);
    float s = 0.f;
    for (int i=0;i<16;i++) s += expf(lg[i]-m);
    mred = m; lred = logf(s);
  }
  __syncthreads();
  if (t < 16) out[b*16 + t] = lg[t] - mred - lred;
}

extern "C" void kernel_launch(void* const* d_in, const int* in_sizes, int n_in,
                              void* d_out, int out_size, void* d_ws, size_t ws_size,
                              hipStream_t stream){
  const float* x      = (const float*)d_in[0];
  const int*   ei     = (const int*)  d_in[1];
  const float* ea     = (const float*)d_in[2];
  const int*   batch  = (const int*)  d_in[3];
  const float* dx     = (const float*)d_in[4];
  const int*   dei    = (const int*)  d_in[5];
  const float* dea    = (const float*)d_in[6];
  const float* seq    = (const float*)d_in[7];
  const float* g1_Wr  = (const float*)d_in[8];
  const float* g1_br  = (const float*)d_in[9];
  const float* g1_Wrt = (const float*)d_in[10];
  const float* g2_Wr  = (const float*)d_in[11];
  const float* g2_br  = (const float*)d_in[12];
  const float* g2_Wrt = (const float*)d_in[13];
  const float* d1_Wr  = (const float*)d_in[14];
  const float* d1_br  = (const float*)d_in[15];
  const float* d1_Wrt = (const float*)d_in[16];
  const float* c1_Wr  = (const float*)d_in[17];
  const float* c1_br  = (const float*)d_in[18];
  const float* c1_Wrt = (const float*)d_in[19];
  const float* skip_W = (const float*)d_in[20];
  const float* skip_b = (const float*)d_in[21];
  const float* fc1_W  = (const float*)d_in[22];
  const float* fc1_b  = (const float*)d_in[23];
  const float* fc2_W  = (const float*)d_in[24];
  const float* fc2_b  = (const float*)d_in[25];
  const float* fcc_W  = (const float*)d_in[26];
  const float* fcc_b  = (const float*)d_in[27];
  const float* cls_W  = (const float*)d_in[28];
  const float* cls_b  = (const float*)d_in[29];
  float* out = (float*)d_out;

  char* wp = (char*)d_ws;
  auto alloc = [&](size_t bytes)->char*{
    char* p = wp; wp += (bytes + 255) & ~(size_t)255; return p;
  };
  half_t* XM16 = (half_t*)alloc((size_t)MP*128*2);
  half_t* F116 = (half_t*)alloc((size_t)MP*128*2);
  half_t* DX16 = (half_t*)alloc((size_t)MP*64*2);
  half_t* XC16 = (half_t*)alloc((size_t)MP*256*2);
  half_t* AG16 = (half_t*)alloc((size_t)MP*256*2);
  half_t* AGD  = (half_t*)alloc((size_t)MP*64*2);
  half_t* XCP  = (half_t*)alloc((size_t)MP*256*2);
  unsigned char* XM8 = (unsigned char*)alloc((size_t)MP*128);
  unsigned char* F18 = (unsigned char*)alloc((size_t)MP*128);
  unsigned char* DX8 = (unsigned char*)alloc((size_t)MP*64);
  unsigned char* XC8 = (unsigned char*)alloc((size_t)MP*256);
  half_t* T1 = (half_t*)alloc(128*128*2);
  half_t* T2 = (half_t*)alloc(128*128*2);
  half_t* T3 = (half_t*)alloc(128*128*2);
  half_t* T4 = (half_t*)alloc(128*128*2);
  half_t* T5 = (half_t*)alloc(64*128*2);
  half_t* T6 = (half_t*)alloc(64*128*2);
  half_t* T7 = (half_t*)alloc(256*256*2);
  half_t* T8 = (half_t*)alloc(256*256*2);
  uint2*    BUF  = (uint2*)alloc((size_t)2*NBUK*SEGCAP*8);
  unsigned* REC  = (unsigned*)alloc((size_t)2*NBUK*SEGCAP*4);
  int* BCUR = (int*)alloc((size_t)2*NBUK*4);
  int2* PTR1 = (int2*)alloc((size_t)NN*8);
  int2* PTR2 = (int2*)alloc((size_t)NN*8);
  float* EMBS = (float*)alloc((size_t)BB*256*4);

  const int* src1 = ei;  const int* dst1 = ei + EE;
  const int* src2 = dei; const int* dst2 = dei + EE;

  // ---- fused prep: zero + fp16/fp8 activations + weight transposes ----
  {
    Prep P;
    P.x = x;  P.xm16 = XM16; P.xm8 = XM8;
    P.dx = dx; P.dx16 = DX16; P.dx8 = DX8;
    P.bcur = BCUR; P.embs = EMBS;
    int base = 0;
    auto put = [&](int idx, const float* W, const float* add, half_t* oh, int K, int N){
      P.t[idx] = TS{W, add, oh, K, N, base}; base += K*N;
    };
    put(0, g1_Wr,  nullptr, T1, 128,128);
    put(1, g1_Wrt, nullptr, T2, 128,128);
    put(2, g2_Wr,  nullptr, T3, 128,128);
    put(3, g2_Wrt, nullptr, T4, 128,128);
    put(4, d1_Wr,  nullptr, T5, 64,128);
    put(5, d1_Wrt, nullptr, T6, 64,128);
    put(6, c1_Wr,  nullptr, T7, 256,256);
    put(7, c1_Wrt, skip_W,  T8, 256,256);
    P.ttotal = base;
    P.nbx = (NN*16 + 255)/256;
    P.nbd = (NN*8 + 255)/256;
    P.nbt = (P.ttotal + 255)/256;
    int nbz = 66;
    prep_kernel<<<P.nbx + P.nbd + P.nbt + nbz, 256, 0, stream>>>(P);
  }

  // ---- CSR build ----
  bscatter_kernel<<<SBLK,256,0,stream>>>(src1,dst1,ea, src2,dst2,dea, BCUR, BUF);
  bfinal_kernel<<<2*NBUK,256,0,stream>>>(BUF, BCUR, REC, PTR1, PTR2);

  const int GB = (NN+63)/64;   // 782
  const int NB1 = (NN*16 + 255)/256;   // g1 gather blocks
  const int NB2 = (NN*8  + 255)/256;   // duration gather blocks

  // ---- g1 + duration gathers (one dispatch) ----
  gatherA_kernel<<<NB1+NB2,256,0,stream>>>(XM8, PTR1, DX8, PTR2, REC, AG16, AGD, NB1);
  // ---- g1 + duration GEMMs (one dispatch) ----
  {
    GemmJob j0{AG16,128,T1, XM16,128,T2, g1_br, F116,F18, 128, 0};
    GemmJob j1{AGD, 64, T5, DX16,64, T6, d1_br, XC16,XC8, 256, 128};
    gemm2_kernel<<<dim3(GB,2),256,0,stream>>>(j0, j1);
  }
  // ---- g2 ----
  gather_kernel<128><<<NB1,256,0,stream>>>(F18,128, PTR1,REC, AG16,128);
  mfma_gemm_kernel<true><<<dim3(GB,1),256,0,stream>>>(AG16,128, T3, F116,128, T4,
                                                      g2_br, nullptr, XC16, XC8, 256, 0);
  // ---- c1 + folded skip ----
  gather_kernel<256><<<(NN*32+255)/256,256,0,stream>>>(XC8,256, PTR1,REC, AG16,256);
  mfma_gemm_kernel<false><<<dim3(GB,2),256,0,stream>>>(AG16,256, T7, XC16,256, T8,
                                                       c1_br, skip_b, XCP, nullptr, 256, 0);
  // ---- pool + tail ----
  pool_partial_kernel<<<(NN+63)/64,256,0,stream>>>(XCP, batch, EMBS);
  tail_kernel<<<BB,1024,0,stream>>>(EMBS, batch, seq, fc1_W, fc1_b, fc2_W, fc2_b,
                                    fcc_W, fcc_b, cls_W, cls_b, out);
}